// Round 4
// baseline (1540.093 us; speedup 1.0000x reference)
//
#include <hip/hip_runtime.h>

#define BS 8
#define NP 2048
#define CIN 128
#define OC 128
#define NSUP 3
#define KNN 16
#define NC 512   // (NSUP+1)*OC
#define SC 384   // NSUP*OC

#define TQ 32
#define TP 64
#define CAND 24  // fp32 candidate depth (exact top-16 inside; margin ~1e5 ulps)

// ---------- 1: squared norms of feature rows ----------
__global__ __launch_bounds__(256) void sq_kernel(const float* __restrict__ feat,
                                                 float* __restrict__ sq) {
    int r = blockIdx.x * 4 + (threadIdx.x >> 6);
    int lane = threadIdx.x & 63;
    const float* row = feat + (size_t)r * CIN;
    float a = row[lane], b = row[lane + 64];
    float s = a * a + b * b;
    for (int off = 32; off > 0; off >>= 1) s += __shfl_down(s, off);
    if (lane == 0) sq[r] = s;
}

// ---------- 2: feature-space KNN pass 1 — fp32 top-24 candidate sets ----------
// Metric: sq_j - 2*dot (query-constant shift). Self excluded by index. Only the
// candidate SET matters; exact ranking happens in the refine pass.
__global__ __launch_bounds__(256) void knn_feat_kernel(const float* __restrict__ feat,
                                                       const float* __restrict__ sqn,
                                                       int* __restrict__ cand) {
    __shared__ float Qs[TQ][132];
    __shared__ float Ps[TP][132];
    __shared__ float Ds[TQ][65];
    __shared__ float sqP[TP];
    __shared__ float Ld[TQ][CAND];
    __shared__ int   Li[TQ][CAND];

    const int b = blockIdx.y;
    const int q0 = blockIdx.x * TQ;
    const int tid = threadIdx.x;
    const float* fb = feat + (size_t)b * NP * CIN;

    for (int i = 0; i < 4; ++i) {                 // Q tile 32x128
        int e = i * 256 + tid;
        int row = e >> 5, c4 = (e & 31) << 2;
        *(float4*)&Qs[row][c4] = *(const float4*)&fb[(size_t)(q0 + row) * CIN + c4];
    }
    for (int e = tid; e < TQ * CAND; e += 256) Ld[e / CAND][e % CAND] = 3.0e38f;

    const int tq = tid & 15;      // q in {tq, tq+16}
    const int tp = tid >> 4;      // p in {tp, tp+16, tp+32, tp+48}
    const bool scanner = ((tid & 7) == 0);
    const int qs = tid >> 3;
    const int qglob = q0 + qs;
    float wr = 3.0e38f;

    // preload chunk 0
    for (int i = 0; i < 8; ++i) {
        int e = i * 256 + tid;
        int row = e >> 5, c4 = (e & 31) << 2;
        *(float4*)&Ps[row][c4] = *(const float4*)&fb[(size_t)row * CIN + c4];
    }
    if (tid < TP) sqP[tid] = sqn[b * NP + tid];

    for (int ch = 0; ch < NP / TP; ++ch) {
        __syncthreads();                           // Ps/sqP ready; scanners done with prev Ds
        float acc[2][4] = {};
        for (int c4 = 0; c4 < CIN; c4 += 4) {
            float4 qa = *(const float4*)&Qs[tq][c4];
            float4 qb = *(const float4*)&Qs[tq + 16][c4];
#pragma unroll
            for (int j = 0; j < 4; ++j) {
                float4 pv = *(const float4*)&Ps[tp + 16 * j][c4];
                acc[0][j] += qa.x * pv.x + qa.y * pv.y + qa.z * pv.z + qa.w * pv.w;
                acc[1][j] += qb.x * pv.x + qb.y * pv.y + qb.z * pv.z + qb.w * pv.w;
            }
        }
#pragma unroll
        for (int a = 0; a < 2; ++a)
#pragma unroll
            for (int j = 0; j < 4; ++j) {
                int p = tp + 16 * j;
                Ds[tq + 16 * a][p] = sqP[p] - 2.0f * acc[a][j];
            }
        __syncthreads();                           // Ds ready; Ps consumed
        if (ch + 1 < NP / TP) {                    // prefetch next chunk
            int p0n = (ch + 1) * TP;
            for (int i = 0; i < 8; ++i) {
                int e = i * 256 + tid;
                int row = e >> 5, c4 = (e & 31) << 2;
                *(float4*)&Ps[row][c4] = *(const float4*)&fb[(size_t)(p0n + row) * CIN + c4];
            }
            if (tid < TP) sqP[tid] = sqn[b * NP + p0n + tid];
        }
        if (scanner) {                             // maintain top-CAND (self-free)
            int p0 = ch * TP;
            for (int p = 0; p < TP; ++p) {
                int gi = p0 + p;
                if (gi == qglob) continue;
                float d = Ds[qs][p];
                if (d < wr) {
                    int pos = CAND - 1;
                    while (pos > 0 && Ld[qs][pos - 1] > d) {
                        Ld[qs][pos] = Ld[qs][pos - 1];
                        Li[qs][pos] = Li[qs][pos - 1];
                        --pos;
                    }
                    Ld[qs][pos] = d;
                    Li[qs][pos] = gi;
                    wr = Ld[qs][CAND - 1];
                }
            }
        }
    }
    __syncthreads();
    if (scanner) {
        int* dst = cand + ((size_t)b * NP + qglob) * CAND;
        for (int t = 0; t < CAND; ++t) dst[t] = Li[qs][t];
    }
}

// ---------- 2b: refine 24 candidates -> top-16 under REFERENCE fp32 rounding ----------
// sq/dot computed in fp64 (error ~1e-13), then the reference's exact rounding chain:
// d32 = fl32( fl32(sq_i + sq_j) - fl32(2*dot) ). Near-tie pairs collapse to the
// same fp32 grid point (as in the jax/np references) and break by index, matching
// jax.lax.top_k tie-breaking.
__global__ __launch_bounds__(256) void knn_refine_kernel(const float* __restrict__ feat,
                                                         const int* __restrict__ cand,
                                                         int* __restrict__ nbr) {
    __shared__ float lds_d[4][KNN];
    __shared__ int   lds_i[4][KNN];
    const int w = threadIdx.x >> 6;
    const int lane = threadIdx.x & 63;
    const int gq = blockIdx.x * 4 + w;             // 0 .. BS*NP-1
    const int b = gq >> 11;
    const int q = gq & (NP - 1);
    const float* fb = feat + (size_t)b * NP * CIN;

    double q0 = (double)fb[(size_t)q * CIN + lane];
    double q1 = (double)fb[(size_t)q * CIN + lane + 64];
    double sqd = q0 * q0 + q1 * q1;
    for (int off = 32; off > 0; off >>= 1) sqd += __shfl_down(sqd, off);
    sqd = __shfl(sqd, 0);
    const float sqi = (float)sqd;

    if (lane == 0)
        for (int t = 0; t < KNN; ++t) { lds_d[w][t] = 3.0e38f; lds_i[w][t] = 0x7fffffff; }

    for (int t = 0; t < CAND; ++t) {
        int j = cand[(size_t)gq * CAND + t];
        double f0 = (double)fb[(size_t)j * CIN + lane];
        double f1 = (double)fb[(size_t)j * CIN + lane + 64];
        double dot = q0 * f0 + q1 * f1;
        double sj  = f0 * f0 + f1 * f1;
        for (int off = 32; off > 0; off >>= 1) {
            dot += __shfl_down(dot, off);
            sj  += __shfl_down(sj, off);
        }
        if (lane == 0) {
            float t1 = sqi + (float)sj;            // fl32(sq_i + sq_j)
            float t2 = (float)(2.0 * dot);         // fl32(2*dot)
            float d32 = t1 - t2;                   // fl32(t1 - t2)
            float wd = lds_d[w][KNN - 1]; int wi = lds_i[w][KNN - 1];
            if (d32 < wd || (d32 == wd && j < wi)) {
                int pos = KNN - 1;
                while (pos > 0 && (lds_d[w][pos - 1] > d32 ||
                                   (lds_d[w][pos - 1] == d32 && lds_i[w][pos - 1] > j))) {
                    lds_d[w][pos] = lds_d[w][pos - 1];
                    lds_i[w][pos] = lds_i[w][pos - 1];
                    --pos;
                }
                lds_d[w][pos] = d32;
                lds_i[w][pos] = j;
            }
        }
    }
    if (lane == 0) {
        int* dst = nbr + (size_t)gq * KNN;
        for (int t = 0; t < KNN; ++t) dst[t] = lds_i[w][t];
    }
}

// ---------- 3: vertex-space KNN, fp64 exact ----------
// (Vertex-KNN flips only reach the output through mean(pooled)/2048 ~ 1e-4 —
// far below threshold; exact fp64 selection is safe here.)
__global__ __launch_bounds__(256) void knn_vert_kernel(const float* __restrict__ vert,
                                                       int* __restrict__ nbr) {
    __shared__ float vx[NP], vy[NP], vz[NP];
    __shared__ double Dsd[TQ][65];
    __shared__ double Ldd[TQ][17];
    __shared__ int    Li[TQ][17];

    const int b = blockIdx.y;
    const int q0 = blockIdx.x * TQ;
    const int tid = threadIdx.x;
    const float* vb = vert + (size_t)b * NP * 3;

    for (int i = 0; i < NP * 3 / 256; ++i) {
        int e = i * 256 + tid;
        float v = vb[e];
        int row = e / 3, comp = e % 3;
        (comp == 0 ? vx : comp == 1 ? vy : vz)[row] = v;
    }
    for (int e = tid; e < TQ * 17; e += 256) Ldd[e / 17][e % 17] = 1.0e300;

    const int tq = tid & 15;
    const int tp = tid >> 4;
    const bool scanner = ((tid & 7) == 0);
    const int qs = tid >> 3;
    double wr = 1.0e300;
    __syncthreads();

    double qx[2], qy[2], qz[2];
#pragma unroll
    for (int a = 0; a < 2; ++a) {
        int q = q0 + tq + 16 * a;
        qx[a] = (double)vx[q]; qy[a] = (double)vy[q]; qz[a] = (double)vz[q];
    }

    for (int ch = 0; ch < NP / TP; ++ch) {
        int p0 = ch * TP;
#pragma unroll
        for (int a = 0; a < 2; ++a)
#pragma unroll
            for (int j = 0; j < 4; ++j) {
                int p = tp + 16 * j;
                double dx = qx[a] - (double)vx[p0 + p];
                double dy = qy[a] - (double)vy[p0 + p];
                double dz = qz[a] - (double)vz[p0 + p];
                Dsd[tq + 16 * a][p] = dx * dx + dy * dy + dz * dz;
            }
        __syncthreads();
        if (scanner) {                             // top-17, stable (asc index scan)
            for (int p = 0; p < TP; ++p) {
                double d = Dsd[qs][p];
                if (d < wr) {
                    int pos = 16;
                    while (pos > 0 && Ldd[qs][pos - 1] > d) {
                        Ldd[qs][pos] = Ldd[qs][pos - 1];
                        Li[qs][pos] = Li[qs][pos - 1];
                        --pos;
                    }
                    Ldd[qs][pos] = d;
                    Li[qs][pos] = p0 + p;
                    wr = Ldd[qs][16];
                }
            }
        }
        __syncthreads();
    }
    if (scanner) {
        int* dst = nbr + ((size_t)b * NP + q0 + qs) * KNN;
        for (int t = 1; t <= 16; ++t) dst[t - 1] = Li[qs][t];   // drop self (rank 0)
    }
}

// ---------- 4: fm = feature_map @ weights + bias ----------
__global__ __launch_bounds__(256) void fm_gemm_kernel(const float* __restrict__ A,
                                                      const float* __restrict__ W,
                                                      const float* __restrict__ bias,
                                                      float* __restrict__ C) {
    __shared__ float As[64][132];
    __shared__ float Bt[64][132];
    const int m0 = blockIdx.x * 64;
    const int n0 = blockIdx.y * 64;
    const int tid = threadIdx.x;
    for (int i = 0; i < 8; ++i) {
        int e = i * 256 + tid;
        int row = e >> 5, c4 = (e & 31) << 2;
        *(float4*)&As[row][c4] = *(const float4*)&A[(size_t)(m0 + row) * CIN + c4];
    }
    for (int i = 0; i < 8; ++i) {
        int e = i * 256 + tid;
        int kk = e >> 4, n4 = (e & 15) << 2;
        float4 w = *(const float4*)&W[(size_t)kk * NC + n0 + n4];
        Bt[n4 + 0][kk] = w.x; Bt[n4 + 1][kk] = w.y;
        Bt[n4 + 2][kk] = w.z; Bt[n4 + 3][kk] = w.w;
    }
    __syncthreads();
    const int tm = tid & 15, tn = tid >> 4;
    float acc[4][4] = {};
    for (int c4 = 0; c4 < CIN; c4 += 4) {
        float4 av[4], bv[4];
#pragma unroll
        for (int a = 0; a < 4; ++a) av[a] = *(const float4*)&As[tm + 16 * a][c4];
#pragma unroll
        for (int bb = 0; bb < 4; ++bb) bv[bb] = *(const float4*)&Bt[tn + 16 * bb][c4];
#pragma unroll
        for (int a = 0; a < 4; ++a)
#pragma unroll
            for (int bb = 0; bb < 4; ++bb)
                acc[a][bb] += av[a].x * bv[bb].x + av[a].y * bv[bb].y
                            + av[a].z * bv[bb].z + av[a].w * bv[bb].w;
    }
#pragma unroll
    for (int a = 0; a < 4; ++a)
#pragma unroll
        for (int bb = 0; bb < 4; ++bb) {
            int m = m0 + tm + 16 * a, n = n0 + tn + 16 * bb;
            C[(size_t)m * NC + n] = acc[a][bb] + bias[n];
        }
}

// ---------- 5: direction-gated support activation + center ----------
__global__ __launch_bounds__(128) void act_kernel(const float* __restrict__ fm,
                                                  const int* __restrict__ nbr,
                                                  const float* __restrict__ vert,
                                                  const float* __restrict__ dirs,
                                                  float* __restrict__ feature) {
    __shared__ int sj[KNN];
    __shared__ float rf[KNN][4];
    const int i = blockIdx.x;
    const int b = blockIdx.y;
    const int tid = threadIdx.x;
    const size_t bi = (size_t)b * NP + i;
    if (tid < KNN) {
        int j = nbr[bi * KNN + tid];
        sj[tid] = j;
        const float* vb = vert + (size_t)b * NP * 3;
        float dx = vb[j * 3 + 0] - vb[i * 3 + 0];
        float dy = vb[j * 3 + 1] - vb[i * 3 + 1];
        float dz = vb[j * 3 + 2] - vb[i * 3 + 2];
        float nrm = sqrtf(dx * dx + dy * dy + dz * dz);
        float den = fmaxf(nrm, 1e-12f);
        rf[tid][0] = dx / den; rf[tid][1] = dy / den; rf[tid][2] = dz / den;
    }
    __syncthreads();
    const int oc = tid;
    float accm = 0.0f;
#pragma unroll
    for (int s = 0; s < NSUP; ++s) {
        int m = s * OC + oc;
        float d0 = dirs[m], d1 = dirs[SC + m], d2 = dirs[2 * SC + m];
        float nrm = sqrtf(d0 * d0 + d1 * d1 + d2 * d2);
        float den = fmaxf(nrm, 1e-12f);
        float s0 = d0 / den, s1 = d1 / den, s2 = d2 / den;
        float vmax = -3.0e38f;
        for (int kk = 0; kk < KNN; ++kk) {
            float th = fmaxf(rf[kk][0] * s0 + rf[kk][1] * s1 + rf[kk][2] * s2, 0.0f);
            float sup = fm[((size_t)b * NP + sj[kk]) * NC + OC + m];
            vmax = fmaxf(vmax, th * sup);
        }
        accm += vmax;
    }
    feature[bi * OC + oc] = fm[bi * NC + oc] + accm / 3.0f;
}

// ---------- 6: neighborhood max-pool over vertex-space KNN ----------
__global__ __launch_bounds__(128) void pool_kernel(const float* __restrict__ feature,
                                                   const int* __restrict__ nbr2,
                                                   float* __restrict__ pooled) {
    __shared__ int sj[KNN];
    const int i = blockIdx.x, b = blockIdx.y, tid = threadIdx.x;
    const size_t bi = (size_t)b * NP + i;
    if (tid < KNN) sj[tid] = nbr2[bi * KNN + tid];
    __syncthreads();
    float mx = -3.0e38f;
    for (int kk = 0; kk < KNN; ++kk)
        mx = fmaxf(mx, feature[((size_t)b * NP + sj[kk]) * OC + tid]);
    pooled[bi * OC + tid] = mx;
}

// ---------- 7/8: deterministic mean over N ----------
__global__ __launch_bounds__(128) void partial_kernel(const float* __restrict__ pooled,
                                                      float* __restrict__ part) {
    const int ch = blockIdx.x, b = blockIdx.y, tid = threadIdx.x;
    float s = 0.f;
    for (int i = 0; i < 128; ++i)
        s += pooled[((size_t)b * NP + ch * 128 + i) * OC + tid];
    part[((size_t)b * 16 + ch) * OC + tid] = s;
}
__global__ __launch_bounds__(128) void fglob_kernel(const float* __restrict__ part,
                                                    float* __restrict__ fg) {
    const int b = blockIdx.x, tid = threadIdx.x;
    float s = 0.f;
    for (int c = 0; c < 16; ++c) s += part[((size_t)b * 16 + c) * OC + tid];
    fg[b * OC + tid] = s / (float)NP;
}

// ---------- 9: transpose weights for coalesced final GEMM ----------
__global__ __launch_bounds__(256) void transpose_kernel(const float* __restrict__ conv2,
                                                        const float* __restrict__ stew,
                                                        float* __restrict__ cT,
                                                        float* __restrict__ sT) {
    int idx = blockIdx.x * 256 + threadIdx.x;
    if (idx < OC * 2 * OC) {
        int o = idx >> 8, c = idx & 255;
        cT[c * OC + o] = conv2[idx];
    } else {
        int e = idx - OC * 2 * OC;
        int o = e >> 7, c = e & 127;
        sT[c * OC + o] = stew[e];
    }
}

// ---------- 10: f_global contribution (shared per (b,o)) ----------
__global__ __launch_bounds__(128) void gdot_kernel(const float* __restrict__ fg,
                                                   const float* __restrict__ cT,
                                                   float* __restrict__ gd) {
    const int b = blockIdx.x, o = threadIdx.x;
    float s = 0.f;
    for (int c = 0; c < OC; ++c) s += fg[b * OC + c] * cT[(OC + c) * OC + o];
    gd[b * OC + o] = s;
}

// ---------- 11: fused conv2 + residual + ste ----------
__global__ __launch_bounds__(256) void final_kernel(const float* __restrict__ feature,
                                                    const float* __restrict__ fmap,
                                                    const float* __restrict__ cT,
                                                    const float* __restrict__ sT,
                                                    const float* __restrict__ gd,
                                                    float* __restrict__ out) {
    __shared__ float featL[8][128];
    __shared__ float fmapL[8][128];
    const int gp = blockIdx.x;
    const int b = gp >> 8;
    const int i0 = (gp & 255) * 8;
    const int tid = threadIdx.x;
    const size_t base = ((size_t)b * NP + i0) * OC;
    for (int e = tid; e < 8 * 128; e += 256) {
        featL[e >> 7][e & 127] = feature[base + e];
        fmapL[e >> 7][e & 127] = fmap[base + e];
    }
    __syncthreads();
    const int o = tid & 127;
    const int half = tid >> 7;
    float acc[4] = {};
    for (int c = 0; c < OC; ++c) {
        float w1 = cT[c * OC + o];
#pragma unroll
        for (int j = 0; j < 4; ++j) acc[j] += featL[half * 4 + j][c] * w1;
    }
    for (int c = 0; c < OC; ++c) {
        float w2 = sT[c * OC + o];
#pragma unroll
        for (int j = 0; j < 4; ++j) acc[j] += fmapL[half * 4 + j][c] * w2;
    }
    float g = gd[b * OC + o];
#pragma unroll
    for (int j = 0; j < 4; ++j) {
        int p = half * 4 + j;
        out[base + p * OC + o] = acc[j] + g + featL[p][o];
    }
}

extern "C" void kernel_launch(void* const* d_in, const int* in_sizes, int n_in,
                              void* d_out, int out_size, void* d_ws, size_t ws_size,
                              hipStream_t stream) {
    const float* vert  = (const float*)d_in[0];
    const float* fmap  = (const float*)d_in[1];
    const float* W     = (const float*)d_in[2];
    const float* bias  = (const float*)d_in[3];
    const float* dirs  = (const float*)d_in[4];
    const float* stew  = (const float*)d_in[5];
    const float* conv2 = (const float*)d_in[6];
    float* out = (float*)d_out;

    float* ws      = (float*)d_ws;
    float* sqn     = ws;                  // 16384
    float* C1      = sqn + 16384;         // 8*2048*512
    float* feature = C1 + 8388608;        // 8*2048*128
    float* pooled  = feature + 2097152;   // 8*2048*128
    float* part    = pooled + 2097152;    // 8*16*128
    float* fg      = part + 16384;        // 8*128
    float* gd      = fg + 1024;           // 8*128
    float* cT      = gd + 1024;           // 256*128
    float* sT      = cT + 32768;          // 128*128
    int*   nbr1    = (int*)(sT + 16384);  // 8*2048*16
    int*   nbr2    = nbr1 + 262144;       // 8*2048*16
    int*   cand    = nbr2 + 262144;       // 8*2048*24

    sq_kernel<<<4096, 256, 0, stream>>>(fmap, sqn);
    knn_feat_kernel<<<dim3(64, 8), 256, 0, stream>>>(fmap, sqn, cand);
    knn_refine_kernel<<<4096, 256, 0, stream>>>(fmap, cand, nbr1);
    knn_vert_kernel<<<dim3(64, 8), 256, 0, stream>>>(vert, nbr2);
    fm_gemm_kernel<<<dim3(256, 8), 256, 0, stream>>>(fmap, W, bias, C1);
    act_kernel<<<dim3(2048, 8), 128, 0, stream>>>(C1, nbr1, vert, dirs, feature);
    pool_kernel<<<dim3(2048, 8), 128, 0, stream>>>(feature, nbr2, pooled);
    partial_kernel<<<dim3(16, 8), 128, 0, stream>>>(pooled, part);
    fglob_kernel<<<8, 128, 0, stream>>>(part, fg);
    transpose_kernel<<<192, 256, 0, stream>>>(conv2, stew, cT, sT);
    gdot_kernel<<<8, 128, 0, stream>>>(fg, cT, gd);
    final_kernel<<<2048, 256, 0, stream>>>(feature, fmap, cT, sT, gd, out);
}

// Round 6
// 957.732 us; speedup vs baseline: 1.6081x; 1.6081x over previous
//
#include <hip/hip_runtime.h>
#include <hip/hip_bf16.h>

#define BS 8
#define NP 2048
#define CIN 128
#define OC 128
#define NSUP 3
#define KNN 16
#define NC 512   // (NSUP+1)*OC
#define SC 384   // NSUP*OC
#define CAND 24  // pass-1 candidate depth (bf16 err 3sigma~0.4 << 8-rank gap ~4.8)

typedef __attribute__((ext_vector_type(8))) short bf16x8;
typedef __attribute__((ext_vector_type(4))) float f32x4;

__device__ inline unsigned short f2bf(float x) {
    __hip_bfloat16 h = __float2bfloat16(x);
    return *reinterpret_cast<unsigned short*>(&h);
}

// ---------- 0: fp32 -> bf16 feature copy (for MFMA pass-1) ----------
__global__ __launch_bounds__(256) void tobf16_kernel(const float* __restrict__ in,
                                                     short* __restrict__ outp) {
    size_t e = ((size_t)blockIdx.x * 256 + threadIdx.x) * 8;
    float4 f0 = *(const float4*)&in[e];
    float4 f1 = *(const float4*)&in[e + 4];
    bf16x8 s;
    s[0] = (short)f2bf(f0.x); s[1] = (short)f2bf(f0.y);
    s[2] = (short)f2bf(f0.z); s[3] = (short)f2bf(f0.w);
    s[4] = (short)f2bf(f1.x); s[5] = (short)f2bf(f1.y);
    s[6] = (short)f2bf(f1.z); s[7] = (short)f2bf(f1.w);
    *(bf16x8*)&outp[e] = s;
}

// ---------- 1: squared norms of feature rows (fp32) ----------
__global__ __launch_bounds__(256) void sq_kernel(const float* __restrict__ feat,
                                                 float* __restrict__ sq) {
    int r = blockIdx.x * 4 + (threadIdx.x >> 6);
    int lane = threadIdx.x & 63;
    const float* row = feat + (size_t)r * CIN;
    float a = row[lane], b = row[lane + 64];
    float s = a * a + b * b;
    for (int off = 32; off > 0; off >>= 1) s += __shfl_down(s, off);
    if (lane == 0) sq[r] = s;
}

// ---------- 2: feature-space KNN pass 1 — MFMA bf16 Gram + flag-scan top-24 ----------
// Metric: sq_j - 2*dot_bf16. Candidate SET only; exact ranking in refine.
// LDS tiles XOR-swizzled in 16B granules (g ^= row&7) on write AND read.
#define TQF 32
#define TPF 64
#define NCHF (NP / TPF)
__global__ __launch_bounds__(256) void knn_feat_kernel(const short* __restrict__ fbb,
                                                       const float* __restrict__ sqn,
                                                       int* __restrict__ cand) {
    __shared__ alignas(16) short Qb[TQF][128];
    __shared__ alignas(16) short Pb[2][TPF][128];
    __shared__ float sqP[2][TPF];
    __shared__ alignas(16) float Ds[TQF][68];
    __shared__ float Ld[TQF][CAND];
    __shared__ int   Li[TQF][CAND];
    __shared__ float wrS[TQF];
    __shared__ alignas(8) unsigned char Bm[TQF][8];

    const int b = blockIdx.y;
    const int q0 = blockIdx.x * TQF;
    const int tid = threadIdx.x;
    const int lane = tid & 63;
    const int wid = tid >> 6;
    const short* fb = fbb + (size_t)b * NP * CIN;

    for (int e = tid; e < TQF * CAND; e += 256) {
        Ld[e / CAND][e % CAND] = 3.0e38f;
        Li[e / CAND][e % CAND] = 0x7fffffff;
    }
    if (tid < TQF) wrS[tid] = 3.0e38f;

    // stage Q tile (swizzled)
    for (int i = 0; i < 2; ++i) {
        int v = i * 256 + tid;
        int row = v >> 4, g = v & 15;
        *(bf16x8*)&Qb[row][(g ^ (row & 7)) * 8] =
            *(const bf16x8*)&fb[(size_t)(q0 + row) * CIN + g * 8];
    }
    // stage P chunk 0 (swizzled)
    for (int i = 0; i < 4; ++i) {
        int v = i * 256 + tid;
        int row = v >> 4, g = v & 15;
        *(bf16x8*)&Pb[0][row][(g ^ (row & 7)) * 8] =
            *(const bf16x8*)&fb[(size_t)row * CIN + g * 8];
    }
    if (tid < TPF) sqP[0][tid] = sqn[b * NP + tid];

    const int qt  = wid >> 1;      // wave's q-tile (0..1)
    const int ph  = wid & 1;       // wave's p-half (0..1)
    const int qsl = tid >> 3;      // scan: query 0..31
    const int sub = tid & 7;       // scan: sub-scanner 0..7
    const int qglob = q0 + qsl;

    int buf = 0;
    for (int ch = 0; ch < NCHF; ++ch) {
        __syncthreads();           // (A) Pb[buf]/sqP[buf] published; Ds free

        // issue next-chunk global loads early (reg staging; hides under MFMA+scan)
        bf16x8 st0, st1, st2, st3;
        float sq_next = 0.0f;
        const int nxt = (ch + 1 < NCHF) ? 1 : 0;
        if (nxt) {
            int p0n = (ch + 1) * TPF;
            {
                int v = tid;               int row = v >> 4, g = v & 15;
                st0 = *(const bf16x8*)&fb[(size_t)(p0n + row) * CIN + g * 8];
            }
            {
                int v = 256 + tid;         int row = v >> 4, g = v & 15;
                st1 = *(const bf16x8*)&fb[(size_t)(p0n + row) * CIN + g * 8];
            }
            {
                int v = 512 + tid;         int row = v >> 4, g = v & 15;
                st2 = *(const bf16x8*)&fb[(size_t)(p0n + row) * CIN + g * 8];
            }
            {
                int v = 768 + tid;         int row = v >> 4, g = v & 15;
                st3 = *(const bf16x8*)&fb[(size_t)(p0n + row) * CIN + g * 8];
            }
            if (tid < TPF) sq_next = sqn[b * NP + p0n + tid];
        }

        // MFMA Gram: D[32q x 64p], each wave 1 q-tile x 2 p-tiles, K=128
        {
            const int arow = qt * 16 + (lane & 15);
            const int asw = arow & 7;
            const int brow0 = ph * 32 + (lane & 15);
            const int brow1 = brow0 + 16;
            const int bsw0 = brow0 & 7;
            const int bsw1 = brow1 & 7;
            const int oct = lane >> 4;
            f32x4 acc0 = {0.f, 0.f, 0.f, 0.f};
            f32x4 acc1 = {0.f, 0.f, 0.f, 0.f};
#pragma unroll
            for (int kk = 0; kk < 4; ++kk) {
                int g = kk * 4 + oct;
                bf16x8 av  = *(const bf16x8*)&Qb[arow][(g ^ asw) * 8];
                bf16x8 bv0 = *(const bf16x8*)&Pb[buf][brow0][(g ^ bsw0) * 8];
                bf16x8 bv1 = *(const bf16x8*)&Pb[buf][brow1][(g ^ bsw1) * 8];
                acc0 = __builtin_amdgcn_mfma_f32_16x16x32_bf16(av, bv0, acc0, 0, 0, 0);
                acc1 = __builtin_amdgcn_mfma_f32_16x16x32_bf16(av, bv1, acc1, 0, 0, 0);
            }
            const int qrow = qt * 16 + (lane >> 4) * 4;   // C/D: row=(lane>>4)*4+reg
            const float sp0 = sqP[buf][brow0];
            const float sp1 = sqP[buf][brow1];
#pragma unroll
            for (int r = 0; r < 4; ++r) {
                Ds[qrow + r][brow0] = sp0 - 2.0f * acc0[r];
                Ds[qrow + r][brow1] = sp1 - 2.0f * acc1[r];
            }
        }
        __syncthreads();           // (B) Ds ready

        // flag scan: 8 threads/query, 8 points each
        {
            float wr = wrS[qsl];
            float4 dA = *(const float4*)&Ds[qsl][sub * 8];
            float4 dB = *(const float4*)&Ds[qsl][sub * 8 + 4];
            unsigned m = 0;
            m |= (dA.x < wr) ? 1u : 0u;
            m |= (dA.y < wr) ? 2u : 0u;
            m |= (dA.z < wr) ? 4u : 0u;
            m |= (dA.w < wr) ? 8u : 0u;
            m |= (dB.x < wr) ? 16u : 0u;
            m |= (dB.y < wr) ? 32u : 0u;
            m |= (dB.z < wr) ? 64u : 0u;
            m |= (dB.w < wr) ? 128u : 0u;
            Bm[qsl][sub] = (unsigned char)m;
        }
        __syncthreads();           // (C) masks ready
        if (sub == 0) {            // leader: only flagged bits (rare after warmup)
            unsigned long long mask = *(const unsigned long long*)&Bm[qsl][0];
            const int p0c = ch * TPF;
            while (mask) {
                int p = (int)__builtin_ctzll(mask);
                mask &= mask - 1;
                int gi = p0c + p;
                if (gi == qglob) continue;
                float d = Ds[qsl][p];
                if (d < Ld[qsl][CAND - 1]) {
                    int pos = CAND - 1;
                    while (pos > 0 && Ld[qsl][pos - 1] > d) {
                        Ld[qsl][pos] = Ld[qsl][pos - 1];
                        Li[qsl][pos] = Li[qsl][pos - 1];
                        --pos;
                    }
                    Ld[qsl][pos] = d;
                    Li[qsl][pos] = gi;
                }
            }
            wrS[qsl] = Ld[qsl][CAND - 1];
        }
        // write staged next chunk (overlaps leader work)
        if (nxt) {
            {
                int v = tid;               int row = v >> 4, g = v & 15;
                *(bf16x8*)&Pb[buf ^ 1][row][(g ^ (row & 7)) * 8] = st0;
            }
            {
                int v = 256 + tid;         int row = v >> 4, g = v & 15;
                *(bf16x8*)&Pb[buf ^ 1][row][(g ^ (row & 7)) * 8] = st1;
            }
            {
                int v = 512 + tid;         int row = v >> 4, g = v & 15;
                *(bf16x8*)&Pb[buf ^ 1][row][(g ^ (row & 7)) * 8] = st2;
            }
            {
                int v = 768 + tid;         int row = v >> 4, g = v & 15;
                *(bf16x8*)&Pb[buf ^ 1][row][(g ^ (row & 7)) * 8] = st3;
            }
            if (tid < TPF) sqP[buf ^ 1][tid] = sq_next;
            buf ^= 1;
        }
    }
    __syncthreads();
    if (sub == 0) {
        int* dst = cand + ((size_t)b * NP + qglob) * CAND;
        for (int t = 0; t < CAND; ++t) dst[t] = Li[qsl][t];
    }
}

// ---------- 2b: refine 24 candidates -> top-16 under REFERENCE fp32 rounding ----------
// (byte-identical to round 4 — this made the test pass; do not touch)
__global__ __launch_bounds__(256) void knn_refine_kernel(const float* __restrict__ feat,
                                                         const int* __restrict__ cand,
                                                         int* __restrict__ nbr) {
    __shared__ float lds_d[4][KNN];
    __shared__ int   lds_i[4][KNN];
    const int w = threadIdx.x >> 6;
    const int lane = threadIdx.x & 63;
    const int gq = blockIdx.x * 4 + w;
    const int b = gq >> 11;
    const int q = gq & (NP - 1);
    const float* fb = feat + (size_t)b * NP * CIN;

    double q0 = (double)fb[(size_t)q * CIN + lane];
    double q1 = (double)fb[(size_t)q * CIN + lane + 64];
    double sqd = q0 * q0 + q1 * q1;
    for (int off = 32; off > 0; off >>= 1) sqd += __shfl_down(sqd, off);
    sqd = __shfl(sqd, 0);
    const float sqi = (float)sqd;

    if (lane == 0)
        for (int t = 0; t < KNN; ++t) { lds_d[w][t] = 3.0e38f; lds_i[w][t] = 0x7fffffff; }

    for (int t = 0; t < CAND; ++t) {
        int j = cand[(size_t)gq * CAND + t];
        double f0 = (double)fb[(size_t)j * CIN + lane];
        double f1 = (double)fb[(size_t)j * CIN + lane + 64];
        double dot = q0 * f0 + q1 * f1;
        double sj  = f0 * f0 + f1 * f1;
        for (int off = 32; off > 0; off >>= 1) {
            dot += __shfl_down(dot, off);
            sj  += __shfl_down(sj, off);
        }
        if (lane == 0) {
            float t1 = sqi + (float)sj;
            float t2 = (float)(2.0 * dot);
            float d32 = t1 - t2;
            float wd = lds_d[w][KNN - 1]; int wi = lds_i[w][KNN - 1];
            if (d32 < wd || (d32 == wd && j < wi)) {
                int pos = KNN - 1;
                while (pos > 0 && (lds_d[w][pos - 1] > d32 ||
                                   (lds_d[w][pos - 1] == d32 && lds_i[w][pos - 1] > j))) {
                    lds_d[w][pos] = lds_d[w][pos - 1];
                    lds_i[w][pos] = lds_i[w][pos - 1];
                    --pos;
                }
                lds_d[w][pos] = d32;
                lds_i[w][pos] = j;
            }
        }
    }
    if (lane == 0) {
        int* dst = nbr + (size_t)gq * KNN;
        for (int t = 0; t < KNN; ++t) dst[t] = lds_i[w][t];
    }
}

// ---------- 3: vertex-space KNN, fp32 + flag-scan (flips ~1e-4 on output) ----------
#define TQV 32
#define TPV 64
__global__ __launch_bounds__(256) void knn_vert_kernel(const float* __restrict__ vert,
                                                       int* __restrict__ nbr) {
    __shared__ alignas(16) float vx[NP], vy[NP], vz[NP];
    __shared__ float Ld[TQV][17];
    __shared__ int   Li[TQV][17];
    __shared__ float wrS[TQV];
    __shared__ alignas(8) unsigned char Bm[TQV][8];

    const int b = blockIdx.y;
    const int q0 = blockIdx.x * TQV;
    const int tid = threadIdx.x;
    const float* vb = vert + (size_t)b * NP * 3;

    for (int i = 0; i < NP * 3 / 256; ++i) {
        int e = i * 256 + tid;
        float v = vb[e];
        int row = e / 3, comp = e % 3;
        (comp == 0 ? vx : comp == 1 ? vy : vz)[row] = v;
    }
    for (int e = tid; e < TQV * 17; e += 256) {
        Ld[e / 17][e % 17] = 3.0e38f;
        Li[e / 17][e % 17] = 0x7fffffff;
    }
    if (tid < TQV) wrS[tid] = 3.0e38f;
    __syncthreads();

    const int q = tid >> 3;
    const int sub = tid & 7;
    const float qx = vx[q0 + q], qy = vy[q0 + q], qz = vz[q0 + q];

    for (int ch = 0; ch < NP / TPV; ++ch) {
        const int p0 = ch * TPV;
        const int pb = p0 + sub * 8;
        float4 xA = *(const float4*)&vx[pb], xB = *(const float4*)&vx[pb + 4];
        float4 yA = *(const float4*)&vy[pb], yB = *(const float4*)&vy[pb + 4];
        float4 zA = *(const float4*)&vz[pb], zB = *(const float4*)&vz[pb + 4];
        float wr = wrS[q];
        unsigned m = 0;
        {
            float dx, dy, dz, dd;
            dx = qx - xA.x; dy = qy - yA.x; dz = qz - zA.x; dd = dx*dx + dy*dy + dz*dz; m |= (dd <= wr) ? 1u : 0u;
            dx = qx - xA.y; dy = qy - yA.y; dz = qz - zA.y; dd = dx*dx + dy*dy + dz*dz; m |= (dd <= wr) ? 2u : 0u;
            dx = qx - xA.z; dy = qy - yA.z; dz = qz - zA.z; dd = dx*dx + dy*dy + dz*dz; m |= (dd <= wr) ? 4u : 0u;
            dx = qx - xA.w; dy = qy - yA.w; dz = qz - zA.w; dd = dx*dx + dy*dy + dz*dz; m |= (dd <= wr) ? 8u : 0u;
            dx = qx - xB.x; dy = qy - yB.x; dz = qz - zB.x; dd = dx*dx + dy*dy + dz*dz; m |= (dd <= wr) ? 16u : 0u;
            dx = qx - xB.y; dy = qy - yB.y; dz = qz - zB.y; dd = dx*dx + dy*dy + dz*dz; m |= (dd <= wr) ? 32u : 0u;
            dx = qx - xB.z; dy = qy - yB.z; dz = qz - zB.z; dd = dx*dx + dy*dy + dz*dz; m |= (dd <= wr) ? 64u : 0u;
            dx = qx - xB.w; dy = qy - yB.w; dz = qz - zB.w; dd = dx*dx + dy*dy + dz*dz; m |= (dd <= wr) ? 128u : 0u;
        }
        Bm[q][sub] = (unsigned char)m;
        __syncthreads();
        if (sub == 0) {
            unsigned long long mask = *(const unsigned long long*)&Bm[q][0];
            while (mask) {
                int p = (int)__builtin_ctzll(mask);
                mask &= mask - 1;
                int gi = p0 + p;
                float dx = qx - vx[gi], dy = qy - vy[gi], dz = qz - vz[gi];
                float dd = dx * dx + dy * dy + dz * dz;
                float wd = Ld[q][16]; int wi = Li[q][16];
                if (dd < wd || (dd == wd && gi < wi)) {
                    int pos = 16;
                    while (pos > 0 && (Ld[q][pos - 1] > dd ||
                                       (Ld[q][pos - 1] == dd && Li[q][pos - 1] > gi))) {
                        Ld[q][pos] = Ld[q][pos - 1];
                        Li[q][pos] = Li[q][pos - 1];
                        --pos;
                    }
                    Ld[q][pos] = dd;
                    Li[q][pos] = gi;
                }
            }
            wrS[q] = Ld[q][16];
        }
        __syncthreads();
    }
    if (sub == 0) {
        int* dst = nbr + ((size_t)b * NP + q0 + q) * KNN;
        for (int t = 1; t <= 16; ++t) dst[t - 1] = Li[q][t];   // drop self (rank 0)
    }
}

// ---------- 4: fm = feature_map @ weights + bias ----------
__global__ __launch_bounds__(256) void fm_gemm_kernel(const float* __restrict__ A,
                                                      const float* __restrict__ W,
                                                      const float* __restrict__ bias,
                                                      float* __restrict__ C) {
    __shared__ float As[64][132];
    __shared__ float Bt[64][132];
    const int m0 = blockIdx.x * 64;
    const int n0 = blockIdx.y * 64;
    const int tid = threadIdx.x;
    for (int i = 0; i < 8; ++i) {
        int e = i * 256 + tid;
        int row = e >> 5, c4 = (e & 31) << 2;
        *(float4*)&As[row][c4] = *(const float4*)&A[(size_t)(m0 + row) * CIN + c4];
    }
    for (int i = 0; i < 8; ++i) {
        int e = i * 256 + tid;
        int kk = e >> 4, n4 = (e & 15) << 2;
        float4 w = *(const float4*)&W[(size_t)kk * NC + n0 + n4];
        Bt[n4 + 0][kk] = w.x; Bt[n4 + 1][kk] = w.y;
        Bt[n4 + 2][kk] = w.z; Bt[n4 + 3][kk] = w.w;
    }
    __syncthreads();
    const int tm = tid & 15, tn = tid >> 4;
    float acc[4][4] = {};
    for (int c4 = 0; c4 < CIN; c4 += 4) {
        float4 av[4], bv[4];
#pragma unroll
        for (int a = 0; a < 4; ++a) av[a] = *(const float4*)&As[tm + 16 * a][c4];
#pragma unroll
        for (int bb = 0; bb < 4; ++bb) bv[bb] = *(const float4*)&Bt[tn + 16 * bb][c4];
#pragma unroll
        for (int a = 0; a < 4; ++a)
#pragma unroll
            for (int bb = 0; bb < 4; ++bb)
                acc[a][bb] += av[a].x * bv[bb].x + av[a].y * bv[bb].y
                            + av[a].z * bv[bb].z + av[a].w * bv[bb].w;
    }
#pragma unroll
    for (int a = 0; a < 4; ++a)
#pragma unroll
        for (int bb = 0; bb < 4; ++bb) {
            int m = m0 + tm + 16 * a, n = n0 + tn + 16 * bb;
            C[(size_t)m * NC + n] = acc[a][bb] + bias[n];
        }
}

// ---------- 5: direction-gated support activation + center ----------
__global__ __launch_bounds__(128) void act_kernel(const float* __restrict__ fm,
                                                  const int* __restrict__ nbr,
                                                  const float* __restrict__ vert,
                                                  const float* __restrict__ dirs,
                                                  float* __restrict__ feature) {
    __shared__ int sj[KNN];
    __shared__ float rf[KNN][4];
    const int i = blockIdx.x;
    const int b = blockIdx.y;
    const int tid = threadIdx.x;
    const size_t bi = (size_t)b * NP + i;
    if (tid < KNN) {
        int j = nbr[bi * KNN + tid];
        sj[tid] = j;
        const float* vb = vert + (size_t)b * NP * 3;
        float dx = vb[j * 3 + 0] - vb[i * 3 + 0];
        float dy = vb[j * 3 + 1] - vb[i * 3 + 1];
        float dz = vb[j * 3 + 2] - vb[i * 3 + 2];
        float nrm = sqrtf(dx * dx + dy * dy + dz * dz);
        float den = fmaxf(nrm, 1e-12f);
        rf[tid][0] = dx / den; rf[tid][1] = dy / den; rf[tid][2] = dz / den;
    }
    __syncthreads();
    const int oc = tid;
    float accm = 0.0f;
#pragma unroll
    for (int s = 0; s < NSUP; ++s) {
        int m = s * OC + oc;
        float d0 = dirs[m], d1 = dirs[SC + m], d2 = dirs[2 * SC + m];
        float nrm = sqrtf(d0 * d0 + d1 * d1 + d2 * d2);
        float den = fmaxf(nrm, 1e-12f);
        float s0 = d0 / den, s1 = d1 / den, s2 = d2 / den;
        float vmax = -3.0e38f;
        for (int kk = 0; kk < KNN; ++kk) {
            float th = fmaxf(rf[kk][0] * s0 + rf[kk][1] * s1 + rf[kk][2] * s2, 0.0f);
            float sup = fm[((size_t)b * NP + sj[kk]) * NC + OC + m];
            vmax = fmaxf(vmax, th * sup);
        }
        accm += vmax;
    }
    feature[bi * OC + oc] = fm[bi * NC + oc] + accm / 3.0f;
}

// ---------- 6: neighborhood max-pool over vertex-space KNN ----------
__global__ __launch_bounds__(128) void pool_kernel(const float* __restrict__ feature,
                                                   const int* __restrict__ nbr2,
                                                   float* __restrict__ pooled) {
    __shared__ int sj[KNN];
    const int i = blockIdx.x, b = blockIdx.y, tid = threadIdx.x;
    const size_t bi = (size_t)b * NP + i;
    if (tid < KNN) sj[tid] = nbr2[bi * KNN + tid];
    __syncthreads();
    float mx = -3.0e38f;
    for (int kk = 0; kk < KNN; ++kk)
        mx = fmaxf(mx, feature[((size_t)b * NP + sj[kk]) * OC + tid]);
    pooled[bi * OC + tid] = mx;
}

// ---------- 7/8: deterministic mean over N ----------
__global__ __launch_bounds__(128) void partial_kernel(const float* __restrict__ pooled,
                                                      float* __restrict__ part) {
    const int ch = blockIdx.x, b = blockIdx.y, tid = threadIdx.x;
    float s = 0.f;
    for (int i = 0; i < 128; ++i)
        s += pooled[((size_t)b * NP + ch * 128 + i) * OC + tid];
    part[((size_t)b * 16 + ch) * OC + tid] = s;
}
__global__ __launch_bounds__(128) void fglob_kernel(const float* __restrict__ part,
                                                    float* __restrict__ fg) {
    const int b = blockIdx.x, tid = threadIdx.x;
    float s = 0.f;
    for (int c = 0; c < 16; ++c) s += part[((size_t)b * 16 + c) * OC + tid];
    fg[b * OC + tid] = s / (float)NP;
}

// ---------- 9: transpose weights for coalesced final GEMM ----------
__global__ __launch_bounds__(256) void transpose_kernel(const float* __restrict__ conv2,
                                                        const float* __restrict__ stew,
                                                        float* __restrict__ cT,
                                                        float* __restrict__ sT) {
    int idx = blockIdx.x * 256 + threadIdx.x;
    if (idx < OC * 2 * OC) {
        int o = idx >> 8, c = idx & 255;
        cT[c * OC + o] = conv2[idx];
    } else {
        int e = idx - OC * 2 * OC;
        int o = e >> 7, c = e & 127;
        sT[c * OC + o] = stew[e];
    }
}

// ---------- 10: f_global contribution (shared per (b,o)) ----------
__global__ __launch_bounds__(128) void gdot_kernel(const float* __restrict__ fg,
                                                   const float* __restrict__ cT,
                                                   float* __restrict__ gd) {
    const int b = blockIdx.x, o = threadIdx.x;
    float s = 0.f;
    for (int c = 0; c < OC; ++c) s += fg[b * OC + c] * cT[(OC + c) * OC + o];
    gd[b * OC + o] = s;
}

// ---------- 11: fused conv2 + residual + ste ----------
__global__ __launch_bounds__(256) void final_kernel(const float* __restrict__ feature,
                                                    const float* __restrict__ fmap,
                                                    const float* __restrict__ cT,
                                                    const float* __restrict__ sT,
                                                    const float* __restrict__ gd,
                                                    float* __restrict__ out) {
    __shared__ float featL[8][128];
    __shared__ float fmapL[8][128];
    const int gp = blockIdx.x;
    const int b = gp >> 8;
    const int i0 = (gp & 255) * 8;
    const int tid = threadIdx.x;
    const size_t base = ((size_t)b * NP + i0) * OC;
    for (int e = tid; e < 8 * 128; e += 256) {
        featL[e >> 7][e & 127] = feature[base + e];
        fmapL[e >> 7][e & 127] = fmap[base + e];
    }
    __syncthreads();
    const int o = tid & 127;
    const int half = tid >> 7;
    float acc[4] = {};
    for (int c = 0; c < OC; ++c) {
        float w1 = cT[c * OC + o];
#pragma unroll
        for (int j = 0; j < 4; ++j) acc[j] += featL[half * 4 + j][c] * w1;
    }
    for (int c = 0; c < OC; ++c) {
        float w2 = sT[c * OC + o];
#pragma unroll
        for (int j = 0; j < 4; ++j) acc[j] += fmapL[half * 4 + j][c] * w2;
    }
    float g = gd[b * OC + o];
#pragma unroll
    for (int j = 0; j < 4; ++j) {
        int p = half * 4 + j;
        out[base + p * OC + o] = acc[j] + g + featL[p][o];
    }
}

extern "C" void kernel_launch(void* const* d_in, const int* in_sizes, int n_in,
                              void* d_out, int out_size, void* d_ws, size_t ws_size,
                              hipStream_t stream) {
    const float* vert  = (const float*)d_in[0];
    const float* fmap  = (const float*)d_in[1];
    const float* W     = (const float*)d_in[2];
    const float* bias  = (const float*)d_in[3];
    const float* dirs  = (const float*)d_in[4];
    const float* stew  = (const float*)d_in[5];
    const float* conv2 = (const float*)d_in[6];
    float* out = (float*)d_out;

    float* ws      = (float*)d_ws;
    float* sqn     = ws;                  // 16384
    float* C1      = sqn + 16384;         // 8*2048*512
    float* feature = C1 + 8388608;        // 8*2048*128
    float* pooled  = feature + 2097152;   // 8*2048*128
    float* part    = pooled + 2097152;    // 8*16*128
    float* fg      = part + 16384;        // 8*128
    float* gd      = fg + 1024;           // 8*128
    float* cT      = gd + 1024;           // 256*128
    float* sT      = cT + 32768;          // 128*128
    int*   nbr1    = (int*)(sT + 16384);  // 8*2048*16
    int*   nbr2    = nbr1 + 262144;       // 8*2048*16
    int*   cand    = nbr2 + 262144;       // 8*2048*24
    // fbb aliases 'pooled': fbb is dead before pool_kernel writes pooled
    // (tobf16 -> knn_feat both run first; pooled written at step 6).
    short* fbb     = (short*)pooled;      // 8*2048*128 bf16 (4 MB of pooled's 8 MB)

    sq_kernel<<<4096, 256, 0, stream>>>(fmap, sqn);
    tobf16_kernel<<<1024, 256, 0, stream>>>(fmap, fbb);
    knn_feat_kernel<<<dim3(64, 8), 256, 0, stream>>>(fbb, sqn, cand);
    knn_refine_kernel<<<4096, 256, 0, stream>>>(fmap, cand, nbr1);
    knn_vert_kernel<<<dim3(64, 8), 256, 0, stream>>>(vert, nbr2);
    fm_gemm_kernel<<<dim3(256, 8), 256, 0, stream>>>(fmap, W, bias, C1);
    act_kernel<<<dim3(2048, 8), 128, 0, stream>>>(C1, nbr1, vert, dirs, feature);
    pool_kernel<<<dim3(2048, 8), 128, 0, stream>>>(feature, nbr2, pooled);
    partial_kernel<<<dim3(16, 8), 128, 0, stream>>>(pooled, part);
    fglob_kernel<<<8, 128, 0, stream>>>(part, fg);
    transpose_kernel<<<192, 256, 0, stream>>>(conv2, stew, cT, sT);
    gdot_kernel<<<8, 128, 0, stream>>>(fg, cT, gd);
    final_kernel<<<2048, 256, 0, stream>>>(feature, fmap, cT, sT, gd, out);
}

// Round 7
// 807.610 us; speedup vs baseline: 1.9070x; 1.1859x over previous
//
#include <hip/hip_runtime.h>
#include <hip/hip_bf16.h>

#define BS 8
#define NP 2048
#define CIN 128
#define OC 128
#define NSUP 3
#define KNN 16
#define NC 512   // (NSUP+1)*OC
#define SC 384   // NSUP*OC
#define CAND 24  // pass-1 candidate depth (bf16 err 3sigma~0.4 << 8-rank gap ~4.8)

typedef __attribute__((ext_vector_type(8))) short bf16x8;
typedef __attribute__((ext_vector_type(4))) float f32x4;

__device__ inline unsigned short f2bf(float x) {
    __hip_bfloat16 h = __float2bfloat16(x);
    return *reinterpret_cast<unsigned short*>(&h);
}

// ---------- 1: fused squared-norms + fp32->bf16 copy ----------
// block = 256 threads = 16 rows x 16 segments of 8
__global__ __launch_bounds__(256) void sqbf_kernel(const float* __restrict__ in,
                                                   float* __restrict__ sq,
                                                   short* __restrict__ outp) {
    const int tid = threadIdx.x;
    const int row = blockIdx.x * 16 + (tid >> 4);
    const int seg = tid & 15;
    const float* p = in + (size_t)row * CIN + seg * 8;
    float4 f0 = *(const float4*)p;
    float4 f1 = *(const float4*)(p + 4);
    bf16x8 s;
    s[0] = (short)f2bf(f0.x); s[1] = (short)f2bf(f0.y);
    s[2] = (short)f2bf(f0.z); s[3] = (short)f2bf(f0.w);
    s[4] = (short)f2bf(f1.x); s[5] = (short)f2bf(f1.y);
    s[6] = (short)f2bf(f1.z); s[7] = (short)f2bf(f1.w);
    *(bf16x8*)&outp[(size_t)row * CIN + seg * 8] = s;
    float ss = f0.x*f0.x + f0.y*f0.y + f0.z*f0.z + f0.w*f0.w
             + f1.x*f1.x + f1.y*f1.y + f1.z*f1.z + f1.w*f1.w;
#pragma unroll
    for (int msk = 1; msk <= 8; msk <<= 1) ss += __shfl_xor(ss, msk);
    if (seg == 0) sq[row] = ss;
}

// ---------- 2: feature-space KNN pass 1 — MFMA bf16 Gram + register top-24 ----------
// Metric: sq_j - 2*dot_bf16. Candidate SET only; exact ranking in refine.
// Each of 8 sub-threads per query keeps its own top-CAND over its disjoint
// 256-point stream in REGISTERS (unrolled insert); shfl-merge at the end.
#define TQF 32
#define TPF 64
#define NCHF (NP / TPF)
__global__ __launch_bounds__(256) void knn_feat_kernel(const short* __restrict__ fbb,
                                                       const float* __restrict__ sqn,
                                                       int* __restrict__ cand) {
    __shared__ alignas(16) short Qb[TQF][128];
    __shared__ alignas(16) short Pb[2][TPF][128];
    __shared__ float sqP[2][TPF];
    __shared__ alignas(16) float Ds[TQF][68];

    const int b = blockIdx.y;
    const int q0 = blockIdx.x * TQF;
    const int tid = threadIdx.x;
    const int lane = tid & 63;
    const int wid = tid >> 6;
    const short* fb = fbb + (size_t)b * NP * CIN;

    // register top-CAND list, (d, idx)-lexicographic ascending
    float rd[CAND]; int ri[CAND];
#pragma unroll
    for (int t = 0; t < CAND; ++t) { rd[t] = 3.0e38f; ri[t] = 0x7fffffff; }

    // stage Q tile (swizzled)
    for (int i = 0; i < 2; ++i) {
        int v = i * 256 + tid;
        int row = v >> 4, g = v & 15;
        *(bf16x8*)&Qb[row][(g ^ (row & 7)) * 8] =
            *(const bf16x8*)&fb[(size_t)(q0 + row) * CIN + g * 8];
    }
    // stage P chunk 0 (swizzled)
    for (int i = 0; i < 4; ++i) {
        int v = i * 256 + tid;
        int row = v >> 4, g = v & 15;
        *(bf16x8*)&Pb[0][row][(g ^ (row & 7)) * 8] =
            *(const bf16x8*)&fb[(size_t)row * CIN + g * 8];
    }
    if (tid < TPF) sqP[0][tid] = sqn[b * NP + tid];

    const int qt  = wid >> 1;      // wave's q-tile (0..1)
    const int ph  = wid & 1;       // wave's p-half (0..1)
    const int qsl = tid >> 3;      // query 0..31
    const int sub = tid & 7;       // sub-thread 0..7
    const int qglob = q0 + qsl;

    int buf = 0;
    for (int ch = 0; ch < NCHF; ++ch) {
        __syncthreads();           // (A) Pb[buf]/sqP[buf] published; Ds free

        // issue next-chunk global loads early (hidden under MFMA + insert)
        bf16x8 st0, st1, st2, st3;
        float sq_next = 0.0f;
        const int nxt = (ch + 1 < NCHF) ? 1 : 0;
        if (nxt) {
            int p0n = (ch + 1) * TPF;
            { int v = tid;       int row = v >> 4, g = v & 15;
              st0 = *(const bf16x8*)&fb[(size_t)(p0n + row) * CIN + g * 8]; }
            { int v = 256 + tid; int row = v >> 4, g = v & 15;
              st1 = *(const bf16x8*)&fb[(size_t)(p0n + row) * CIN + g * 8]; }
            { int v = 512 + tid; int row = v >> 4, g = v & 15;
              st2 = *(const bf16x8*)&fb[(size_t)(p0n + row) * CIN + g * 8]; }
            { int v = 768 + tid; int row = v >> 4, g = v & 15;
              st3 = *(const bf16x8*)&fb[(size_t)(p0n + row) * CIN + g * 8]; }
            if (tid < TPF) sq_next = sqn[b * NP + p0n + tid];
        }

        // MFMA Gram: D[32q x 64p], each wave 1 q-tile x 2 p-tiles, K=128
        {
            const int arow = qt * 16 + (lane & 15);
            const int asw = arow & 7;
            const int brow0 = ph * 32 + (lane & 15);
            const int brow1 = brow0 + 16;
            const int bsw0 = brow0 & 7;
            const int bsw1 = brow1 & 7;
            const int oct = lane >> 4;
            f32x4 acc0 = {0.f, 0.f, 0.f, 0.f};
            f32x4 acc1 = {0.f, 0.f, 0.f, 0.f};
#pragma unroll
            for (int kk = 0; kk < 4; ++kk) {
                int g = kk * 4 + oct;
                bf16x8 av  = *(const bf16x8*)&Qb[arow][(g ^ asw) * 8];
                bf16x8 bv0 = *(const bf16x8*)&Pb[buf][brow0][(g ^ bsw0) * 8];
                bf16x8 bv1 = *(const bf16x8*)&Pb[buf][brow1][(g ^ bsw1) * 8];
                acc0 = __builtin_amdgcn_mfma_f32_16x16x32_bf16(av, bv0, acc0, 0, 0, 0);
                acc1 = __builtin_amdgcn_mfma_f32_16x16x32_bf16(av, bv1, acc1, 0, 0, 0);
            }
            const int qrow = qt * 16 + (lane >> 4) * 4;   // C/D: row=(lane>>4)*4+reg
            const float sp0 = sqP[buf][brow0];
            const float sp1 = sqP[buf][brow1];
#pragma unroll
            for (int r = 0; r < 4; ++r) {
                Ds[qrow + r][brow0] = sp0 - 2.0f * acc0[r];
                Ds[qrow + r][brow1] = sp1 - 2.0f * acc1[r];
            }
        }
        __syncthreads();           // (B) Ds ready

        // per-thread register inserts: 8 values from this thread's stream
        {
            const int p0c = ch * TPF + sub * 8;
            float4 dA = *(const float4*)&Ds[qsl][sub * 8];
            float4 dB = *(const float4*)&Ds[qsl][sub * 8 + 4];
            float dv[8] = {dA.x, dA.y, dA.z, dA.w, dB.x, dB.y, dB.z, dB.w};
#pragma unroll
            for (int j = 0; j < 8; ++j) {
                const int gi = p0c + j;
                float d = (gi == qglob) ? 3.0e38f : dv[j];
                if (d < rd[CAND - 1]) {
#pragma unroll
                    for (int t = CAND - 1; t > 0; --t) {
                        bool c0 = rd[t - 1] > d;
                        bool c1 = rd[t] > d;
                        float nd = c0 ? rd[t - 1] : (c1 ? d : rd[t]);
                        int   ni = c0 ? ri[t - 1] : (c1 ? gi : ri[t]);
                        rd[t] = nd; ri[t] = ni;
                    }
                    if (rd[0] > d) { rd[0] = d; ri[0] = gi; }
                }
            }
        }

        // write staged next chunk into other buffer
        if (nxt) {
            { int v = tid;       int row = v >> 4, g = v & 15;
              *(bf16x8*)&Pb[buf ^ 1][row][(g ^ (row & 7)) * 8] = st0; }
            { int v = 256 + tid; int row = v >> 4, g = v & 15;
              *(bf16x8*)&Pb[buf ^ 1][row][(g ^ (row & 7)) * 8] = st1; }
            { int v = 512 + tid; int row = v >> 4, g = v & 15;
              *(bf16x8*)&Pb[buf ^ 1][row][(g ^ (row & 7)) * 8] = st2; }
            { int v = 768 + tid; int row = v >> 4, g = v & 15;
              *(bf16x8*)&Pb[buf ^ 1][row][(g ^ (row & 7)) * 8] = st3; }
            if (tid < TPF) sqP[buf ^ 1][tid] = sq_next;
            buf ^= 1;
        }
    }

    // merge: 8 sorted register lists per query -> global top-CAND via shfl
    {
        float hd = rd[0]; int hi = ri[0];
        int* dst = cand + ((size_t)b * NP + qglob) * CAND;
        for (int it = 0; it < CAND; ++it) {
            float m = hd; int mi = hi;
#pragma unroll
            for (int msk = 1; msk <= 4; msk <<= 1) {
                float om = __shfl_xor(m, msk);
                int   omi = __shfl_xor(mi, msk);
                if (om < m || (om == m && omi < mi)) { m = om; mi = omi; }
            }
            if (sub == 0) dst[it] = mi;
            if (hd == m && hi == mi) {          // owner pops its head
#pragma unroll
                for (int t = 0; t < CAND - 1; ++t) { rd[t] = rd[t + 1]; ri[t] = ri[t + 1]; }
                rd[CAND - 1] = 3.0e38f; ri[CAND - 1] = 0x7fffffff;
                hd = rd[0]; hi = ri[0];
            }
        }
    }
}

// ---------- 2b: refine 24 candidates -> top-16 under REFERENCE fp32 rounding ----------
// (byte-identical to round 4 — this made the test pass; do not touch)
__global__ __launch_bounds__(256) void knn_refine_kernel(const float* __restrict__ feat,
                                                         const int* __restrict__ cand,
                                                         int* __restrict__ nbr) {
    __shared__ float lds_d[4][KNN];
    __shared__ int   lds_i[4][KNN];
    const int w = threadIdx.x >> 6;
    const int lane = threadIdx.x & 63;
    const int gq = blockIdx.x * 4 + w;
    const int b = gq >> 11;
    const int q = gq & (NP - 1);
    const float* fb = feat + (size_t)b * NP * CIN;

    double q0 = (double)fb[(size_t)q * CIN + lane];
    double q1 = (double)fb[(size_t)q * CIN + lane + 64];
    double sqd = q0 * q0 + q1 * q1;
    for (int off = 32; off > 0; off >>= 1) sqd += __shfl_down(sqd, off);
    sqd = __shfl(sqd, 0);
    const float sqi = (float)sqd;

    if (lane == 0)
        for (int t = 0; t < KNN; ++t) { lds_d[w][t] = 3.0e38f; lds_i[w][t] = 0x7fffffff; }

    for (int t = 0; t < CAND; ++t) {
        int j = cand[(size_t)gq * CAND + t];
        double f0 = (double)fb[(size_t)j * CIN + lane];
        double f1 = (double)fb[(size_t)j * CIN + lane + 64];
        double dot = q0 * f0 + q1 * f1;
        double sj  = f0 * f0 + f1 * f1;
        for (int off = 32; off > 0; off >>= 1) {
            dot += __shfl_down(dot, off);
            sj  += __shfl_down(sj, off);
        }
        if (lane == 0) {
            float t1 = sqi + (float)sj;
            float t2 = (float)(2.0 * dot);
            float d32 = t1 - t2;
            float wd = lds_d[w][KNN - 1]; int wi = lds_i[w][KNN - 1];
            if (d32 < wd || (d32 == wd && j < wi)) {
                int pos = KNN - 1;
                while (pos > 0 && (lds_d[w][pos - 1] > d32 ||
                                   (lds_d[w][pos - 1] == d32 && lds_i[w][pos - 1] > j))) {
                    lds_d[w][pos] = lds_d[w][pos - 1];
                    lds_i[w][pos] = lds_i[w][pos - 1];
                    --pos;
                }
                lds_d[w][pos] = d32;
                lds_i[w][pos] = j;
            }
        }
    }
    if (lane == 0) {
        int* dst = nbr + (size_t)gq * KNN;
        for (int t = 0; t < KNN; ++t) dst[t] = lds_i[w][t];
    }
}

// ---------- 3: vertex-space KNN — register top-17 per sub-thread, no barriers ----------
#define TQV 32
__global__ __launch_bounds__(256) void knn_vert_kernel(const float* __restrict__ vert,
                                                       int* __restrict__ nbr) {
    __shared__ alignas(16) float vx[NP], vy[NP], vz[NP];
    const int b = blockIdx.y;
    const int q0 = blockIdx.x * TQV;
    const int tid = threadIdx.x;
    const float* vb = vert + (size_t)b * NP * 3;

    for (int i = 0; i < NP * 3 / 256; ++i) {
        int e = i * 256 + tid;
        float v = vb[e];
        int row = e / 3, comp = e % 3;
        (comp == 0 ? vx : comp == 1 ? vy : vz)[row] = v;
    }
    __syncthreads();

    const int q = tid >> 3;
    const int sub = tid & 7;
    const float qx = vx[q0 + q], qy = vy[q0 + q], qz = vz[q0 + q];

    float rd[17]; int ri[17];
#pragma unroll
    for (int t = 0; t < 17; ++t) { rd[t] = 3.0e38f; ri[t] = 0x7fffffff; }

    for (int m = 0; m < NP / 64; ++m) {
        const int p0 = m * 64 + sub * 8;
        float4 xA = *(const float4*)&vx[p0], xB = *(const float4*)&vx[p0 + 4];
        float4 yA = *(const float4*)&vy[p0], yB = *(const float4*)&vy[p0 + 4];
        float4 zA = *(const float4*)&vz[p0], zB = *(const float4*)&vz[p0 + 4];
        float dv[8];
        { float dx = qx-xA.x, dy = qy-yA.x, dz = qz-zA.x; dv[0] = dx*dx+dy*dy+dz*dz; }
        { float dx = qx-xA.y, dy = qy-yA.y, dz = qz-zA.y; dv[1] = dx*dx+dy*dy+dz*dz; }
        { float dx = qx-xA.z, dy = qy-yA.z, dz = qz-zA.z; dv[2] = dx*dx+dy*dy+dz*dz; }
        { float dx = qx-xA.w, dy = qy-yA.w, dz = qz-zA.w; dv[3] = dx*dx+dy*dy+dz*dz; }
        { float dx = qx-xB.x, dy = qy-yB.x, dz = qz-zB.x; dv[4] = dx*dx+dy*dy+dz*dz; }
        { float dx = qx-xB.y, dy = qy-yB.y, dz = qz-zB.y; dv[5] = dx*dx+dy*dy+dz*dz; }
        { float dx = qx-xB.z, dy = qy-yB.z, dz = qz-zB.z; dv[6] = dx*dx+dy*dy+dz*dz; }
        { float dx = qx-xB.w, dy = qy-yB.w, dz = qz-zB.w; dv[7] = dx*dx+dy*dy+dz*dz; }
#pragma unroll
        for (int j = 0; j < 8; ++j) {
            const int gi = p0 + j;          // self stays (d=0 -> rank 0, dropped below)
            float d = dv[j];
            if (d < rd[16]) {
#pragma unroll
                for (int t = 16; t > 0; --t) {
                    bool c0 = rd[t - 1] > d;
                    bool c1 = rd[t] > d;
                    float nd = c0 ? rd[t - 1] : (c1 ? d : rd[t]);
                    int   ni = c0 ? ri[t - 1] : (c1 ? gi : ri[t]);
                    rd[t] = nd; ri[t] = ni;
                }
                if (rd[0] > d) { rd[0] = d; ri[0] = gi; }
            }
        }
    }

    // merge 8 lists -> 17 ranks; write ranks 1..16 (drop self)
    {
        float hd = rd[0]; int hi = ri[0];
        int* dst = nbr + ((size_t)b * NP + q0 + q) * KNN;
        for (int it = 0; it < 17; ++it) {
            float m = hd; int mi = hi;
#pragma unroll
            for (int msk = 1; msk <= 4; msk <<= 1) {
                float om = __shfl_xor(m, msk);
                int   omi = __shfl_xor(mi, msk);
                if (om < m || (om == m && omi < mi)) { m = om; mi = omi; }
            }
            if (sub == 0 && it >= 1) dst[it - 1] = mi;
            if (hd == m && hi == mi) {
#pragma unroll
                for (int t = 0; t < 16; ++t) { rd[t] = rd[t + 1]; ri[t] = ri[t + 1]; }
                rd[16] = 3.0e38f; ri[16] = 0x7fffffff;
                hd = rd[0]; hi = ri[0];
            }
        }
    }
}

// ---------- 4: fm = feature_map @ weights + bias ----------
__global__ __launch_bounds__(256) void fm_gemm_kernel(const float* __restrict__ A,
                                                      const float* __restrict__ W,
                                                      const float* __restrict__ bias,
                                                      float* __restrict__ C) {
    __shared__ float As[64][132];
    __shared__ float Bt[64][132];
    const int m0 = blockIdx.x * 64;
    const int n0 = blockIdx.y * 64;
    const int tid = threadIdx.x;
    for (int i = 0; i < 8; ++i) {
        int e = i * 256 + tid;
        int row = e >> 5, c4 = (e & 31) << 2;
        *(float4*)&As[row][c4] = *(const float4*)&A[(size_t)(m0 + row) * CIN + c4];
    }
    for (int i = 0; i < 8; ++i) {
        int e = i * 256 + tid;
        int kk = e >> 4, n4 = (e & 15) << 2;
        float4 w = *(const float4*)&W[(size_t)kk * NC + n0 + n4];
        Bt[n4 + 0][kk] = w.x; Bt[n4 + 1][kk] = w.y;
        Bt[n4 + 2][kk] = w.z; Bt[n4 + 3][kk] = w.w;
    }
    __syncthreads();
    const int tm = tid & 15, tn = tid >> 4;
    float acc[4][4] = {};
    for (int c4 = 0; c4 < CIN; c4 += 4) {
        float4 av[4], bv[4];
#pragma unroll
        for (int a = 0; a < 4; ++a) av[a] = *(const float4*)&As[tm + 16 * a][c4];
#pragma unroll
        for (int bb = 0; bb < 4; ++bb) bv[bb] = *(const float4*)&Bt[tn + 16 * bb][c4];
#pragma unroll
        for (int a = 0; a < 4; ++a)
#pragma unroll
            for (int bb = 0; bb < 4; ++bb)
                acc[a][bb] += av[a].x * bv[bb].x + av[a].y * bv[bb].y
                            + av[a].z * bv[bb].z + av[a].w * bv[bb].w;
    }
#pragma unroll
    for (int a = 0; a < 4; ++a)
#pragma unroll
        for (int bb = 0; bb < 4; ++bb) {
            int m = m0 + tm + 16 * a, n = n0 + tn + 16 * bb;
            C[(size_t)m * NC + n] = acc[a][bb] + bias[n];
        }
}

// ---------- 5: direction-gated support activation + center ----------
__global__ __launch_bounds__(128) void act_kernel(const float* __restrict__ fm,
                                                  const int* __restrict__ nbr,
                                                  const float* __restrict__ vert,
                                                  const float* __restrict__ dirs,
                                                  float* __restrict__ feature) {
    __shared__ int sj[KNN];
    __shared__ float rf[KNN][4];
    const int i = blockIdx.x;
    const int b = blockIdx.y;
    const int tid = threadIdx.x;
    const size_t bi = (size_t)b * NP + i;
    if (tid < KNN) {
        int j = nbr[bi * KNN + tid];
        sj[tid] = j;
        const float* vb = vert + (size_t)b * NP * 3;
        float dx = vb[j * 3 + 0] - vb[i * 3 + 0];
        float dy = vb[j * 3 + 1] - vb[i * 3 + 1];
        float dz = vb[j * 3 + 2] - vb[i * 3 + 2];
        float nrm = sqrtf(dx * dx + dy * dy + dz * dz);
        float den = fmaxf(nrm, 1e-12f);
        rf[tid][0] = dx / den; rf[tid][1] = dy / den; rf[tid][2] = dz / den;
    }
    __syncthreads();
    const int oc = tid;
    float accm = 0.0f;
#pragma unroll
    for (int s = 0; s < NSUP; ++s) {
        int m = s * OC + oc;
        float d0 = dirs[m], d1 = dirs[SC + m], d2 = dirs[2 * SC + m];
        float nrm = sqrtf(d0 * d0 + d1 * d1 + d2 * d2);
        float den = fmaxf(nrm, 1e-12f);
        float s0 = d0 / den, s1 = d1 / den, s2 = d2 / den;
        float vmax = -3.0e38f;
        for (int kk = 0; kk < KNN; ++kk) {
            float th = fmaxf(rf[kk][0] * s0 + rf[kk][1] * s1 + rf[kk][2] * s2, 0.0f);
            float sup = fm[((size_t)b * NP + sj[kk]) * NC + OC + m];
            vmax = fmaxf(vmax, th * sup);
        }
        accm += vmax;
    }
    feature[bi * OC + oc] = fm[bi * NC + oc] + accm / 3.0f;
}

// ---------- 6: neighborhood max-pool over vertex-space KNN ----------
__global__ __launch_bounds__(128) void pool_kernel(const float* __restrict__ feature,
                                                   const int* __restrict__ nbr2,
                                                   float* __restrict__ pooled) {
    __shared__ int sj[KNN];
    const int i = blockIdx.x, b = blockIdx.y, tid = threadIdx.x;
    const size_t bi = (size_t)b * NP + i;
    if (tid < KNN) sj[tid] = nbr2[bi * KNN + tid];
    __syncthreads();
    float mx = -3.0e38f;
    for (int kk = 0; kk < KNN; ++kk)
        mx = fmaxf(mx, feature[((size_t)b * NP + sj[kk]) * OC + tid]);
    pooled[bi * OC + tid] = mx;
}

// ---------- 7: fused mean-over-N + gdot (replaces partial/fglob/gdot) ----------
__global__ __launch_bounds__(128) void global_kernel(const float* __restrict__ pooled,
                                                     const float* __restrict__ conv2,
                                                     float* __restrict__ gd) {
    __shared__ float fgs[OC];
    const int b = blockIdx.x, tid = threadIdx.x;
    float s0 = 0.f, s1 = 0.f, s2 = 0.f, s3 = 0.f;
    const float* base = pooled + (size_t)b * NP * OC + tid;
    for (int i = 0; i < NP; i += 4) {
        s0 += base[(size_t)(i + 0) * OC];
        s1 += base[(size_t)(i + 1) * OC];
        s2 += base[(size_t)(i + 2) * OC];
        s3 += base[(size_t)(i + 3) * OC];
    }
    fgs[tid] = ((s0 + s1) + (s2 + s3)) / (float)NP;
    __syncthreads();
    float g = 0.f;
    const float* w = conv2 + (size_t)tid * 2 * OC + OC;   // cT[(OC+c)*OC+o] == conv2[o*2OC+OC+c]
    for (int c = 0; c < OC; ++c) g += fgs[c] * w[c];
    gd[b * OC + tid] = g;
}

// ---------- 9: transpose weights for coalesced final GEMM ----------
__global__ __launch_bounds__(256) void transpose_kernel(const float* __restrict__ conv2,
                                                        const float* __restrict__ stew,
                                                        float* __restrict__ cT,
                                                        float* __restrict__ sT) {
    int idx = blockIdx.x * 256 + threadIdx.x;
    if (idx < OC * 2 * OC) {
        int o = idx >> 8, c = idx & 255;
        cT[c * OC + o] = conv2[idx];
    } else {
        int e = idx - OC * 2 * OC;
        int o = e >> 7, c = e & 127;
        sT[c * OC + o] = stew[e];
    }
}

// ---------- 11: fused conv2 + residual + ste ----------
__global__ __launch_bounds__(256) void final_kernel(const float* __restrict__ feature,
                                                    const float* __restrict__ fmap,
                                                    const float* __restrict__ cT,
                                                    const float* __restrict__ sT,
                                                    const float* __restrict__ gd,
                                                    float* __restrict__ out) {
    __shared__ float featL[8][128];
    __shared__ float fmapL[8][128];
    const int gp = blockIdx.x;
    const int b = gp >> 8;
    const int i0 = (gp & 255) * 8;
    const int tid = threadIdx.x;
    const size_t base = ((size_t)b * NP + i0) * OC;
    for (int e = tid; e < 8 * 128; e += 256) {
        featL[e >> 7][e & 127] = feature[base + e];
        fmapL[e >> 7][e & 127] = fmap[base + e];
    }
    __syncthreads();
    const int o = tid & 127;
    const int half = tid >> 7;
    float acc[4] = {};
    for (int c = 0; c < OC; ++c) {
        float w1 = cT[c * OC + o];
#pragma unroll
        for (int j = 0; j < 4; ++j) acc[j] += featL[half * 4 + j][c] * w1;
    }
    for (int c = 0; c < OC; ++c) {
        float w2 = sT[c * OC + o];
#pragma unroll
        for (int j = 0; j < 4; ++j) acc[j] += fmapL[half * 4 + j][c] * w2;
    }
    float g = gd[b * OC + o];
#pragma unroll
    for (int j = 0; j < 4; ++j) {
        int p = half * 4 + j;
        out[base + p * OC + o] = acc[j] + g + featL[p][o];
    }
}

extern "C" void kernel_launch(void* const* d_in, const int* in_sizes, int n_in,
                              void* d_out, int out_size, void* d_ws, size_t ws_size,
                              hipStream_t stream) {
    const float* vert  = (const float*)d_in[0];
    const float* fmap  = (const float*)d_in[1];
    const float* W     = (const float*)d_in[2];
    const float* bias  = (const float*)d_in[3];
    const float* dirs  = (const float*)d_in[4];
    const float* stew  = (const float*)d_in[5];
    const float* conv2 = (const float*)d_in[6];
    float* out = (float*)d_out;

    float* ws      = (float*)d_ws;
    float* sqn     = ws;                  // 16384
    float* C1      = sqn + 16384;         // 8*2048*512
    float* feature = C1 + 8388608;        // 8*2048*128
    float* pooled  = feature + 2097152;   // 8*2048*128
    float* part    = pooled + 2097152;    // (unused, layout kept)
    float* fg      = part + 16384;
    float* gd      = fg + 1024;           // 8*128
    float* cT      = gd + 1024;           // 256*128
    float* sT      = cT + 32768;          // 128*128
    int*   nbr1    = (int*)(sT + 16384);  // 8*2048*16
    int*   nbr2    = nbr1 + 262144;       // 8*2048*16
    int*   cand    = nbr2 + 262144;       // 8*2048*24
    // fbb aliases 'pooled': dead before pool_kernel writes pooled.
    short* fbb     = (short*)pooled;      // 8*2048*128 bf16

    sqbf_kernel<<<1024, 256, 0, stream>>>(fmap, sqn, fbb);
    knn_feat_kernel<<<dim3(64, 8), 256, 0, stream>>>(fbb, sqn, cand);
    knn_refine_kernel<<<4096, 256, 0, stream>>>(fmap, cand, nbr1);
    knn_vert_kernel<<<dim3(64, 8), 256, 0, stream>>>(vert, nbr2);
    fm_gemm_kernel<<<dim3(256, 8), 256, 0, stream>>>(fmap, W, bias, C1);
    act_kernel<<<dim3(2048, 8), 128, 0, stream>>>(C1, nbr1, vert, dirs, feature);
    pool_kernel<<<dim3(2048, 8), 128, 0, stream>>>(feature, nbr2, pooled);
    global_kernel<<<8, 128, 0, stream>>>(pooled, conv2, gd);
    transpose_kernel<<<192, 256, 0, stream>>>(conv2, stew, cT, sT);
    final_kernel<<<2048, 256, 0, stream>>>(feature, fmap, cT, sT, gd, out);
}

// Round 8
// 385.208 us; speedup vs baseline: 3.9981x; 2.0966x over previous
//
#include <hip/hip_runtime.h>
#include <hip/hip_bf16.h>

#define BS 8
#define NP 2048
#define CIN 128
#define OC 128
#define NSUP 3
#define KNN 16
#define NC 512   // (NSUP+1)*OC
#define SC 384   // NSUP*OC
#define CAND 24  // pass-1 candidate depth; key-quant err ~0.012 << rank margin ~4

typedef __attribute__((ext_vector_type(8))) short bf16x8;
typedef __attribute__((ext_vector_type(4))) float f32x4;

__device__ inline unsigned short f2bf(float x) {
    __hip_bfloat16 h = __float2bfloat16(x);
    return *reinterpret_cast<unsigned short*>(&h);
}
// sortable key: float order-preserving bits, low 11 bits replaced by point index
__device__ inline unsigned fkey(float d, int gi) {
    unsigned u = __float_as_uint(d);
    u ^= (unsigned)((int)u >> 31) | 0x80000000u;
    return (u & 0xFFFFF800u) | (unsigned)gi;
}
__device__ inline unsigned umn(unsigned a, unsigned b) { return a < b ? a : b; }
__device__ inline unsigned umx(unsigned a, unsigned b) { return a > b ? a : b; }

// ---------- 1: fused squared-norms + fp32->bf16 copy ----------
__global__ __launch_bounds__(256) void sqbf_kernel(const float* __restrict__ in,
                                                   float* __restrict__ sq,
                                                   short* __restrict__ outp) {
    const int tid = threadIdx.x;
    const int row = blockIdx.x * 16 + (tid >> 4);
    const int seg = tid & 15;
    const float* p = in + (size_t)row * CIN + seg * 8;
    float4 f0 = *(const float4*)p;
    float4 f1 = *(const float4*)(p + 4);
    bf16x8 s;
    s[0] = (short)f2bf(f0.x); s[1] = (short)f2bf(f0.y);
    s[2] = (short)f2bf(f0.z); s[3] = (short)f2bf(f0.w);
    s[4] = (short)f2bf(f1.x); s[5] = (short)f2bf(f1.y);
    s[6] = (short)f2bf(f1.z); s[7] = (short)f2bf(f1.w);
    *(bf16x8*)&outp[(size_t)row * CIN + seg * 8] = s;
    float ss = f0.x*f0.x + f0.y*f0.y + f0.z*f0.z + f0.w*f0.w
             + f1.x*f1.x + f1.y*f1.y + f1.z*f1.z + f1.w*f1.w;
#pragma unroll
    for (int msk = 1; msk <= 8; msk <<= 1) ss += __shfl_xor(ss, msk);
    if (seg == 0) sq[row] = ss;
}

// ---------- 1b: weight prep — Wt[n][k], conv2b, stewb in bf16 ----------
__global__ __launch_bounds__(256) void wprep_kernel(const float* __restrict__ W,
                                                    const float* __restrict__ conv2,
                                                    const float* __restrict__ stew,
                                                    short* __restrict__ Wt,
                                                    short* __restrict__ conv2b,
                                                    short* __restrict__ stewb) {
    int idx = blockIdx.x * 256 + threadIdx.x;      // 448 blocks
    if (idx < NC * CIN) {
        int n = idx >> 7, k = idx & 127;
        Wt[idx] = (short)f2bf(W[(size_t)k * NC + n]);
    } else if (idx < NC * CIN + OC * 2 * OC) {
        int e = idx - NC * CIN;
        conv2b[e] = (short)f2bf(conv2[e]);
    } else {
        int e = idx - NC * CIN - OC * 2 * OC;
        stewb[e] = (short)f2bf(stew[e]);
    }
}

// ---------- 2: feature KNN pass 1 — MFMA Gram + packed-key register top-24 ----------
#define TQF 32
#define TPF 64
__global__ __launch_bounds__(256) void knn_feat_kernel(const short* __restrict__ fbb,
                                                       const float* __restrict__ sqn,
                                                       int* __restrict__ cand) {
    __shared__ alignas(16) short Qb[TQF][128];
    __shared__ alignas(16) short Pb[TPF][128];     // single buffer (writes after (B))
    __shared__ float sqP[TPF];
    __shared__ unsigned Ds[TQF][68];               // packed keys

    const int b = blockIdx.y, q0 = blockIdx.x * TQF, tid = threadIdx.x;
    const int lane = tid & 63, wid = tid >> 6;
    const short* fb = fbb + (size_t)b * NP * CIN;

    unsigned rk[CAND];
#pragma unroll
    for (int t = 0; t < CAND; ++t) rk[t] = 0xFFFFFFFFu;

    for (int i = 0; i < 2; ++i) {                  // Q tile (swizzled)
        int v = i * 256 + tid, row = v >> 4, g = v & 15;
        *(bf16x8*)&Qb[row][(g ^ (row & 7)) * 8] =
            *(const bf16x8*)&fb[(size_t)(q0 + row) * CIN + g * 8];
    }
    for (int i = 0; i < 4; ++i) {                  // P chunk 0
        int v = i * 256 + tid, row = v >> 4, g = v & 15;
        *(bf16x8*)&Pb[row][(g ^ (row & 7)) * 8] =
            *(const bf16x8*)&fb[(size_t)row * CIN + g * 8];
    }
    if (tid < TPF) sqP[tid] = sqn[b * NP + tid];

    const int qt = wid >> 1, ph = wid & 1;
    const int qsl = tid >> 3, sub = tid & 7;
    const int arow = qt * 16 + (lane & 15), asw = arow & 7;
    const int brow0 = ph * 32 + (lane & 15), brow1 = brow0 + 16;
    const int bsw0 = brow0 & 7, bsw1 = brow1 & 7;
    const int oct = lane >> 4;
    const int qrow = qt * 16 + oct * 4;

    for (int ch = 0; ch < NP / TPF; ++ch) {
        __syncthreads();                           // (A) Pb ready; prev scans done
        bf16x8 st0, st1, st2, st3;
        float sq_next = 0.f;
        const int nxt = (ch + 1 < NP / TPF);
        if (nxt) {                                 // reg-stage next chunk
            int p0n = (ch + 1) * TPF;
            { int v = tid;       int row = v>>4, g = v&15; st0 = *(const bf16x8*)&fb[(size_t)(p0n+row)*CIN + g*8]; }
            { int v = 256 + tid; int row = v>>4, g = v&15; st1 = *(const bf16x8*)&fb[(size_t)(p0n+row)*CIN + g*8]; }
            { int v = 512 + tid; int row = v>>4, g = v&15; st2 = *(const bf16x8*)&fb[(size_t)(p0n+row)*CIN + g*8]; }
            { int v = 768 + tid; int row = v>>4, g = v&15; st3 = *(const bf16x8*)&fb[(size_t)(p0n+row)*CIN + g*8]; }
            if (tid < TPF) sq_next = sqn[b * NP + p0n + tid];
        }
        f32x4 acc0 = {0.f,0.f,0.f,0.f}, acc1 = {0.f,0.f,0.f,0.f};
#pragma unroll
        for (int kk = 0; kk < 4; ++kk) {
            int g = kk * 4 + oct;
            bf16x8 av  = *(const bf16x8*)&Qb[arow][(g ^ asw) * 8];
            bf16x8 bv0 = *(const bf16x8*)&Pb[brow0][(g ^ bsw0) * 8];
            bf16x8 bv1 = *(const bf16x8*)&Pb[brow1][(g ^ bsw1) * 8];
            acc0 = __builtin_amdgcn_mfma_f32_16x16x32_bf16(av, bv0, acc0, 0, 0, 0);
            acc1 = __builtin_amdgcn_mfma_f32_16x16x32_bf16(av, bv1, acc1, 0, 0, 0);
        }
        const float sp0 = sqP[brow0], sp1 = sqP[brow1];
        const int pg0 = ch * TPF + brow0, pg1 = ch * TPF + brow1;
#pragma unroll
        for (int r = 0; r < 4; ++r) {
            int qg = q0 + qrow + r;
            unsigned k0 = fkey(sp0 - 2.0f * acc0[r], pg0);
            unsigned k1 = fkey(sp1 - 2.0f * acc1[r], pg1);
            if (qg == pg0) k0 = 0xFFFFFFFFu;       // self excluded
            if (qg == pg1) k1 = 0xFFFFFFFFu;
            Ds[qrow + r][brow0] = k0;
            Ds[qrow + r][brow1] = k1;
        }
        __syncthreads();                           // (B) Ds ready; Pb consumed
        {
            uint4 kA = *(const uint4*)&Ds[qsl][sub * 8];
            uint4 kB = *(const uint4*)&Ds[qsl][sub * 8 + 4];
            unsigned kv[8] = {kA.x, kA.y, kA.z, kA.w, kB.x, kB.y, kB.z, kB.w};
#pragma unroll
            for (int j = 0; j < 8; ++j) {
                unsigned k = kv[j];
                if (k < rk[CAND - 1]) {            // med3-style 2-inst shift steps
#pragma unroll
                    for (int t = CAND - 1; t > 0; --t)
                        rk[t] = umn(umx(rk[t - 1], k), rk[t]);
                    rk[0] = umn(rk[0], k);
                }
            }
        }
        if (nxt) {                                 // write staged chunk (Pb free)
            { int v = tid;       int row = v>>4, g = v&15; *(bf16x8*)&Pb[row][(g^(row&7))*8] = st0; }
            { int v = 256 + tid; int row = v>>4, g = v&15; *(bf16x8*)&Pb[row][(g^(row&7))*8] = st1; }
            { int v = 512 + tid; int row = v>>4, g = v&15; *(bf16x8*)&Pb[row][(g^(row&7))*8] = st2; }
            { int v = 768 + tid; int row = v>>4, g = v&15; *(bf16x8*)&Pb[row][(g^(row&7))*8] = st3; }
            if (tid < TPF) sqP[tid] = sq_next;
        }
    }

    // merge 8 sorted key-lists per query -> top-CAND (keys unique: index embedded)
    {
        unsigned hk = rk[0];
        int* dst = cand + ((size_t)b * NP + q0 + qsl) * CAND;
        for (int it = 0; it < CAND; ++it) {
            unsigned mk = hk;
#pragma unroll
            for (int msk = 1; msk <= 4; msk <<= 1)
                mk = umn(mk, (unsigned)__shfl_xor((int)mk, msk));
            if (sub == 0) dst[it] = (int)(mk & 0x7FFu);
            if (hk == mk) {                        // owner pops
#pragma unroll
                for (int t = 0; t < CAND - 1; ++t) rk[t] = rk[t + 1];
                rk[CAND - 1] = 0xFFFFFFFFu;
                hk = rk[0];
            }
        }
    }
}

// ---------- 2b: refine 24 candidates -> top-16 under REFERENCE fp32 rounding ----------
// (byte-identical logic since round 4 — this made the test pass; do not touch)
__global__ __launch_bounds__(256) void knn_refine_kernel(const float* __restrict__ feat,
                                                         const int* __restrict__ cand,
                                                         int* __restrict__ nbr) {
    __shared__ float lds_d[4][KNN];
    __shared__ int   lds_i[4][KNN];
    const int w = threadIdx.x >> 6;
    const int lane = threadIdx.x & 63;
    const int gq = blockIdx.x * 4 + w;
    const int b = gq >> 11;
    const int q = gq & (NP - 1);
    const float* fb = feat + (size_t)b * NP * CIN;

    double q0 = (double)fb[(size_t)q * CIN + lane];
    double q1 = (double)fb[(size_t)q * CIN + lane + 64];
    double sqd = q0 * q0 + q1 * q1;
    for (int off = 32; off > 0; off >>= 1) sqd += __shfl_down(sqd, off);
    sqd = __shfl(sqd, 0);
    const float sqi = (float)sqd;

    if (lane == 0)
        for (int t = 0; t < KNN; ++t) { lds_d[w][t] = 3.0e38f; lds_i[w][t] = 0x7fffffff; }

    for (int t = 0; t < CAND; ++t) {
        int j = cand[(size_t)gq * CAND + t];
        double f0 = (double)fb[(size_t)j * CIN + lane];
        double f1 = (double)fb[(size_t)j * CIN + lane + 64];
        double dot = q0 * f0 + q1 * f1;
        double sj  = f0 * f0 + f1 * f1;
        for (int off = 32; off > 0; off >>= 1) {
            dot += __shfl_down(dot, off);
            sj  += __shfl_down(sj, off);
        }
        if (lane == 0) {
            float t1 = sqi + (float)sj;
            float t2 = (float)(2.0 * dot);
            float d32 = t1 - t2;
            float wd = lds_d[w][KNN - 1]; int wi = lds_i[w][KNN - 1];
            if (d32 < wd || (d32 == wd && j < wi)) {
                int pos = KNN - 1;
                while (pos > 0 && (lds_d[w][pos - 1] > d32 ||
                                   (lds_d[w][pos - 1] == d32 && lds_i[w][pos - 1] > j))) {
                    lds_d[w][pos] = lds_d[w][pos - 1];
                    lds_i[w][pos] = lds_i[w][pos - 1];
                    --pos;
                }
                lds_d[w][pos] = d32;
                lds_i[w][pos] = j;
            }
        }
    }
    if (lane == 0) {
        int* dst = nbr + (size_t)gq * KNN;
        for (int t = 0; t < KNN; ++t) dst[t] = lds_i[w][t];
    }
}

// ---------- 3: vertex KNN — packed-key register top-17 ----------
#define TQV 32
__global__ __launch_bounds__(256) void knn_vert_kernel(const float* __restrict__ vert,
                                                       int* __restrict__ nbr) {
    __shared__ alignas(16) float vx[NP], vy[NP], vz[NP];
    const int b = blockIdx.y;
    const int q0 = blockIdx.x * TQV;
    const int tid = threadIdx.x;
    const float* vb = vert + (size_t)b * NP * 3;

    for (int i = 0; i < NP * 3 / 256; ++i) {
        int e = i * 256 + tid;
        float v = vb[e];
        int row = e / 3, comp = e % 3;
        (comp == 0 ? vx : comp == 1 ? vy : vz)[row] = v;
    }
    __syncthreads();

    const int q = tid >> 3;
    const int sub = tid & 7;
    const float qx = vx[q0 + q], qy = vy[q0 + q], qz = vz[q0 + q];

    unsigned rk[17];
#pragma unroll
    for (int t = 0; t < 17; ++t) rk[t] = 0xFFFFFFFFu;

    for (int m = 0; m < NP / 64; ++m) {
        const int p0 = m * 64 + sub * 8;
        float4 xA = *(const float4*)&vx[p0], xB = *(const float4*)&vx[p0 + 4];
        float4 yA = *(const float4*)&vy[p0], yB = *(const float4*)&vy[p0 + 4];
        float4 zA = *(const float4*)&vz[p0], zB = *(const float4*)&vz[p0 + 4];
        float dv[8];
        { float dx = qx-xA.x, dy = qy-yA.x, dz = qz-zA.x; dv[0] = dx*dx+dy*dy+dz*dz; }
        { float dx = qx-xA.y, dy = qy-yA.y, dz = qz-zA.y; dv[1] = dx*dx+dy*dy+dz*dz; }
        { float dx = qx-xA.z, dy = qy-yA.z, dz = qz-zA.z; dv[2] = dx*dx+dy*dy+dz*dz; }
        { float dx = qx-xA.w, dy = qy-yA.w, dz = qz-zA.w; dv[3] = dx*dx+dy*dy+dz*dz; }
        { float dx = qx-xB.x, dy = qy-yB.x, dz = qz-zB.x; dv[4] = dx*dx+dy*dy+dz*dz; }
        { float dx = qx-xB.y, dy = qy-yB.y, dz = qz-zB.y; dv[5] = dx*dx+dy*dy+dz*dz; }
        { float dx = qx-xB.z, dy = qy-yB.z, dz = qz-zB.z; dv[6] = dx*dx+dy*dy+dz*dz; }
        { float dx = qx-xB.w, dy = qy-yB.w, dz = qz-zB.w; dv[7] = dx*dx+dy*dy+dz*dz; }
#pragma unroll
        for (int j = 0; j < 8; ++j) {
            unsigned k = fkey(dv[j], p0 + j);      // self d=0 -> rank 0, dropped at merge
            if (k < rk[16]) {
#pragma unroll
                for (int t = 16; t > 0; --t) rk[t] = umn(umx(rk[t - 1], k), rk[t]);
                rk[0] = umn(rk[0], k);
            }
        }
    }
    {
        unsigned hk = rk[0];
        int* dst = nbr + ((size_t)b * NP + q0 + q) * KNN;
        for (int it = 0; it < 17; ++it) {
            unsigned mk = hk;
#pragma unroll
            for (int msk = 1; msk <= 4; msk <<= 1)
                mk = umn(mk, (unsigned)__shfl_xor((int)mk, msk));
            if (sub == 0 && it >= 1) dst[it - 1] = (int)(mk & 0x7FFu);
            if (hk == mk) {
#pragma unroll
                for (int t = 0; t < 16; ++t) rk[t] = rk[t + 1];
                rk[16] = 0xFFFFFFFFu;
                hk = rk[0];
            }
        }
    }
}

// ---------- 4: fm = fmap @ W + bias — bf16 MFMA (fp32 acc) ----------
__global__ __launch_bounds__(256) void fm_gemm_kernel(const short* __restrict__ fbb,
                                                      const short* __restrict__ Wt,
                                                      const float* __restrict__ bias,
                                                      float* __restrict__ C) {
    __shared__ alignas(16) short As[64][128];
    const int m0 = blockIdx.x * 64, n0 = blockIdx.y * 128, tid = threadIdx.x;
    const int lane = tid & 63, wid = tid >> 6, oct = lane >> 4;
    for (int i = 0; i < 4; ++i) {
        int v = i * 256 + tid, row = v >> 4, g = v & 15;
        *(bf16x8*)&As[row][(g ^ (row & 7)) * 8] =
            *(const bf16x8*)&fbb[(size_t)(m0 + row) * CIN + g * 8];
    }
    __syncthreads();
    f32x4 acc[4][2] = {};
#pragma unroll
    for (int kk = 0; kk < 4; ++kk) {
        int g = kk * 4 + oct;
        bf16x8 bv[2];
#pragma unroll
        for (int nt = 0; nt < 2; ++nt) {
            int n = n0 + (wid * 2 + nt) * 16 + (lane & 15);
            bv[nt] = *(const bf16x8*)&Wt[(size_t)n * CIN + g * 8];
        }
#pragma unroll
        for (int mt = 0; mt < 4; ++mt) {
            int ar = mt * 16 + (lane & 15);
            bf16x8 av = *(const bf16x8*)&As[ar][(g ^ (ar & 7)) * 8];
#pragma unroll
            for (int nt = 0; nt < 2; ++nt)
                acc[mt][nt] = __builtin_amdgcn_mfma_f32_16x16x32_bf16(av, bv[nt], acc[mt][nt], 0, 0, 0);
        }
    }
#pragma unroll
    for (int mt = 0; mt < 4; ++mt)
#pragma unroll
        for (int nt = 0; nt < 2; ++nt) {
            int n = n0 + (wid * 2 + nt) * 16 + (lane & 15);
            float bsv = bias[n];
            int mbase = m0 + mt * 16 + oct * 4;
#pragma unroll
            for (int r = 0; r < 4; ++r)
                C[(size_t)(mbase + r) * NC + n] = acc[mt][nt][r] + bsv;
        }
}

// ---------- 5: direction-gated support activation + center (+ bf16 copy) ----------
__global__ __launch_bounds__(128) void act_kernel(const float* __restrict__ fm,
                                                  const int* __restrict__ nbr,
                                                  const float* __restrict__ vert,
                                                  const float* __restrict__ dirs,
                                                  float* __restrict__ feature,
                                                  short* __restrict__ featb) {
    __shared__ int sj[KNN];
    __shared__ float rf[KNN][4];
    const int i = blockIdx.x;
    const int b = blockIdx.y;
    const int tid = threadIdx.x;
    const size_t bi = (size_t)b * NP + i;
    if (tid < KNN) {
        int j = nbr[bi * KNN + tid];
        sj[tid] = j;
        const float* vb = vert + (size_t)b * NP * 3;
        float dx = vb[j * 3 + 0] - vb[i * 3 + 0];
        float dy = vb[j * 3 + 1] - vb[i * 3 + 1];
        float dz = vb[j * 3 + 2] - vb[i * 3 + 2];
        float nrm = sqrtf(dx * dx + dy * dy + dz * dz);
        float den = fmaxf(nrm, 1e-12f);
        rf[tid][0] = dx / den; rf[tid][1] = dy / den; rf[tid][2] = dz / den;
    }
    __syncthreads();
    const int oc = tid;
    float accm = 0.0f;
#pragma unroll
    for (int s = 0; s < NSUP; ++s) {
        int m = s * OC + oc;
        float d0 = dirs[m], d1 = dirs[SC + m], d2 = dirs[2 * SC + m];
        float nrm = sqrtf(d0 * d0 + d1 * d1 + d2 * d2);
        float den = fmaxf(nrm, 1e-12f);
        float s0 = d0 / den, s1 = d1 / den, s2 = d2 / den;
        float vmax = -3.0e38f;
        for (int kk = 0; kk < KNN; ++kk) {
            float th = fmaxf(rf[kk][0] * s0 + rf[kk][1] * s1 + rf[kk][2] * s2, 0.0f);
            float sup = fm[((size_t)b * NP + sj[kk]) * NC + OC + m];
            vmax = fmaxf(vmax, th * sup);
        }
        accm += vmax;
    }
    float v = fm[bi * NC + oc] + accm / 3.0f;
    feature[bi * OC + oc] = v;
    featb[bi * OC + oc] = (short)f2bf(v);
}

// ---------- 6: neighborhood max-pool over vertex-space KNN ----------
__global__ __launch_bounds__(128) void pool_kernel(const float* __restrict__ feature,
                                                   const int* __restrict__ nbr2,
                                                   float* __restrict__ pooled) {
    __shared__ int sj[KNN];
    const int i = blockIdx.x, b = blockIdx.y, tid = threadIdx.x;
    const size_t bi = (size_t)b * NP + i;
    if (tid < KNN) sj[tid] = nbr2[bi * KNN + tid];
    __syncthreads();
    float mx = -3.0e38f;
    for (int kk = 0; kk < KNN; ++kk)
        mx = fmaxf(mx, feature[((size_t)b * NP + sj[kk]) * OC + tid]);
    pooled[bi * OC + tid] = mx;
}

// ---------- 7: fused mean-over-N + gdot ----------
__global__ __launch_bounds__(128) void global_kernel(const float* __restrict__ pooled,
                                                     const float* __restrict__ conv2,
                                                     float* __restrict__ gd) {
    __shared__ float fgs[OC];
    const int b = blockIdx.x, tid = threadIdx.x;
    float s0 = 0.f, s1 = 0.f, s2 = 0.f, s3 = 0.f;
    const float* base = pooled + (size_t)b * NP * OC + tid;
    for (int i = 0; i < NP; i += 4) {
        s0 += base[(size_t)(i + 0) * OC];
        s1 += base[(size_t)(i + 1) * OC];
        s2 += base[(size_t)(i + 2) * OC];
        s3 += base[(size_t)(i + 3) * OC];
    }
    fgs[tid] = ((s0 + s1) + (s2 + s3)) / (float)NP;
    __syncthreads();
    float g = 0.f;
    const float* w = conv2 + (size_t)tid * 2 * OC + OC;
    for (int c = 0; c < OC; ++c) g += fgs[c] * w[c];
    gd[b * OC + tid] = g;
}

// ---------- 8: final — bf16 MFMA conv2(feat) + ste(fmap) + gd + residual ----------
__global__ __launch_bounds__(256) void final_kernel(const short* __restrict__ featb,
                                                    const short* __restrict__ fbb,
                                                    const short* __restrict__ conv2b,
                                                    const short* __restrict__ stewb,
                                                    const float* __restrict__ gd,
                                                    const float* __restrict__ feature,
                                                    float* __restrict__ out) {
    __shared__ alignas(16) short Af[32][128];
    __shared__ alignas(16) short Am[32][128];
    const int m0 = blockIdx.x * 32, tid = threadIdx.x;
    const int lane = tid & 63, wid = tid >> 6, oct = lane >> 4;
    for (int i = 0; i < 2; ++i) {
        int v = i * 256 + tid, row = v >> 4, g = v & 15;
        *(bf16x8*)&Af[row][(g ^ (row & 7)) * 8] =
            *(const bf16x8*)&featb[(size_t)(m0 + row) * OC + g * 8];
        *(bf16x8*)&Am[row][(g ^ (row & 7)) * 8] =
            *(const bf16x8*)&fbb[(size_t)(m0 + row) * CIN + g * 8];
    }
    __syncthreads();
    f32x4 acc[2][2] = {};
#pragma unroll
    for (int kk = 0; kk < 4; ++kk) {
        int g = kk * 4 + oct;
        bf16x8 bC[2], bS[2];
#pragma unroll
        for (int nt = 0; nt < 2; ++nt) {
            int n = (wid * 2 + nt) * 16 + (lane & 15);
            bC[nt] = *(const bf16x8*)&conv2b[(size_t)n * (2 * OC) + g * 8];
            bS[nt] = *(const bf16x8*)&stewb[(size_t)n * CIN + g * 8];
        }
#pragma unroll
        for (int mt = 0; mt < 2; ++mt) {
            int ar = mt * 16 + (lane & 15);
            bf16x8 aF = *(const bf16x8*)&Af[ar][(g ^ (ar & 7)) * 8];
            bf16x8 aM = *(const bf16x8*)&Am[ar][(g ^ (ar & 7)) * 8];
#pragma unroll
            for (int nt = 0; nt < 2; ++nt) {
                acc[mt][nt] = __builtin_amdgcn_mfma_f32_16x16x32_bf16(aF, bC[nt], acc[mt][nt], 0, 0, 0);
                acc[mt][nt] = __builtin_amdgcn_mfma_f32_16x16x32_bf16(aM, bS[nt], acc[mt][nt], 0, 0, 0);
            }
        }
    }
#pragma unroll
    for (int mt = 0; mt < 2; ++mt)
#pragma unroll
        for (int nt = 0; nt < 2; ++nt) {
            int o = (wid * 2 + nt) * 16 + (lane & 15);
            int mbase = m0 + mt * 16 + oct * 4;
#pragma unroll
            for (int r = 0; r < 4; ++r) {
                int m = mbase + r;
                out[(size_t)m * OC + o] = acc[mt][nt][r]
                    + gd[(m >> 11) * OC + o] + feature[(size_t)m * OC + o];
            }
        }
}

extern "C" void kernel_launch(void* const* d_in, const int* in_sizes, int n_in,
                              void* d_out, int out_size, void* d_ws, size_t ws_size,
                              hipStream_t stream) {
    const float* vert  = (const float*)d_in[0];
    const float* fmap  = (const float*)d_in[1];
    const float* W     = (const float*)d_in[2];
    const float* bias  = (const float*)d_in[3];
    const float* dirs  = (const float*)d_in[4];
    const float* stew  = (const float*)d_in[5];
    const float* conv2 = (const float*)d_in[6];
    float* out = (float*)d_out;

    float* ws      = (float*)d_ws;
    float* sqn     = ws;                            // 16384
    short* fbb     = (short*)(sqn + 16384);         // 2M shorts (1M floats)
    float* C1      = sqn + 16384 + 1048576;         // 8.4M
    float* feature = C1 + 8388608;                  // 2M
    short* featb   = (short*)(feature + 2097152);   // 2M shorts (1M floats)
    float* gd      = feature + 2097152 + 1048576;   // 1024
    short* Wt      = (short*)(gd + 1024);           // 65536 shorts (32768 f)
    short* conv2b  = Wt + 65536;                    // 32768 shorts (16384 f)
    short* stewb   = conv2b + 32768;                // 16384 shorts (8192 f)
    int*   nbr1    = (int*)(stewb + 16384);         // 262144
    int*   nbr2    = nbr1 + 262144;                 // 262144
    int*   cand    = (int*)C1;                      // alias: dead before fm_gemm writes C1
    float* pooled  = C1;                            // alias: C1 dead after act

    sqbf_kernel<<<1024, 256, 0, stream>>>(fmap, sqn, fbb);
    wprep_kernel<<<448, 256, 0, stream>>>(W, conv2, stew, Wt, conv2b, stewb);
    knn_feat_kernel<<<dim3(64, 8), 256, 0, stream>>>(fbb, sqn, cand);
    knn_refine_kernel<<<4096, 256, 0, stream>>>(fmap, cand, nbr1);
    knn_vert_kernel<<<dim3(64, 8), 256, 0, stream>>>(vert, nbr2);
    fm_gemm_kernel<<<dim3(256, 4), 256, 0, stream>>>(fbb, Wt, bias, C1);
    act_kernel<<<dim3(2048, 8), 128, 0, stream>>>(C1, nbr1, vert, dirs, feature, featb);
    pool_kernel<<<dim3(2048, 8), 128, 0, stream>>>(feature, nbr2, pooled);
    global_kernel<<<8, 128, 0, stream>>>(pooled, conv2, gd);
    final_kernel<<<512, 256, 0, stream>>>(featb, fbb, conv2b, stewb, gd, feature, out);
}

// Round 9
// 257.727 us; speedup vs baseline: 5.9757x; 1.4946x over previous
//
#include <hip/hip_runtime.h>
#include <hip/hip_bf16.h>

#define BS 8
#define NP 2048
#define CIN 128
#define OC 128
#define NSUP 3
#define KNN 16
#define NC 512   // (NSUP+1)*OC
#define SC 384   // NSUP*OC
#define CAND 24  // pass-1 candidate depth; key-quant err ~0.012 << rank margin ~4

typedef __attribute__((ext_vector_type(8))) short bf16x8;
typedef __attribute__((ext_vector_type(4))) float f32x4;

__device__ inline unsigned short f2bf(float x) {
    __hip_bfloat16 h = __float2bfloat16(x);
    return *reinterpret_cast<unsigned short*>(&h);
}
// sortable key: float order-preserving bits, low 11 bits replaced by point index
__device__ inline unsigned fkey(float d, int gi) {
    unsigned u = __float_as_uint(d);
    u ^= (unsigned)((int)u >> 31) | 0x80000000u;
    return (u & 0xFFFFF800u) | (unsigned)gi;
}
__device__ inline unsigned umn(unsigned a, unsigned b) { return a < b ? a : b; }
__device__ inline unsigned umx(unsigned a, unsigned b) { return a > b ? a : b; }

// ---------- 1: fused squared-norms + fp32->bf16 copy ----------
__global__ __launch_bounds__(256) void sqbf_kernel(const float* __restrict__ in,
                                                   float* __restrict__ sq,
                                                   short* __restrict__ outp) {
    const int tid = threadIdx.x;
    const int row = blockIdx.x * 16 + (tid >> 4);
    const int seg = tid & 15;
    const float* p = in + (size_t)row * CIN + seg * 8;
    float4 f0 = *(const float4*)p;
    float4 f1 = *(const float4*)(p + 4);
    bf16x8 s;
    s[0] = (short)f2bf(f0.x); s[1] = (short)f2bf(f0.y);
    s[2] = (short)f2bf(f0.z); s[3] = (short)f2bf(f0.w);
    s[4] = (short)f2bf(f1.x); s[5] = (short)f2bf(f1.y);
    s[6] = (short)f2bf(f1.z); s[7] = (short)f2bf(f1.w);
    *(bf16x8*)&outp[(size_t)row * CIN + seg * 8] = s;
    float ss = f0.x*f0.x + f0.y*f0.y + f0.z*f0.z + f0.w*f0.w
             + f1.x*f1.x + f1.y*f1.y + f1.z*f1.z + f1.w*f1.w;
#pragma unroll
    for (int msk = 1; msk <= 8; msk <<= 1) ss += __shfl_xor(ss, msk);
    if (seg == 0) sq[row] = ss;
}

// ---------- 1b: weight prep — Wt[n][k], conv2b, stewb in bf16 ----------
__global__ __launch_bounds__(256) void wprep_kernel(const float* __restrict__ W,
                                                    const float* __restrict__ conv2,
                                                    const float* __restrict__ stew,
                                                    short* __restrict__ Wt,
                                                    short* __restrict__ conv2b,
                                                    short* __restrict__ stewb) {
    int idx = blockIdx.x * 256 + threadIdx.x;      // 448 blocks
    if (idx < NC * CIN) {
        int n = idx >> 7, k = idx & 127;
        Wt[idx] = (short)f2bf(W[(size_t)k * NC + n]);
    } else if (idx < NC * CIN + OC * 2 * OC) {
        int e = idx - NC * CIN;
        conv2b[e] = (short)f2bf(conv2[e]);
    } else {
        int e = idx - NC * CIN - OC * 2 * OC;
        stewb[e] = (short)f2bf(stew[e]);
    }
}

// ---------- 2: feature KNN pass 1 — MFMA Gram + packed-key register top-24 ----------
#define TQF 32
#define TPF 64
__global__ __launch_bounds__(256) void knn_feat_kernel(const short* __restrict__ fbb,
                                                       const float* __restrict__ sqn,
                                                       int* __restrict__ cand) {
    __shared__ alignas(16) short Qb[TQF][128];
    __shared__ alignas(16) short Pb[TPF][128];     // single buffer (writes after (B))
    __shared__ float sqP[TPF];
    __shared__ unsigned Ds[TQF][68];               // packed keys

    const int b = blockIdx.y, q0 = blockIdx.x * TQF, tid = threadIdx.x;
    const int lane = tid & 63, wid = tid >> 6;
    const short* fb = fbb + (size_t)b * NP * CIN;

    unsigned rk[CAND];
#pragma unroll
    for (int t = 0; t < CAND; ++t) rk[t] = 0xFFFFFFFFu;

    for (int i = 0; i < 2; ++i) {                  // Q tile (swizzled)
        int v = i * 256 + tid, row = v >> 4, g = v & 15;
        *(bf16x8*)&Qb[row][(g ^ (row & 7)) * 8] =
            *(const bf16x8*)&fb[(size_t)(q0 + row) * CIN + g * 8];
    }
    for (int i = 0; i < 4; ++i) {                  // P chunk 0
        int v = i * 256 + tid, row = v >> 4, g = v & 15;
        *(bf16x8*)&Pb[row][(g ^ (row & 7)) * 8] =
            *(const bf16x8*)&fb[(size_t)row * CIN + g * 8];
    }
    if (tid < TPF) sqP[tid] = sqn[b * NP + tid];

    const int qt = wid >> 1, ph = wid & 1;
    const int qsl = tid >> 3, sub = tid & 7;
    const int arow = qt * 16 + (lane & 15), asw = arow & 7;
    const int brow0 = ph * 32 + (lane & 15), brow1 = brow0 + 16;
    const int bsw0 = brow0 & 7, bsw1 = brow1 & 7;
    const int oct = lane >> 4;
    const int qrow = qt * 16 + oct * 4;

    for (int ch = 0; ch < NP / TPF; ++ch) {
        __syncthreads();                           // (A) Pb ready; prev scans done
        bf16x8 st0, st1, st2, st3;
        float sq_next = 0.f;
        const int nxt = (ch + 1 < NP / TPF);
        if (nxt) {                                 // reg-stage next chunk
            int p0n = (ch + 1) * TPF;
            { int v = tid;       int row = v>>4, g = v&15; st0 = *(const bf16x8*)&fb[(size_t)(p0n+row)*CIN + g*8]; }
            { int v = 256 + tid; int row = v>>4, g = v&15; st1 = *(const bf16x8*)&fb[(size_t)(p0n+row)*CIN + g*8]; }
            { int v = 512 + tid; int row = v>>4, g = v&15; st2 = *(const bf16x8*)&fb[(size_t)(p0n+row)*CIN + g*8]; }
            { int v = 768 + tid; int row = v>>4, g = v&15; st3 = *(const bf16x8*)&fb[(size_t)(p0n+row)*CIN + g*8]; }
            if (tid < TPF) sq_next = sqn[b * NP + p0n + tid];
        }
        f32x4 acc0 = {0.f,0.f,0.f,0.f}, acc1 = {0.f,0.f,0.f,0.f};
#pragma unroll
        for (int kk = 0; kk < 4; ++kk) {
            int g = kk * 4 + oct;
            bf16x8 av  = *(const bf16x8*)&Qb[arow][(g ^ asw) * 8];
            bf16x8 bv0 = *(const bf16x8*)&Pb[brow0][(g ^ bsw0) * 8];
            bf16x8 bv1 = *(const bf16x8*)&Pb[brow1][(g ^ bsw1) * 8];
            acc0 = __builtin_amdgcn_mfma_f32_16x16x32_bf16(av, bv0, acc0, 0, 0, 0);
            acc1 = __builtin_amdgcn_mfma_f32_16x16x32_bf16(av, bv1, acc1, 0, 0, 0);
        }
        const float sp0 = sqP[brow0], sp1 = sqP[brow1];
        const int pg0 = ch * TPF + brow0, pg1 = ch * TPF + brow1;
#pragma unroll
        for (int r = 0; r < 4; ++r) {
            int qg = q0 + qrow + r;
            unsigned k0 = fkey(sp0 - 2.0f * acc0[r], pg0);
            unsigned k1 = fkey(sp1 - 2.0f * acc1[r], pg1);
            if (qg == pg0) k0 = 0xFFFFFFFFu;       // self excluded
            if (qg == pg1) k1 = 0xFFFFFFFFu;
            Ds[qrow + r][brow0] = k0;
            Ds[qrow + r][brow1] = k1;
        }
        __syncthreads();                           // (B) Ds ready; Pb consumed
        {
            uint4 kA = *(const uint4*)&Ds[qsl][sub * 8];
            uint4 kB = *(const uint4*)&Ds[qsl][sub * 8 + 4];
            unsigned kv[8] = {kA.x, kA.y, kA.z, kA.w, kB.x, kB.y, kB.z, kB.w};
#pragma unroll
            for (int j = 0; j < 8; ++j) {
                unsigned k = kv[j];
                if (k < rk[CAND - 1]) {            // med3-style 2-inst shift steps
#pragma unroll
                    for (int t = CAND - 1; t > 0; --t)
                        rk[t] = umn(umx(rk[t - 1], k), rk[t]);
                    rk[0] = umn(rk[0], k);
                }
            }
        }
        if (nxt) {                                 // write staged chunk (Pb free)
            { int v = tid;       int row = v>>4, g = v&15; *(bf16x8*)&Pb[row][(g^(row&7))*8] = st0; }
            { int v = 256 + tid; int row = v>>4, g = v&15; *(bf16x8*)&Pb[row][(g^(row&7))*8] = st1; }
            { int v = 512 + tid; int row = v>>4, g = v&15; *(bf16x8*)&Pb[row][(g^(row&7))*8] = st2; }
            { int v = 768 + tid; int row = v>>4, g = v&15; *(bf16x8*)&Pb[row][(g^(row&7))*8] = st3; }
            if (tid < TPF) sqP[tid] = sq_next;
        }
    }

    // merge 8 sorted key-lists per query -> top-CAND (keys unique: index embedded)
    {
        unsigned hk = rk[0];
        int* dst = cand + ((size_t)b * NP + q0 + qsl) * CAND;
        for (int it = 0; it < CAND; ++it) {
            unsigned mk = hk;
#pragma unroll
            for (int msk = 1; msk <= 4; msk <<= 1)
                mk = umn(mk, (unsigned)__shfl_xor((int)mk, msk));
            if (sub == 0) dst[it] = (int)(mk & 0x7FFu);
            if (hk == mk) {                        // owner pops
#pragma unroll
                for (int t = 0; t < CAND - 1; ++t) rk[t] = rk[t + 1];
                rk[CAND - 1] = 0xFFFFFFFFu;
                hk = rk[0];
            }
        }
    }
}

// ---------- 2b: refine — 4-way parallel candidates, fp64 inner, REFERENCE fp32
// rounding chain preserved: d32 = fl32( fl32(sq_i)+fl32(sj) - fl32(2*dot) )
// Selection: rank-by-comparison over packed (d32bits, idx) u64 keys — identical
// (d32, idx)-lexicographic semantics as the round-4..8 sorted insert.
__global__ __launch_bounds__(256) void knn_refine_kernel(const float* __restrict__ feat,
                                                         const int* __restrict__ cand,
                                                         int* __restrict__ nbr) {
    __shared__ unsigned long long keyS[4][CAND];
    const int w = threadIdx.x >> 6;
    const int lane = threadIdx.x & 63;
    const int grp = lane >> 4, sl = lane & 15;
    const int gq = blockIdx.x * 4 + w;
    const int b = gq >> 11;
    const int q = gq & (NP - 1);
    const float* fb = feat + (size_t)b * NP * CIN;

    // q-row segment (8 dims/lane) in fp64; group-local 16-lane reduce
    double qd[8];
    {
        float4 a = *(const float4*)&fb[(size_t)q * CIN + sl * 8];
        float4 c = *(const float4*)&fb[(size_t)q * CIN + sl * 8 + 4];
        qd[0] = a.x; qd[1] = a.y; qd[2] = a.z; qd[3] = a.w;
        qd[4] = c.x; qd[5] = c.y; qd[6] = c.z; qd[7] = c.w;
    }
    double sqd = 0.0;
#pragma unroll
    for (int i = 0; i < 8; ++i) sqd += qd[i] * qd[i];
#pragma unroll
    for (int msk = 1; msk <= 8; msk <<= 1) sqd += __shfl_xor(sqd, msk);
    const float sqi = (float)sqd;

    const int* cq = cand + (size_t)gq * CAND;
    int jv[CAND / 4];
#pragma unroll
    for (int t = 0; t < CAND / 4; ++t) jv[t] = cq[t * 4 + grp];

#pragma unroll
    for (int t = 0; t < CAND / 4; ++t) {
        const int j = jv[t];
        float4 a = *(const float4*)&fb[(size_t)j * CIN + sl * 8];
        float4 c = *(const float4*)&fb[(size_t)j * CIN + sl * 8 + 4];
        double fd[8] = {a.x, a.y, a.z, a.w, c.x, c.y, c.z, c.w};
        double dot = 0.0, sj = 0.0;
#pragma unroll
        for (int i = 0; i < 8; ++i) { dot += qd[i] * fd[i]; sj += fd[i] * fd[i]; }
#pragma unroll
        for (int msk = 1; msk <= 8; msk <<= 1) {
            dot += __shfl_xor(dot, msk);
            sj  += __shfl_xor(sj, msk);
        }
        if (sl == 0) {
            float t1 = sqi + (float)sj;            // fl32(sq_i + sq_j)
            float t2 = (float)(2.0 * dot);         // fl32(2*dot)
            float d32 = t1 - t2;                   // fl32(t1 - t2)
            unsigned u = __float_as_uint(d32);
            u ^= (unsigned)((int)u >> 31) | 0x80000000u;
            keyS[w][t * 4 + grp] = ((unsigned long long)u << 32) | (unsigned)j;
        }
    }
    __syncthreads();
    if (lane < CAND) {
        unsigned long long k = keyS[w][lane];
        int rank = 0;
#pragma unroll
        for (int m = 0; m < CAND; ++m) rank += (keyS[w][m] < k) ? 1 : 0;
        if (rank < KNN) nbr[(size_t)gq * KNN + rank] = (int)(k & 0xFFFFFFFFu);
    }
}

// ---------- 3: vertex KNN — packed-key register top-17 ----------
#define TQV 32
__global__ __launch_bounds__(256) void knn_vert_kernel(const float* __restrict__ vert,
                                                       int* __restrict__ nbr) {
    __shared__ alignas(16) float vx[NP], vy[NP], vz[NP];
    const int b = blockIdx.y;
    const int q0 = blockIdx.x * TQV;
    const int tid = threadIdx.x;
    const float* vb = vert + (size_t)b * NP * 3;

    for (int i = 0; i < NP * 3 / 256; ++i) {
        int e = i * 256 + tid;
        float v = vb[e];
        int row = e / 3, comp = e % 3;
        (comp == 0 ? vx : comp == 1 ? vy : vz)[row] = v;
    }
    __syncthreads();

    const int q = tid >> 3;
    const int sub = tid & 7;
    const float qx = vx[q0 + q], qy = vy[q0 + q], qz = vz[q0 + q];

    unsigned rk[17];
#pragma unroll
    for (int t = 0; t < 17; ++t) rk[t] = 0xFFFFFFFFu;

    for (int m = 0; m < NP / 64; ++m) {
        const int p0 = m * 64 + sub * 8;
        float4 xA = *(const float4*)&vx[p0], xB = *(const float4*)&vx[p0 + 4];
        float4 yA = *(const float4*)&vy[p0], yB = *(const float4*)&vy[p0 + 4];
        float4 zA = *(const float4*)&vz[p0], zB = *(const float4*)&vz[p0 + 4];
        float dv[8];
        { float dx = qx-xA.x, dy = qy-yA.x, dz = qz-zA.x; dv[0] = dx*dx+dy*dy+dz*dz; }
        { float dx = qx-xA.y, dy = qy-yA.y, dz = qz-zA.y; dv[1] = dx*dx+dy*dy+dz*dz; }
        { float dx = qx-xA.z, dy = qy-yA.z, dz = qz-zA.z; dv[2] = dx*dx+dy*dy+dz*dz; }
        { float dx = qx-xA.w, dy = qy-yA.w, dz = qz-zA.w; dv[3] = dx*dx+dy*dy+dz*dz; }
        { float dx = qx-xB.x, dy = qy-yB.x, dz = qz-zB.x; dv[4] = dx*dx+dy*dy+dz*dz; }
        { float dx = qx-xB.y, dy = qy-yB.y, dz = qz-zB.y; dv[5] = dx*dx+dy*dy+dz*dz; }
        { float dx = qx-xB.z, dy = qy-yB.z, dz = qz-zB.z; dv[6] = dx*dx+dy*dy+dz*dz; }
        { float dx = qx-xB.w, dy = qy-yB.w, dz = qz-zB.w; dv[7] = dx*dx+dy*dy+dz*dz; }
#pragma unroll
        for (int j = 0; j < 8; ++j) {
            unsigned k = fkey(dv[j], p0 + j);      // self d=0 -> rank 0, dropped at merge
            if (k < rk[16]) {
#pragma unroll
                for (int t = 16; t > 0; --t) rk[t] = umn(umx(rk[t - 1], k), rk[t]);
                rk[0] = umn(rk[0], k);
            }
        }
    }
    {
        unsigned hk = rk[0];
        int* dst = nbr + ((size_t)b * NP + q0 + q) * KNN;
        for (int it = 0; it < 17; ++it) {
            unsigned mk = hk;
#pragma unroll
            for (int msk = 1; msk <= 4; msk <<= 1)
                mk = umn(mk, (unsigned)__shfl_xor((int)mk, msk));
            if (sub == 0 && it >= 1) dst[it - 1] = (int)(mk & 0x7FFu);
            if (hk == mk) {
#pragma unroll
                for (int t = 0; t < 16; ++t) rk[t] = rk[t + 1];
                rk[16] = 0xFFFFFFFFu;
                hk = rk[0];
            }
        }
    }
}

// ---------- 4: fm = fmap @ W + bias — bf16 MFMA (fp32 acc) ----------
__global__ __launch_bounds__(256) void fm_gemm_kernel(const short* __restrict__ fbb,
                                                      const short* __restrict__ Wt,
                                                      const float* __restrict__ bias,
                                                      float* __restrict__ C) {
    __shared__ alignas(16) short As[64][128];
    const int m0 = blockIdx.x * 64, n0 = blockIdx.y * 128, tid = threadIdx.x;
    const int lane = tid & 63, wid = tid >> 6, oct = lane >> 4;
    for (int i = 0; i < 4; ++i) {
        int v = i * 256 + tid, row = v >> 4, g = v & 15;
        *(bf16x8*)&As[row][(g ^ (row & 7)) * 8] =
            *(const bf16x8*)&fbb[(size_t)(m0 + row) * CIN + g * 8];
    }
    __syncthreads();
    f32x4 acc[4][2] = {};
#pragma unroll
    for (int kk = 0; kk < 4; ++kk) {
        int g = kk * 4 + oct;
        bf16x8 bv[2];
#pragma unroll
        for (int nt = 0; nt < 2; ++nt) {
            int n = n0 + (wid * 2 + nt) * 16 + (lane & 15);
            bv[nt] = *(const bf16x8*)&Wt[(size_t)n * CIN + g * 8];
        }
#pragma unroll
        for (int mt = 0; mt < 4; ++mt) {
            int ar = mt * 16 + (lane & 15);
            bf16x8 av = *(const bf16x8*)&As[ar][(g ^ (ar & 7)) * 8];
#pragma unroll
            for (int nt = 0; nt < 2; ++nt)
                acc[mt][nt] = __builtin_amdgcn_mfma_f32_16x16x32_bf16(av, bv[nt], acc[mt][nt], 0, 0, 0);
        }
    }
#pragma unroll
    for (int mt = 0; mt < 4; ++mt)
#pragma unroll
        for (int nt = 0; nt < 2; ++nt) {
            int n = n0 + (wid * 2 + nt) * 16 + (lane & 15);
            float bsv = bias[n];
            int mbase = m0 + mt * 16 + oct * 4;
#pragma unroll
            for (int r = 0; r < 4; ++r)
                C[(size_t)(mbase + r) * NC + n] = acc[mt][nt][r] + bsv;
        }
}

// ---------- 5: direction-gated support activation + center (+ bf16 copy) ----------
__global__ __launch_bounds__(128) void act_kernel(const float* __restrict__ fm,
                                                  const int* __restrict__ nbr,
                                                  const float* __restrict__ vert,
                                                  const float* __restrict__ dirs,
                                                  float* __restrict__ feature,
                                                  short* __restrict__ featb) {
    __shared__ int sj[KNN];
    __shared__ float rf[KNN][4];
    const int i = blockIdx.x;
    const int b = blockIdx.y;
    const int tid = threadIdx.x;
    const size_t bi = (size_t)b * NP + i;
    if (tid < KNN) {
        int j = nbr[bi * KNN + tid];
        sj[tid] = j;
        const float* vb = vert + (size_t)b * NP * 3;
        float dx = vb[j * 3 + 0] - vb[i * 3 + 0];
        float dy = vb[j * 3 + 1] - vb[i * 3 + 1];
        float dz = vb[j * 3 + 2] - vb[i * 3 + 2];
        float nrm = sqrtf(dx * dx + dy * dy + dz * dz);
        float den = fmaxf(nrm, 1e-12f);
        rf[tid][0] = dx / den; rf[tid][1] = dy / den; rf[tid][2] = dz / den;
    }
    __syncthreads();
    const int oc = tid;
    float accm = 0.0f;
#pragma unroll
    for (int s = 0; s < NSUP; ++s) {
        int m = s * OC + oc;
        float d0 = dirs[m], d1 = dirs[SC + m], d2 = dirs[2 * SC + m];
        float nrm = sqrtf(d0 * d0 + d1 * d1 + d2 * d2);
        float den = fmaxf(nrm, 1e-12f);
        float s0 = d0 / den, s1 = d1 / den, s2 = d2 / den;
        float vmax = -3.0e38f;
        for (int kk = 0; kk < KNN; ++kk) {
            float th = fmaxf(rf[kk][0] * s0 + rf[kk][1] * s1 + rf[kk][2] * s2, 0.0f);
            float sup = fm[((size_t)b * NP + sj[kk]) * NC + OC + m];
            vmax = fmaxf(vmax, th * sup);
        }
        accm += vmax;
    }
    float v = fm[bi * NC + oc] + accm / 3.0f;
    feature[bi * OC + oc] = v;
    featb[bi * OC + oc] = (short)f2bf(v);
}

// ---------- 6: neighborhood max-pool over vertex-space KNN ----------
__global__ __launch_bounds__(128) void pool_kernel(const float* __restrict__ feature,
                                                   const int* __restrict__ nbr2,
                                                   float* __restrict__ pooled) {
    __shared__ int sj[KNN];
    const int i = blockIdx.x, b = blockIdx.y, tid = threadIdx.x;
    const size_t bi = (size_t)b * NP + i;
    if (tid < KNN) sj[tid] = nbr2[bi * KNN + tid];
    __syncthreads();
    float mx = -3.0e38f;
    for (int kk = 0; kk < KNN; ++kk)
        mx = fmaxf(mx, feature[((size_t)b * NP + sj[kk]) * OC + tid]);
    pooled[bi * OC + tid] = mx;
}

// ---------- 7: fused mean-over-N + gdot ----------
__global__ __launch_bounds__(128) void global_kernel(const float* __restrict__ pooled,
                                                     const float* __restrict__ conv2,
                                                     float* __restrict__ gd) {
    __shared__ float fgs[OC];
    const int b = blockIdx.x, tid = threadIdx.x;
    float s0 = 0.f, s1 = 0.f, s2 = 0.f, s3 = 0.f;
    const float* base = pooled + (size_t)b * NP * OC + tid;
    for (int i = 0; i < NP; i += 4) {
        s0 += base[(size_t)(i + 0) * OC];
        s1 += base[(size_t)(i + 1) * OC];
        s2 += base[(size_t)(i + 2) * OC];
        s3 += base[(size_t)(i + 3) * OC];
    }
    fgs[tid] = ((s0 + s1) + (s2 + s3)) / (float)NP;
    __syncthreads();
    float g = 0.f;
    const float* w = conv2 + (size_t)tid * 2 * OC + OC;
    for (int c = 0; c < OC; ++c) g += fgs[c] * w[c];
    gd[b * OC + tid] = g;
}

// ---------- 8: final — bf16 MFMA conv2(feat) + ste(fmap) + gd + residual ----------
__global__ __launch_bounds__(256) void final_kernel(const short* __restrict__ featb,
                                                    const short* __restrict__ fbb,
                                                    const short* __restrict__ conv2b,
                                                    const short* __restrict__ stewb,
                                                    const float* __restrict__ gd,
                                                    const float* __restrict__ feature,
                                                    float* __restrict__ out) {
    __shared__ alignas(16) short Af[32][128];
    __shared__ alignas(16) short Am[32][128];
    const int m0 = blockIdx.x * 32, tid = threadIdx.x;
    const int lane = tid & 63, wid = tid >> 6, oct = lane >> 4;
    for (int i = 0; i < 2; ++i) {
        int v = i * 256 + tid, row = v >> 4, g = v & 15;
        *(bf16x8*)&Af[row][(g ^ (row & 7)) * 8] =
            *(const bf16x8*)&featb[(size_t)(m0 + row) * OC + g * 8];
        *(bf16x8*)&Am[row][(g ^ (row & 7)) * 8] =
            *(const bf16x8*)&fbb[(size_t)(m0 + row) * CIN + g * 8];
    }
    __syncthreads();
    f32x4 acc[2][2] = {};
#pragma unroll
    for (int kk = 0; kk < 4; ++kk) {
        int g = kk * 4 + oct;
        bf16x8 bC[2], bS[2];
#pragma unroll
        for (int nt = 0; nt < 2; ++nt) {
            int n = (wid * 2 + nt) * 16 + (lane & 15);
            bC[nt] = *(const bf16x8*)&conv2b[(size_t)n * (2 * OC) + g * 8];
            bS[nt] = *(const bf16x8*)&stewb[(size_t)n * CIN + g * 8];
        }
#pragma unroll
        for (int mt = 0; mt < 2; ++mt) {
            int ar = mt * 16 + (lane & 15);
            bf16x8 aF = *(const bf16x8*)&Af[ar][(g ^ (ar & 7)) * 8];
            bf16x8 aM = *(const bf16x8*)&Am[ar][(g ^ (ar & 7)) * 8];
#pragma unroll
            for (int nt = 0; nt < 2; ++nt) {
                acc[mt][nt] = __builtin_amdgcn_mfma_f32_16x16x32_bf16(aF, bC[nt], acc[mt][nt], 0, 0, 0);
                acc[mt][nt] = __builtin_amdgcn_mfma_f32_16x16x32_bf16(aM, bS[nt], acc[mt][nt], 0, 0, 0);
            }
        }
    }
#pragma unroll
    for (int mt = 0; mt < 2; ++mt)
#pragma unroll
        for (int nt = 0; nt < 2; ++nt) {
            int o = (wid * 2 + nt) * 16 + (lane & 15);
            int mbase = m0 + mt * 16 + oct * 4;
#pragma unroll
            for (int r = 0; r < 4; ++r) {
                int m = mbase + r;
                out[(size_t)m * OC + o] = acc[mt][nt][r]
                    + gd[(m >> 11) * OC + o] + feature[(size_t)m * OC + o];
            }
        }
}

extern "C" void kernel_launch(void* const* d_in, const int* in_sizes, int n_in,
                              void* d_out, int out_size, void* d_ws, size_t ws_size,
                              hipStream_t stream) {
    const float* vert  = (const float*)d_in[0];
    const float* fmap  = (const float*)d_in[1];
    const float* W     = (const float*)d_in[2];
    const float* bias  = (const float*)d_in[3];
    const float* dirs  = (const float*)d_in[4];
    const float* stew  = (const float*)d_in[5];
    const float* conv2 = (const float*)d_in[6];
    float* out = (float*)d_out;

    float* ws      = (float*)d_ws;
    float* sqn     = ws;                            // 16384
    short* fbb     = (short*)(sqn + 16384);         // 2M shorts (1M floats)
    float* C1      = sqn + 16384 + 1048576;         // 8.4M
    float* feature = C1 + 8388608;                  // 2M
    short* featb   = (short*)(feature + 2097152);   // 2M shorts (1M floats)
    float* gd      = feature + 2097152 + 1048576;   // 1024
    short* Wt      = (short*)(gd + 1024);           // 65536 shorts (32768 f)
    short* conv2b  = Wt + 65536;                    // 32768 shorts (16384 f)
    short* stewb   = conv2b + 32768;                // 16384 shorts (8192 f)
    int*   nbr1    = (int*)(stewb + 16384);         // 262144
    int*   nbr2    = nbr1 + 262144;                 // 262144
    int*   cand    = (int*)C1;                      // alias: dead before fm_gemm writes C1
    float* pooled  = C1;                            // alias: C1 dead after act

    sqbf_kernel<<<1024, 256, 0, stream>>>(fmap, sqn, fbb);
    wprep_kernel<<<448, 256, 0, stream>>>(W, conv2, stew, Wt, conv2b, stewb);
    knn_feat_kernel<<<dim3(64, 8), 256, 0, stream>>>(fbb, sqn, cand);
    knn_refine_kernel<<<4096, 256, 0, stream>>>(fmap, cand, nbr1);
    knn_vert_kernel<<<dim3(64, 8), 256, 0, stream>>>(vert, nbr2);
    fm_gemm_kernel<<<dim3(256, 4), 256, 0, stream>>>(fbb, Wt, bias, C1);
    act_kernel<<<dim3(2048, 8), 128, 0, stream>>>(C1, nbr1, vert, dirs, feature, featb);
    pool_kernel<<<dim3(2048, 8), 128, 0, stream>>>(feature, nbr2, pooled);
    global_kernel<<<8, 128, 0, stream>>>(pooled, conv2, gd);
    final_kernel<<<512, 256, 0, stream>>>(featb, fbb, conv2b, stewb, gd, feature, out);
}

// Round 10
// 242.610 us; speedup vs baseline: 6.3480x; 1.0623x over previous
//
#include <hip/hip_runtime.h>
#include <hip/hip_bf16.h>

#define BS 8
#define NP 2048
#define CIN 128
#define OC 128
#define NSUP 3
#define KNN 16
#define NC 512   // (NSUP+1)*OC
#define SC 384   // NSUP*OC
#define CAND 24  // pass-1 candidate depth; key-quant err ~0.012 << rank margin ~4

typedef __attribute__((ext_vector_type(8))) short bf16x8;
typedef __attribute__((ext_vector_type(4))) float f32x4;

__device__ inline unsigned short f2bf(float x) {
    __hip_bfloat16 h = __float2bfloat16(x);
    return *reinterpret_cast<unsigned short*>(&h);
}
// sortable key: float order-preserving bits, low 11 bits replaced by point index
__device__ inline unsigned fkey(float d, int gi) {
    unsigned u = __float_as_uint(d);
    u ^= (unsigned)((int)u >> 31) | 0x80000000u;
    return (u & 0xFFFFF800u) | (unsigned)gi;
}
__device__ inline unsigned umn(unsigned a, unsigned b) { return a < b ? a : b; }
__device__ inline unsigned umx(unsigned a, unsigned b) { return a > b ? a : b; }

// ---------- 1: fused squared-norms + fp32->bf16 copy ----------
__global__ __launch_bounds__(256) void sqbf_kernel(const float* __restrict__ in,
                                                   float* __restrict__ sq,
                                                   short* __restrict__ outp) {
    const int tid = threadIdx.x;
    const int row = blockIdx.x * 16 + (tid >> 4);
    const int seg = tid & 15;
    const float* p = in + (size_t)row * CIN + seg * 8;
    float4 f0 = *(const float4*)p;
    float4 f1 = *(const float4*)(p + 4);
    bf16x8 s;
    s[0] = (short)f2bf(f0.x); s[1] = (short)f2bf(f0.y);
    s[2] = (short)f2bf(f0.z); s[3] = (short)f2bf(f0.w);
    s[4] = (short)f2bf(f1.x); s[5] = (short)f2bf(f1.y);
    s[6] = (short)f2bf(f1.z); s[7] = (short)f2bf(f1.w);
    *(bf16x8*)&outp[(size_t)row * CIN + seg * 8] = s;
    float ss = f0.x*f0.x + f0.y*f0.y + f0.z*f0.z + f0.w*f0.w
             + f1.x*f1.x + f1.y*f1.y + f1.z*f1.z + f1.w*f1.w;
#pragma unroll
    for (int msk = 1; msk <= 8; msk <<= 1) ss += __shfl_xor(ss, msk);
    if (seg == 0) sq[row] = ss;
}

// ---------- 1b: weight prep — Wt[n][k], conv2b, stewb in bf16 ----------
__global__ __launch_bounds__(256) void wprep_kernel(const float* __restrict__ W,
                                                    const float* __restrict__ conv2,
                                                    const float* __restrict__ stew,
                                                    short* __restrict__ Wt,
                                                    short* __restrict__ conv2b,
                                                    short* __restrict__ stewb) {
    int idx = blockIdx.x * 256 + threadIdx.x;      // 448 blocks
    if (idx < NC * CIN) {
        int n = idx >> 7, k = idx & 127;
        Wt[idx] = (short)f2bf(W[(size_t)k * NC + n]);
    } else if (idx < NC * CIN + OC * 2 * OC) {
        int e = idx - NC * CIN;
        conv2b[e] = (short)f2bf(conv2[e]);
    } else {
        int e = idx - NC * CIN - OC * 2 * OC;
        stewb[e] = (short)f2bf(stew[e]);
    }
}

// ---------- 2: feature KNN pass 1 — MFMA Gram, 1-barrier pipeline, gated top-24 ----
// Safety of gate T = min over 8 sub-lanes of rk[23]: every filled lane's 24th-best
// >= global 24th-best, so k >= T => k not in global top-24 (keys unique by index).
#define TQF 32
#define TPF 64
#define NCHF (NP / TPF)
__global__ __launch_bounds__(256) void knn_feat_kernel(const short* __restrict__ fbb,
                                                       const float* __restrict__ sqn,
                                                       int* __restrict__ cand) {
    __shared__ alignas(16) short Qb[TQF][128];
    __shared__ alignas(16) short Pb[2][TPF][128];
    __shared__ float sqP[2][TPF];
    __shared__ unsigned Ds[2][TQF][68];            // packed keys, double-buffered

    const int b = blockIdx.y, q0 = blockIdx.x * TQF, tid = threadIdx.x;
    const int lane = tid & 63, wid = tid >> 6;
    const short* fb = fbb + (size_t)b * NP * CIN;

    unsigned rk[CAND];
#pragma unroll
    for (int t = 0; t < CAND; ++t) rk[t] = 0xFFFFFFFFu;
    unsigned Treg = 0xFFFFFFFFu;

    for (int i = 0; i < 2; ++i) {                  // Q tile (swizzled)
        int v = i * 256 + tid, row = v >> 4, g = v & 15;
        *(bf16x8*)&Qb[row][(g ^ (row & 7)) * 8] =
            *(const bf16x8*)&fb[(size_t)(q0 + row) * CIN + g * 8];
    }
    for (int i = 0; i < 4; ++i) {                  // P chunk 0 -> Pb[0]
        int v = i * 256 + tid, row = v >> 4, g = v & 15;
        *(bf16x8*)&Pb[0][row][(g ^ (row & 7)) * 8] =
            *(const bf16x8*)&fb[(size_t)row * CIN + g * 8];
    }
    if (tid < TPF) sqP[0][tid] = sqn[b * NP + tid];
    __syncthreads();

    const int qt = wid >> 1, ph = wid & 1;
    const int qsl = tid >> 3, sub = tid & 7;
    const int arow = qt * 16 + (lane & 15), asw = arow & 7;
    const int brow0 = ph * 32 + (lane & 15), brow1 = brow0 + 16;
    const int bsw0 = brow0 & 7, bsw1 = brow1 & 7;
    const int oct = lane >> 4;
    const int qrow = qt * 16 + oct * 4;

    auto scan = [&](int pb) {                      // scan one chunk's keys (gated)
        uint4 kA = *(const uint4*)&Ds[pb][qsl][sub * 8];
        uint4 kB = *(const uint4*)&Ds[pb][qsl][sub * 8 + 4];
        unsigned kv[8] = {kA.x, kA.y, kA.z, kA.w, kB.x, kB.y, kB.z, kB.w};
#pragma unroll
        for (int j = 0; j < 8; ++j) {
            unsigned k = kv[j];
            if (k < Treg) {                        // gate: provably-safe skip
#pragma unroll
                for (int t = CAND - 1; t > 0; --t)
                    rk[t] = umn(umx(rk[t - 1], k), rk[t]);
                rk[0] = umn(rk[0], k);
            }
        }
        unsigned t23 = rk[CAND - 1];               // refresh T (8-lane min)
        t23 = umn(t23, (unsigned)__shfl_xor((int)t23, 1));
        t23 = umn(t23, (unsigned)__shfl_xor((int)t23, 2));
        t23 = umn(t23, (unsigned)__shfl_xor((int)t23, 4));
        Treg = t23;
    };

    for (int ch = 0; ch < NCHF; ++ch) {
        const int cur = ch & 1;
        bf16x8 st0, st1, st2, st3;
        float sq_next = 0.f;
        const int nxt = (ch + 1 < NCHF);
        if (nxt) {                                 // issue next-chunk loads early
            int p0n = (ch + 1) * TPF;
            { int v = tid;       int row = v>>4, g = v&15; st0 = *(const bf16x8*)&fb[(size_t)(p0n+row)*CIN + g*8]; }
            { int v = 256 + tid; int row = v>>4, g = v&15; st1 = *(const bf16x8*)&fb[(size_t)(p0n+row)*CIN + g*8]; }
            { int v = 512 + tid; int row = v>>4, g = v&15; st2 = *(const bf16x8*)&fb[(size_t)(p0n+row)*CIN + g*8]; }
            { int v = 768 + tid; int row = v>>4, g = v&15; st3 = *(const bf16x8*)&fb[(size_t)(p0n+row)*CIN + g*8]; }
            if (tid < TPF) sq_next = sqn[b * NP + p0n + tid];
        }
        // MFMA chunk ch from Pb[cur] -> keys -> Ds[cur]
        f32x4 acc0 = {0.f,0.f,0.f,0.f}, acc1 = {0.f,0.f,0.f,0.f};
#pragma unroll
        for (int kk = 0; kk < 4; ++kk) {
            int g = kk * 4 + oct;
            bf16x8 av  = *(const bf16x8*)&Qb[arow][(g ^ asw) * 8];
            bf16x8 bv0 = *(const bf16x8*)&Pb[cur][brow0][(g ^ bsw0) * 8];
            bf16x8 bv1 = *(const bf16x8*)&Pb[cur][brow1][(g ^ bsw1) * 8];
            acc0 = __builtin_amdgcn_mfma_f32_16x16x32_bf16(av, bv0, acc0, 0, 0, 0);
            acc1 = __builtin_amdgcn_mfma_f32_16x16x32_bf16(av, bv1, acc1, 0, 0, 0);
        }
        const float sp0 = sqP[cur][brow0], sp1 = sqP[cur][brow1];
        const int pg0 = ch * TPF + brow0, pg1 = ch * TPF + brow1;
#pragma unroll
        for (int r = 0; r < 4; ++r) {
            int qg = q0 + qrow + r;
            unsigned k0 = fkey(sp0 - 2.0f * acc0[r], pg0);
            unsigned k1 = fkey(sp1 - 2.0f * acc1[r], pg1);
            if (qg == pg0) k0 = 0xFFFFFFFFu;       // self excluded
            if (qg == pg1) k1 = 0xFFFFFFFFu;
            Ds[cur][qrow + r][brow0] = k0;
            Ds[cur][qrow + r][brow1] = k1;
        }
        if (ch > 0) scan(cur ^ 1);                 // scan previous chunk (overlap)
        if (nxt) {                                 // write staged chunk -> Pb[cur^1]
            { int v = tid;       int row = v>>4, g = v&15; *(bf16x8*)&Pb[cur^1][row][(g^(row&7))*8] = st0; }
            { int v = 256 + tid; int row = v>>4, g = v&15; *(bf16x8*)&Pb[cur^1][row][(g^(row&7))*8] = st1; }
            { int v = 512 + tid; int row = v>>4, g = v&15; *(bf16x8*)&Pb[cur^1][row][(g^(row&7))*8] = st2; }
            { int v = 768 + tid; int row = v>>4, g = v&15; *(bf16x8*)&Pb[cur^1][row][(g^(row&7))*8] = st3; }
            if (tid < TPF) sqP[cur ^ 1][tid] = sq_next;
        }
        __syncthreads();                           // ONE barrier per chunk
    }
    scan((NCHF - 1) & 1);                          // epilogue: last chunk

    // merge 8 sorted key-lists per query -> top-CAND (keys unique: index embedded)
    {
        unsigned hk = rk[0];
        int* dst = cand + ((size_t)b * NP + q0 + qsl) * CAND;
        for (int it = 0; it < CAND; ++it) {
            unsigned mk = hk;
#pragma unroll
            for (int msk = 1; msk <= 4; msk <<= 1)
                mk = umn(mk, (unsigned)__shfl_xor((int)mk, msk));
            if (sub == 0) dst[it] = (int)(mk & 0x7FFu);
            if (hk == mk) {                        // owner pops
#pragma unroll
                for (int t = 0; t < CAND - 1; ++t) rk[t] = rk[t + 1];
                rk[CAND - 1] = 0xFFFFFFFFu;
                hk = rk[0];
            }
        }
    }
}

// ---------- 2b: refine — 4-way parallel candidates, fp64 inner, REFERENCE fp32
// rounding chain preserved: d32 = fl32( fl32(sq_i)+fl32(sj) - fl32(2*dot) )
__global__ __launch_bounds__(256) void knn_refine_kernel(const float* __restrict__ feat,
                                                         const int* __restrict__ cand,
                                                         int* __restrict__ nbr) {
    __shared__ unsigned long long keyS[4][CAND];
    const int w = threadIdx.x >> 6;
    const int lane = threadIdx.x & 63;
    const int grp = lane >> 4, sl = lane & 15;
    const int gq = blockIdx.x * 4 + w;
    const int b = gq >> 11;
    const int q = gq & (NP - 1);
    const float* fb = feat + (size_t)b * NP * CIN;

    double qd[8];
    {
        float4 a = *(const float4*)&fb[(size_t)q * CIN + sl * 8];
        float4 c = *(const float4*)&fb[(size_t)q * CIN + sl * 8 + 4];
        qd[0] = a.x; qd[1] = a.y; qd[2] = a.z; qd[3] = a.w;
        qd[4] = c.x; qd[5] = c.y; qd[6] = c.z; qd[7] = c.w;
    }
    double sqd = 0.0;
#pragma unroll
    for (int i = 0; i < 8; ++i) sqd += qd[i] * qd[i];
#pragma unroll
    for (int msk = 1; msk <= 8; msk <<= 1) sqd += __shfl_xor(sqd, msk);
    const float sqi = (float)sqd;

    const int* cq = cand + (size_t)gq * CAND;
    int jv[CAND / 4];
#pragma unroll
    for (int t = 0; t < CAND / 4; ++t) jv[t] = cq[t * 4 + grp];

#pragma unroll
    for (int t = 0; t < CAND / 4; ++t) {
        const int j = jv[t];
        float4 a = *(const float4*)&fb[(size_t)j * CIN + sl * 8];
        float4 c = *(const float4*)&fb[(size_t)j * CIN + sl * 8 + 4];
        double fd[8] = {a.x, a.y, a.z, a.w, c.x, c.y, c.z, c.w};
        double dot = 0.0, sj = 0.0;
#pragma unroll
        for (int i = 0; i < 8; ++i) { dot += qd[i] * fd[i]; sj += fd[i] * fd[i]; }
#pragma unroll
        for (int msk = 1; msk <= 8; msk <<= 1) {
            dot += __shfl_xor(dot, msk);
            sj  += __shfl_xor(sj, msk);
        }
        if (sl == 0) {
            float t1 = sqi + (float)sj;
            float t2 = (float)(2.0 * dot);
            float d32 = t1 - t2;
            unsigned u = __float_as_uint(d32);
            u ^= (unsigned)((int)u >> 31) | 0x80000000u;
            keyS[w][t * 4 + grp] = ((unsigned long long)u << 32) | (unsigned)j;
        }
    }
    __syncthreads();
    if (lane < CAND) {
        unsigned long long k = keyS[w][lane];
        int rank = 0;
#pragma unroll
        for (int m = 0; m < CAND; ++m) rank += (keyS[w][m] < k) ? 1 : 0;
        if (rank < KNN) nbr[(size_t)gq * KNN + rank] = (int)(k & 0xFFFFFFFFu);
    }
}

// ---------- 3: vertex KNN — packed-key register top-17, gated ----------
#define TQV 32
__global__ __launch_bounds__(256) void knn_vert_kernel(const float* __restrict__ vert,
                                                       int* __restrict__ nbr) {
    __shared__ alignas(16) float vx[NP], vy[NP], vz[NP];
    const int b = blockIdx.y;
    const int q0 = blockIdx.x * TQV;
    const int tid = threadIdx.x;
    const float* vb = vert + (size_t)b * NP * 3;

    for (int i = 0; i < NP * 3 / 256; ++i) {
        int e = i * 256 + tid;
        float v = vb[e];
        int row = e / 3, comp = e % 3;
        (comp == 0 ? vx : comp == 1 ? vy : vz)[row] = v;
    }
    __syncthreads();

    const int q = tid >> 3;
    const int sub = tid & 7;
    const float qx = vx[q0 + q], qy = vy[q0 + q], qz = vz[q0 + q];

    unsigned rk[17];
#pragma unroll
    for (int t = 0; t < 17; ++t) rk[t] = 0xFFFFFFFFu;
    unsigned Treg = 0xFFFFFFFFu;

    for (int m = 0; m < NP / 64; ++m) {
        const int p0 = m * 64 + sub * 8;
        float4 xA = *(const float4*)&vx[p0], xB = *(const float4*)&vx[p0 + 4];
        float4 yA = *(const float4*)&vy[p0], yB = *(const float4*)&vy[p0 + 4];
        float4 zA = *(const float4*)&vz[p0], zB = *(const float4*)&vz[p0 + 4];
        float dv[8];
        { float dx = qx-xA.x, dy = qy-yA.x, dz = qz-zA.x; dv[0] = dx*dx+dy*dy+dz*dz; }
        { float dx = qx-xA.y, dy = qy-yA.y, dz = qz-zA.y; dv[1] = dx*dx+dy*dy+dz*dz; }
        { float dx = qx-xA.z, dy = qy-yA.z, dz = qz-zA.z; dv[2] = dx*dx+dy*dy+dz*dz; }
        { float dx = qx-xA.w, dy = qy-yA.w, dz = qz-zA.w; dv[3] = dx*dx+dy*dy+dz*dz; }
        { float dx = qx-xB.x, dy = qy-yB.x, dz = qz-zB.x; dv[4] = dx*dx+dy*dy+dz*dz; }
        { float dx = qx-xB.y, dy = qy-yB.y, dz = qz-zB.y; dv[5] = dx*dx+dy*dy+dz*dz; }
        { float dx = qx-xB.z, dy = qy-yB.z, dz = qz-zB.z; dv[6] = dx*dx+dy*dy+dz*dz; }
        { float dx = qx-xB.w, dy = qy-yB.w, dz = qz-zB.w; dv[7] = dx*dx+dy*dy+dz*dz; }
#pragma unroll
        for (int j = 0; j < 8; ++j) {
            unsigned k = fkey(dv[j], p0 + j);      // self d=0 -> minimal key, kept
            if (k < Treg) {
#pragma unroll
                for (int t = 16; t > 0; --t) rk[t] = umn(umx(rk[t - 1], k), rk[t]);
                rk[0] = umn(rk[0], k);
            }
        }
        unsigned t16 = rk[16];
        t16 = umn(t16, (unsigned)__shfl_xor((int)t16, 1));
        t16 = umn(t16, (unsigned)__shfl_xor((int)t16, 2));
        t16 = umn(t16, (unsigned)__shfl_xor((int)t16, 4));
        Treg = t16;
    }
    {
        unsigned hk = rk[0];
        int* dst = nbr + ((size_t)b * NP + q0 + q) * KNN;
        for (int it = 0; it < 17; ++it) {
            unsigned mk = hk;
#pragma unroll
            for (int msk = 1; msk <= 4; msk <<= 1)
                mk = umn(mk, (unsigned)__shfl_xor((int)mk, msk));
            if (sub == 0 && it >= 1) dst[it - 1] = (int)(mk & 0x7FFu);
            if (hk == mk) {
#pragma unroll
                for (int t = 0; t < 16; ++t) rk[t] = rk[t + 1];
                rk[16] = 0xFFFFFFFFu;
                hk = rk[0];
            }
        }
    }
}

// ---------- 4: fm = fmap @ W + bias — bf16 MFMA (fp32 acc) ----------
__global__ __launch_bounds__(256) void fm_gemm_kernel(const short* __restrict__ fbb,
                                                      const short* __restrict__ Wt,
                                                      const float* __restrict__ bias,
                                                      float* __restrict__ C) {
    __shared__ alignas(16) short As[64][128];
    const int m0 = blockIdx.x * 64, n0 = blockIdx.y * 128, tid = threadIdx.x;
    const int lane = tid & 63, wid = tid >> 6, oct = lane >> 4;
    for (int i = 0; i < 4; ++i) {
        int v = i * 256 + tid, row = v >> 4, g = v & 15;
        *(bf16x8*)&As[row][(g ^ (row & 7)) * 8] =
            *(const bf16x8*)&fbb[(size_t)(m0 + row) * CIN + g * 8];
    }
    __syncthreads();
    f32x4 acc[4][2] = {};
#pragma unroll
    for (int kk = 0; kk < 4; ++kk) {
        int g = kk * 4 + oct;
        bf16x8 bv[2];
#pragma unroll
        for (int nt = 0; nt < 2; ++nt) {
            int n = n0 + (wid * 2 + nt) * 16 + (lane & 15);
            bv[nt] = *(const bf16x8*)&Wt[(size_t)n * CIN + g * 8];
        }
#pragma unroll
        for (int mt = 0; mt < 4; ++mt) {
            int ar = mt * 16 + (lane & 15);
            bf16x8 av = *(const bf16x8*)&As[ar][(g ^ (ar & 7)) * 8];
#pragma unroll
            for (int nt = 0; nt < 2; ++nt)
                acc[mt][nt] = __builtin_amdgcn_mfma_f32_16x16x32_bf16(av, bv[nt], acc[mt][nt], 0, 0, 0);
        }
    }
#pragma unroll
    for (int mt = 0; mt < 4; ++mt)
#pragma unroll
        for (int nt = 0; nt < 2; ++nt) {
            int n = n0 + (wid * 2 + nt) * 16 + (lane & 15);
            float bsv = bias[n];
            int mbase = m0 + mt * 16 + oct * 4;
#pragma unroll
            for (int r = 0; r < 4; ++r)
                C[(size_t)(mbase + r) * NC + n] = acc[mt][nt][r] + bsv;
        }
}

// ---------- 5: direction-gated support activation + center (+ bf16 copy) ----------
__global__ __launch_bounds__(128) void act_kernel(const float* __restrict__ fm,
                                                  const int* __restrict__ nbr,
                                                  const float* __restrict__ vert,
                                                  const float* __restrict__ dirs,
                                                  float* __restrict__ feature,
                                                  short* __restrict__ featb) {
    __shared__ int sj[KNN];
    __shared__ float rf[KNN][4];
    const int i = blockIdx.x;
    const int b = blockIdx.y;
    const int tid = threadIdx.x;
    const size_t bi = (size_t)b * NP + i;
    if (tid < KNN) {
        int j = nbr[bi * KNN + tid];
        sj[tid] = j;
        const float* vb = vert + (size_t)b * NP * 3;
        float dx = vb[j * 3 + 0] - vb[i * 3 + 0];
        float dy = vb[j * 3 + 1] - vb[i * 3 + 1];
        float dz = vb[j * 3 + 2] - vb[i * 3 + 2];
        float nrm = sqrtf(dx * dx + dy * dy + dz * dz);
        float den = fmaxf(nrm, 1e-12f);
        rf[tid][0] = dx / den; rf[tid][1] = dy / den; rf[tid][2] = dz / den;
    }
    __syncthreads();
    const int oc = tid;
    float accm = 0.0f;
#pragma unroll
    for (int s = 0; s < NSUP; ++s) {
        int m = s * OC + oc;
        float d0 = dirs[m], d1 = dirs[SC + m], d2 = dirs[2 * SC + m];
        float nrm = sqrtf(d0 * d0 + d1 * d1 + d2 * d2);
        float den = fmaxf(nrm, 1e-12f);
        float s0 = d0 / den, s1 = d1 / den, s2 = d2 / den;
        float vm[4] = {-3.0e38f, -3.0e38f, -3.0e38f, -3.0e38f};   // 4-way ILP; max exact-assoc
#pragma unroll
        for (int kk = 0; kk < KNN; ++kk) {
            float th = fmaxf(rf[kk][0] * s0 + rf[kk][1] * s1 + rf[kk][2] * s2, 0.0f);
            float sup = fm[((size_t)b * NP + sj[kk]) * NC + OC + m];
            vm[kk & 3] = fmaxf(vm[kk & 3], th * sup);
        }
        accm += fmaxf(fmaxf(vm[0], vm[1]), fmaxf(vm[2], vm[3]));
    }
    float v = fm[bi * NC + oc] + accm / 3.0f;
    feature[bi * OC + oc] = v;
    featb[bi * OC + oc] = (short)f2bf(v);
}

// ---------- 6: neighborhood max-pool over vertex-space KNN ----------
__global__ __launch_bounds__(128) void pool_kernel(const float* __restrict__ feature,
                                                   const int* __restrict__ nbr2,
                                                   float* __restrict__ pooled) {
    __shared__ int sj[KNN];
    const int i = blockIdx.x, b = blockIdx.y, tid = threadIdx.x;
    const size_t bi = (size_t)b * NP + i;
    if (tid < KNN) sj[tid] = nbr2[bi * KNN + tid];
    __syncthreads();
    float m0 = -3.0e38f, m1 = -3.0e38f, m2 = -3.0e38f, m3 = -3.0e38f;
#pragma unroll
    for (int kk = 0; kk < KNN; kk += 4) {
        m0 = fmaxf(m0, feature[((size_t)b * NP + sj[kk + 0]) * OC + tid]);
        m1 = fmaxf(m1, feature[((size_t)b * NP + sj[kk + 1]) * OC + tid]);
        m2 = fmaxf(m2, feature[((size_t)b * NP + sj[kk + 2]) * OC + tid]);
        m3 = fmaxf(m3, feature[((size_t)b * NP + sj[kk + 3]) * OC + tid]);
    }
    pooled[bi * OC + tid] = fmaxf(fmaxf(m0, m1), fmaxf(m2, m3));
}

// ---------- 7a: partial sums of pooled over N (128 blocks) ----------
__global__ __launch_bounds__(128) void partial_kernel(const float* __restrict__ pooled,
                                                      float* __restrict__ part) {
    const int ch = blockIdx.x, b = blockIdx.y, tid = threadIdx.x;
    float s0 = 0.f, s1 = 0.f, s2 = 0.f, s3 = 0.f;
    const float* base = pooled + ((size_t)b * NP + ch * 128) * OC + tid;
    for (int i = 0; i < 128; i += 4) {
        s0 += base[(size_t)(i + 0) * OC];
        s1 += base[(size_t)(i + 1) * OC];
        s2 += base[(size_t)(i + 2) * OC];
        s3 += base[(size_t)(i + 3) * OC];
    }
    part[((size_t)b * 16 + ch) * OC + tid] = ((s0 + s1) + (s2 + s3));
}
// ---------- 7b: fused fglob + gdot ----------
__global__ __launch_bounds__(128) void fg_gdot_kernel(const float* __restrict__ part,
                                                      const float* __restrict__ conv2,
                                                      float* __restrict__ gd) {
    __shared__ float fgs[OC];
    const int b = blockIdx.x, tid = threadIdx.x;
    float s = 0.f;
#pragma unroll
    for (int c = 0; c < 16; ++c) s += part[((size_t)b * 16 + c) * OC + tid];
    fgs[tid] = s / (float)NP;
    __syncthreads();
    float g = 0.f;
    const float* w = conv2 + (size_t)tid * 2 * OC + OC;
    for (int c = 0; c < OC; ++c) g += fgs[c] * w[c];
    gd[b * OC + tid] = g;
}

// ---------- 8: final — bf16 MFMA conv2(feat) + ste(fmap) + gd + residual ----------
__global__ __launch_bounds__(256) void final_kernel(const short* __restrict__ featb,
                                                    const short* __restrict__ fbb,
                                                    const short* __restrict__ conv2b,
                                                    const short* __restrict__ stewb,
                                                    const float* __restrict__ gd,
                                                    const float* __restrict__ feature,
                                                    float* __restrict__ out) {
    __shared__ alignas(16) short Af[32][128];
    __shared__ alignas(16) short Am[32][128];
    const int m0 = blockIdx.x * 32, tid = threadIdx.x;
    const int lane = tid & 63, wid = tid >> 6, oct = lane >> 4;
    for (int i = 0; i < 2; ++i) {
        int v = i * 256 + tid, row = v >> 4, g = v & 15;
        *(bf16x8*)&Af[row][(g ^ (row & 7)) * 8] =
            *(const bf16x8*)&featb[(size_t)(m0 + row) * OC + g * 8];
        *(bf16x8*)&Am[row][(g ^ (row & 7)) * 8] =
            *(const bf16x8*)&fbb[(size_t)(m0 + row) * CIN + g * 8];
    }
    __syncthreads();
    f32x4 acc[2][2] = {};
#pragma unroll
    for (int kk = 0; kk < 4; ++kk) {
        int g = kk * 4 + oct;
        bf16x8 bC[2], bS[2];
#pragma unroll
        for (int nt = 0; nt < 2; ++nt) {
            int n = (wid * 2 + nt) * 16 + (lane & 15);
            bC[nt] = *(const bf16x8*)&conv2b[(size_t)n * (2 * OC) + g * 8];
            bS[nt] = *(const bf16x8*)&stewb[(size_t)n * CIN + g * 8];
        }
#pragma unroll
        for (int mt = 0; mt < 2; ++mt) {
            int ar = mt * 16 + (lane & 15);
            bf16x8 aF = *(const bf16x8*)&Af[ar][(g ^ (ar & 7)) * 8];
            bf16x8 aM = *(const bf16x8*)&Am[ar][(g ^ (ar & 7)) * 8];
#pragma unroll
            for (int nt = 0; nt < 2; ++nt) {
                acc[mt][nt] = __builtin_amdgcn_mfma_f32_16x16x32_bf16(aF, bC[nt], acc[mt][nt], 0, 0, 0);
                acc[mt][nt] = __builtin_amdgcn_mfma_f32_16x16x32_bf16(aM, bS[nt], acc[mt][nt], 0, 0, 0);
            }
        }
    }
#pragma unroll
    for (int mt = 0; mt < 2; ++mt)
#pragma unroll
        for (int nt = 0; nt < 2; ++nt) {
            int o = (wid * 2 + nt) * 16 + (lane & 15);
            int mbase = m0 + mt * 16 + oct * 4;
#pragma unroll
            for (int r = 0; r < 4; ++r) {
                int m = mbase + r;
                out[(size_t)m * OC + o] = acc[mt][nt][r]
                    + gd[(m >> 11) * OC + o] + feature[(size_t)m * OC + o];
            }
        }
}

extern "C" void kernel_launch(void* const* d_in, const int* in_sizes, int n_in,
                              void* d_out, int out_size, void* d_ws, size_t ws_size,
                              hipStream_t stream) {
    const float* vert  = (const float*)d_in[0];
    const float* fmap  = (const float*)d_in[1];
    const float* W     = (const float*)d_in[2];
    const float* bias  = (const float*)d_in[3];
    const float* dirs  = (const float*)d_in[4];
    const float* stew  = (const float*)d_in[5];
    const float* conv2 = (const float*)d_in[6];
    float* out = (float*)d_out;

    float* ws      = (float*)d_ws;
    float* sqn     = ws;                            // 16384
    short* fbb     = (short*)(sqn + 16384);         // 2M shorts (1M floats)
    float* C1      = sqn + 16384 + 1048576;         // 8.4M
    float* feature = C1 + 8388608;                  // 2M
    short* featb   = (short*)(feature + 2097152);   // 2M shorts (1M floats)
    float* gd      = feature + 2097152 + 1048576;   // 1024
    short* Wt      = (short*)(gd + 1024);           // 65536 shorts
    short* conv2b  = Wt + 65536;                    // 32768 shorts
    short* stewb   = conv2b + 32768;                // 16384 shorts
    int*   nbr1    = (int*)(stewb + 16384);         // 262144
    int*   nbr2    = nbr1 + 262144;                 // 262144
    float* part    = (float*)(nbr2 + 262144);       // 16384
    int*   cand    = (int*)C1;                      // alias: dead before fm_gemm writes C1
    float* pooled  = C1;                            // alias: C1 dead after act

    sqbf_kernel<<<1024, 256, 0, stream>>>(fmap, sqn, fbb);
    wprep_kernel<<<448, 256, 0, stream>>>(W, conv2, stew, Wt, conv2b, stewb);
    knn_feat_kernel<<<dim3(64, 8), 256, 0, stream>>>(fbb, sqn, cand);
    knn_refine_kernel<<<4096, 256, 0, stream>>>(fmap, cand, nbr1);
    knn_vert_kernel<<<dim3(64, 8), 256, 0, stream>>>(vert, nbr2);
    fm_gemm_kernel<<<dim3(256, 4), 256, 0, stream>>>(fbb, Wt, bias, C1);
    act_kernel<<<dim3(2048, 8), 128, 0, stream>>>(C1, nbr1, vert, dirs, feature, featb);
    pool_kernel<<<dim3(2048, 8), 128, 0, stream>>>(feature, nbr2, pooled);
    partial_kernel<<<dim3(16, 8), 128, 0, stream>>>(pooled, part);
    fg_gdot_kernel<<<8, 128, 0, stream>>>(part, conv2, gd);
    final_kernel<<<512, 256, 0, stream>>>(featb, fbb, conv2b, stewb, gd, feature, out);
}

// Round 11
// 227.843 us; speedup vs baseline: 6.7594x; 1.0648x over previous
//
#include <hip/hip_runtime.h>
#include <hip/hip_bf16.h>

#define BS 8
#define NP 2048
#define CIN 128
#define OC 128
#define NSUP 3
#define KNN 16
#define NC 512   // (NSUP+1)*OC
#define SC 384   // NSUP*OC
#define CAND 24  // candidate depth; distributed as 3 entries x 8 sub-lanes

typedef __attribute__((ext_vector_type(8))) short bf16x8;
typedef __attribute__((ext_vector_type(4))) float f32x4;

__device__ inline unsigned short f2bf(float x) {
    __hip_bfloat16 h = __float2bfloat16(x);
    return *reinterpret_cast<unsigned short*>(&h);
}
// sortable key: float order-preserving bits, low 11 bits replaced by point index
__device__ inline unsigned fkey(float d, int gi) {
    unsigned u = __float_as_uint(d);
    u ^= (unsigned)((int)u >> 31) | 0x80000000u;
    return (u & 0xFFFFF800u) | (unsigned)gi;
}
__device__ inline unsigned umn(unsigned a, unsigned b) { return a < b ? a : b; }
__device__ inline unsigned umx(unsigned a, unsigned b) { return a > b ? a : b; }

// ---------- 1: fused {squared-norms + bf16 copy} and {weight prep} ----------
__global__ __launch_bounds__(256) void prep_kernel(const float* __restrict__ in,
                                                   float* __restrict__ sq,
                                                   short* __restrict__ outp,
                                                   const float* __restrict__ W,
                                                   const float* __restrict__ conv2,
                                                   const float* __restrict__ stew,
                                                   short* __restrict__ Wt,
                                                   short* __restrict__ conv2b,
                                                   short* __restrict__ stewb) {
    const int tid = threadIdx.x;
    if (blockIdx.x < 1024) {                       // sqbf part
        const int row = blockIdx.x * 16 + (tid >> 4);
        const int seg = tid & 15;
        const float* p = in + (size_t)row * CIN + seg * 8;
        float4 f0 = *(const float4*)p;
        float4 f1 = *(const float4*)(p + 4);
        bf16x8 s;
        s[0] = (short)f2bf(f0.x); s[1] = (short)f2bf(f0.y);
        s[2] = (short)f2bf(f0.z); s[3] = (short)f2bf(f0.w);
        s[4] = (short)f2bf(f1.x); s[5] = (short)f2bf(f1.y);
        s[6] = (short)f2bf(f1.z); s[7] = (short)f2bf(f1.w);
        *(bf16x8*)&outp[(size_t)row * CIN + seg * 8] = s;
        float ss = f0.x*f0.x + f0.y*f0.y + f0.z*f0.z + f0.w*f0.w
                 + f1.x*f1.x + f1.y*f1.y + f1.z*f1.z + f1.w*f1.w;
#pragma unroll
        for (int msk = 1; msk <= 8; msk <<= 1) ss += __shfl_xor(ss, msk);
        if (seg == 0) sq[row] = ss;
    } else {                                       // wprep part
        int idx = (blockIdx.x - 1024) * 256 + tid;
        if (idx < NC * CIN) {
            int n = idx >> 7, k = idx & 127;
            Wt[idx] = (short)f2bf(W[(size_t)k * NC + n]);
        } else if (idx < NC * CIN + OC * 2 * OC) {
            int e = idx - NC * CIN;
            conv2b[e] = (short)f2bf(conv2[e]);
        } else {
            int e = idx - NC * CIN - OC * 2 * OC;
            stewb[e] = (short)f2bf(stew[e]);
        }
    }
}

// ---------- 2: feature KNN pass 1 — MFMA Gram + DISTRIBUTED top-24 ----------
// One top-24 list per query, 3 entries/lane over 8 sub-lanes (globally sorted).
// Insert: ballot -> per-group bitmask (uniform in group) -> shfl-broadcast key
// -> distributed med3 insert (shfl_up predecessor tail + 6 min/max).
// Insert of k >= L[23] is a no-op, so stale gate T is safe (perf-only).
#define TQF 32
#define TPF 64
#define NCHF (NP / TPF)
__global__ __launch_bounds__(256) void knn_feat_kernel(const short* __restrict__ fbb,
                                                       const float* __restrict__ sqn,
                                                       int* __restrict__ cand) {
    __shared__ alignas(16) short Qb[TQF][128];
    __shared__ alignas(16) short Pb[TPF][128];
    __shared__ float sqP[TPF];
    __shared__ unsigned Ds[TQF][68];               // packed keys

    const int b = blockIdx.y, q0 = blockIdx.x * TQF, tid = threadIdx.x;
    const int lane = tid & 63, wid = tid >> 6;
    const short* fb = fbb + (size_t)b * NP * CIN;

    unsigned l0 = 0xFFFFFFFFu, l1 = 0xFFFFFFFFu, l2 = 0xFFFFFFFFu;   // ranks 3s..3s+2
    unsigned T = 0xFFFFFFFFu;
    const int gbase = lane & 56;                   // group base within wave
    const int sub = lane & 7;

    for (int i = 0; i < 2; ++i) {                  // Q tile (swizzled)
        int v = i * 256 + tid, row = v >> 4, g = v & 15;
        *(bf16x8*)&Qb[row][(g ^ (row & 7)) * 8] =
            *(const bf16x8*)&fb[(size_t)(q0 + row) * CIN + g * 8];
    }
    for (int i = 0; i < 4; ++i) {                  // P chunk 0
        int v = i * 256 + tid, row = v >> 4, g = v & 15;
        *(bf16x8*)&Pb[row][(g ^ (row & 7)) * 8] =
            *(const bf16x8*)&fb[(size_t)row * CIN + g * 8];
    }
    if (tid < TPF) sqP[tid] = sqn[b * NP + tid];

    const int qt = wid >> 1, ph = wid & 1;
    const int qsl = tid >> 3;                      // query 0..31
    const int arow = qt * 16 + (lane & 15), asw = arow & 7;
    const int brow0 = ph * 32 + (lane & 15), brow1 = brow0 + 16;
    const int bsw0 = brow0 & 7, bsw1 = brow1 & 7;
    const int oct = lane >> 4;
    const int qrow = qt * 16 + oct * 4;

    for (int ch = 0; ch < NCHF; ++ch) {
        __syncthreads();                           // (A) Pb ready; prev scans done
        bf16x8 st0, st1, st2, st3;
        float sq_next = 0.f;
        const int nxt = (ch + 1 < NCHF);
        if (nxt) {                                 // reg-stage next chunk
            int p0n = (ch + 1) * TPF;
            { int v = tid;       int row = v>>4, g = v&15; st0 = *(const bf16x8*)&fb[(size_t)(p0n+row)*CIN + g*8]; }
            { int v = 256 + tid; int row = v>>4, g = v&15; st1 = *(const bf16x8*)&fb[(size_t)(p0n+row)*CIN + g*8]; }
            { int v = 512 + tid; int row = v>>4, g = v&15; st2 = *(const bf16x8*)&fb[(size_t)(p0n+row)*CIN + g*8]; }
            { int v = 768 + tid; int row = v>>4, g = v&15; st3 = *(const bf16x8*)&fb[(size_t)(p0n+row)*CIN + g*8]; }
            if (tid < TPF) sq_next = sqn[b * NP + p0n + tid];
        }
        f32x4 acc0 = {0.f,0.f,0.f,0.f}, acc1 = {0.f,0.f,0.f,0.f};
#pragma unroll
        for (int kk = 0; kk < 4; ++kk) {
            int g = kk * 4 + oct;
            bf16x8 av  = *(const bf16x8*)&Qb[arow][(g ^ asw) * 8];
            bf16x8 bv0 = *(const bf16x8*)&Pb[brow0][(g ^ bsw0) * 8];
            bf16x8 bv1 = *(const bf16x8*)&Pb[brow1][(g ^ bsw1) * 8];
            acc0 = __builtin_amdgcn_mfma_f32_16x16x32_bf16(av, bv0, acc0, 0, 0, 0);
            acc1 = __builtin_amdgcn_mfma_f32_16x16x32_bf16(av, bv1, acc1, 0, 0, 0);
        }
        const float sp0 = sqP[brow0], sp1 = sqP[brow1];
        const int pg0 = ch * TPF + brow0, pg1 = ch * TPF + brow1;
#pragma unroll
        for (int r = 0; r < 4; ++r) {
            int qg = q0 + qrow + r;
            unsigned k0 = fkey(sp0 - 2.0f * acc0[r], pg0);
            unsigned k1 = fkey(sp1 - 2.0f * acc1[r], pg1);
            if (qg == pg0) k0 = 0xFFFFFFFFu;       // self excluded
            if (qg == pg1) k1 = 0xFFFFFFFFu;
            Ds[qrow + r][brow0] = k0;
            Ds[qrow + r][brow1] = k1;
        }
        __syncthreads();                           // (B) Ds ready; Pb consumed

        {   // distributed scan: group of 8 lanes shares one query's list
            uint4 kA = *(const uint4*)&Ds[qsl][sub * 8];
            uint4 kB = *(const uint4*)&Ds[qsl][sub * 8 + 4];
            unsigned kv[8] = {kA.x, kA.y, kA.z, kA.w, kB.x, kB.y, kB.z, kB.w};
#pragma unroll
            for (int j = 0; j < 8; ++j) {
                unsigned long long bal = __ballot(kv[j] < T);
                unsigned gm = (unsigned)(bal >> gbase) & 0xFFu;
                while (gm) {                       // uniform within group
                    int l = __builtin_ctz(gm);
                    gm &= gm - 1;
                    unsigned k = (unsigned)__shfl((int)kv[j], gbase + l);
                    unsigned pv = (unsigned)__shfl_up((int)l2, 1);
                    if (sub == 0) pv = 0u;         // L[-1] = -inf sentinel
                    unsigned n0 = umn(umx(pv, k), l0);
                    unsigned n1 = umn(umx(l0, k), l1);
                    unsigned n2 = umn(umx(l1, k), l2);
                    l0 = n0; l1 = n1; l2 = n2;
                }
            }
            T = (unsigned)__shfl((int)l2, gbase + 7);   // refresh gate (L[23])
        }
        if (nxt) {                                 // write staged chunk (Pb free)
            { int v = tid;       int row = v>>4, g = v&15; *(bf16x8*)&Pb[row][(g^(row&7))*8] = st0; }
            { int v = 256 + tid; int row = v>>4, g = v&15; *(bf16x8*)&Pb[row][(g^(row&7))*8] = st1; }
            { int v = 512 + tid; int row = v>>4, g = v&15; *(bf16x8*)&Pb[row][(g^(row&7))*8] = st2; }
            { int v = 768 + tid; int row = v>>4, g = v&15; *(bf16x8*)&Pb[row][(g^(row&7))*8] = st3; }
            if (tid < TPF) sqP[tid] = sq_next;
        }
    }

    // store: list already globally sorted; lane sub holds ranks 3sub..3sub+2
    {
        int* dst = cand + ((size_t)b * NP + q0 + qsl) * CAND;
        dst[3 * sub + 0] = (int)(l0 & 0x7FFu);
        dst[3 * sub + 1] = (int)(l1 & 0x7FFu);
        dst[3 * sub + 2] = (int)(l2 & 0x7FFu);
    }
}

// ---------- 2b: refine — 4-way parallel candidates, fp64 inner, REFERENCE fp32
// rounding chain preserved: d32 = fl32( fl32(sq_i)+fl32(sj) - fl32(2*dot) )
__global__ __launch_bounds__(256) void knn_refine_kernel(const float* __restrict__ feat,
                                                         const int* __restrict__ cand,
                                                         int* __restrict__ nbr) {
    __shared__ unsigned long long keyS[4][CAND];
    const int w = threadIdx.x >> 6;
    const int lane = threadIdx.x & 63;
    const int grp = lane >> 4, sl = lane & 15;
    const int gq = blockIdx.x * 4 + w;
    const int b = gq >> 11;
    const int q = gq & (NP - 1);
    const float* fb = feat + (size_t)b * NP * CIN;

    double qd[8];
    {
        float4 a = *(const float4*)&fb[(size_t)q * CIN + sl * 8];
        float4 c = *(const float4*)&fb[(size_t)q * CIN + sl * 8 + 4];
        qd[0] = a.x; qd[1] = a.y; qd[2] = a.z; qd[3] = a.w;
        qd[4] = c.x; qd[5] = c.y; qd[6] = c.z; qd[7] = c.w;
    }
    double sqd = 0.0;
#pragma unroll
    for (int i = 0; i < 8; ++i) sqd += qd[i] * qd[i];
#pragma unroll
    for (int msk = 1; msk <= 8; msk <<= 1) sqd += __shfl_xor(sqd, msk);
    const float sqi = (float)sqd;

    const int* cq = cand + (size_t)gq * CAND;
    int jv[CAND / 4];
#pragma unroll
    for (int t = 0; t < CAND / 4; ++t) jv[t] = cq[t * 4 + grp];

#pragma unroll
    for (int t = 0; t < CAND / 4; ++t) {
        const int j = jv[t];
        float4 a = *(const float4*)&fb[(size_t)j * CIN + sl * 8];
        float4 c = *(const float4*)&fb[(size_t)j * CIN + sl * 8 + 4];
        double fd[8] = {a.x, a.y, a.z, a.w, c.x, c.y, c.z, c.w};
        double dot = 0.0, sj = 0.0;
#pragma unroll
        for (int i = 0; i < 8; ++i) { dot += qd[i] * fd[i]; sj += fd[i] * fd[i]; }
#pragma unroll
        for (int msk = 1; msk <= 8; msk <<= 1) {
            dot += __shfl_xor(dot, msk);
            sj  += __shfl_xor(sj, msk);
        }
        if (sl == 0) {
            float t1 = sqi + (float)sj;
            float t2 = (float)(2.0 * dot);
            float d32 = t1 - t2;
            unsigned u = __float_as_uint(d32);
            u ^= (unsigned)((int)u >> 31) | 0x80000000u;
            keyS[w][t * 4 + grp] = ((unsigned long long)u << 32) | (unsigned)j;
        }
    }
    __syncthreads();
    if (lane < CAND) {
        unsigned long long k = keyS[w][lane];
        int rank = 0;
#pragma unroll
        for (int m = 0; m < CAND; ++m) rank += (keyS[w][m] < k) ? 1 : 0;
        if (rank < KNN) nbr[(size_t)gq * KNN + rank] = (int)(k & 0xFFFFFFFFu);
    }
}

// ---------- 3: vertex KNN — DISTRIBUTED top-24, ranks 1..16 stored ----------
#define TQV 32
__global__ __launch_bounds__(256) void knn_vert_kernel(const float* __restrict__ vert,
                                                       int* __restrict__ nbr) {
    __shared__ alignas(16) float vx[NP], vy[NP], vz[NP];
    const int b = blockIdx.y;
    const int q0 = blockIdx.x * TQV;
    const int tid = threadIdx.x;
    const float* vb = vert + (size_t)b * NP * 3;

    for (int i = 0; i < NP * 3 / 256; ++i) {
        int e = i * 256 + tid;
        float v = vb[e];
        int row = e / 3, comp = e % 3;
        (comp == 0 ? vx : comp == 1 ? vy : vz)[row] = v;
    }
    __syncthreads();

    const int lane = tid & 63;
    const int gbase = lane & 56;
    const int q = tid >> 3;
    const int sub = tid & 7;
    const float qx = vx[q0 + q], qy = vy[q0 + q], qz = vz[q0 + q];

    unsigned l0 = 0xFFFFFFFFu, l1 = 0xFFFFFFFFu, l2 = 0xFFFFFFFFu;
    unsigned T = 0xFFFFFFFFu;

    for (int m = 0; m < NP / 64; ++m) {
        const int p0 = m * 64 + sub * 8;
        float4 xA = *(const float4*)&vx[p0], xB = *(const float4*)&vx[p0 + 4];
        float4 yA = *(const float4*)&vy[p0], yB = *(const float4*)&vy[p0 + 4];
        float4 zA = *(const float4*)&vz[p0], zB = *(const float4*)&vz[p0 + 4];
        float dv[8];
        { float dx = qx-xA.x, dy = qy-yA.x, dz = qz-zA.x; dv[0] = dx*dx+dy*dy+dz*dz; }
        { float dx = qx-xA.y, dy = qy-yA.y, dz = qz-zA.y; dv[1] = dx*dx+dy*dy+dz*dz; }
        { float dx = qx-xA.z, dy = qy-yA.z, dz = qz-zA.z; dv[2] = dx*dx+dy*dy+dz*dz; }
        { float dx = qx-xA.w, dy = qy-yA.w, dz = qz-zA.w; dv[3] = dx*dx+dy*dy+dz*dz; }
        { float dx = qx-xB.x, dy = qy-yB.x, dz = qz-zB.x; dv[4] = dx*dx+dy*dy+dz*dz; }
        { float dx = qx-xB.y, dy = qy-yB.y, dz = qz-zB.y; dv[5] = dx*dx+dy*dy+dz*dz; }
        { float dx = qx-xB.z, dy = qy-yB.z, dz = qz-zB.z; dv[6] = dx*dx+dy*dy+dz*dz; }
        { float dx = qx-xB.w, dy = qy-yB.w, dz = qz-zB.w; dv[7] = dx*dx+dy*dy+dz*dz; }
        unsigned kv[8];
#pragma unroll
        for (int j = 0; j < 8; ++j) kv[j] = fkey(dv[j], p0 + j);  // self d=0 -> rank 0
#pragma unroll
        for (int j = 0; j < 8; ++j) {
            unsigned long long bal = __ballot(kv[j] < T);
            unsigned gm = (unsigned)(bal >> gbase) & 0xFFu;
            while (gm) {
                int l = __builtin_ctz(gm);
                gm &= gm - 1;
                unsigned k = (unsigned)__shfl((int)kv[j], gbase + l);
                unsigned pv = (unsigned)__shfl_up((int)l2, 1);
                if (sub == 0) pv = 0u;
                unsigned n0 = umn(umx(pv, k), l0);
                unsigned n1 = umn(umx(l0, k), l1);
                unsigned n2 = umn(umx(l1, k), l2);
                l0 = n0; l1 = n1; l2 = n2;
            }
        }
        T = (unsigned)__shfl((int)l2, gbase + 7);
    }
    {   // ranks: lane sub holds L[3sub+e]; write dst[r-1] for r in 1..16
        int* dst = nbr + ((size_t)b * NP + q0 + q) * KNN;
        unsigned vals[3] = {l0, l1, l2};
#pragma unroll
        for (int e = 0; e < 3; ++e) {
            int r = 3 * sub + e;
            if (r >= 1 && r <= 16) dst[r - 1] = (int)(vals[e] & 0x7FFu);
        }
    }
}

// ---------- 4: fm = fmap @ W + bias — bf16 MFMA (fp32 acc) ----------
__global__ __launch_bounds__(256) void fm_gemm_kernel(const short* __restrict__ fbb,
                                                      const short* __restrict__ Wt,
                                                      const float* __restrict__ bias,
                                                      float* __restrict__ C) {
    __shared__ alignas(16) short As[64][128];
    const int m0 = blockIdx.x * 64, n0 = blockIdx.y * 128, tid = threadIdx.x;
    const int lane = tid & 63, wid = tid >> 6, oct = lane >> 4;
    for (int i = 0; i < 4; ++i) {
        int v = i * 256 + tid, row = v >> 4, g = v & 15;
        *(bf16x8*)&As[row][(g ^ (row & 7)) * 8] =
            *(const bf16x8*)&fbb[(size_t)(m0 + row) * CIN + g * 8];
    }
    __syncthreads();
    f32x4 acc[4][2] = {};
#pragma unroll
    for (int kk = 0; kk < 4; ++kk) {
        int g = kk * 4 + oct;
        bf16x8 bv[2];
#pragma unroll
        for (int nt = 0; nt < 2; ++nt) {
            int n = n0 + (wid * 2 + nt) * 16 + (lane & 15);
            bv[nt] = *(const bf16x8*)&Wt[(size_t)n * CIN + g * 8];
        }
#pragma unroll
        for (int mt = 0; mt < 4; ++mt) {
            int ar = mt * 16 + (lane & 15);
            bf16x8 av = *(const bf16x8*)&As[ar][(g ^ (ar & 7)) * 8];
#pragma unroll
            for (int nt = 0; nt < 2; ++nt)
                acc[mt][nt] = __builtin_amdgcn_mfma_f32_16x16x32_bf16(av, bv[nt], acc[mt][nt], 0, 0, 0);
        }
    }
#pragma unroll
    for (int mt = 0; mt < 4; ++mt)
#pragma unroll
        for (int nt = 0; nt < 2; ++nt) {
            int n = n0 + (wid * 2 + nt) * 16 + (lane & 15);
            float bsv = bias[n];
            int mbase = m0 + mt * 16 + oct * 4;
#pragma unroll
            for (int r = 0; r < 4; ++r)
                C[(size_t)(mbase + r) * NC + n] = acc[mt][nt][r] + bsv;
        }
}

// ---------- 5: direction-gated support activation + center (+ bf16 copy) ----------
__global__ __launch_bounds__(128) void act_kernel(const float* __restrict__ fm,
                                                  const int* __restrict__ nbr,
                                                  const float* __restrict__ vert,
                                                  const float* __restrict__ dirs,
                                                  float* __restrict__ feature,
                                                  short* __restrict__ featb) {
    __shared__ int sj[KNN];
    __shared__ float rf[KNN][4];
    const int i = blockIdx.x;
    const int b = blockIdx.y;
    const int tid = threadIdx.x;
    const size_t bi = (size_t)b * NP + i;
    if (tid < KNN) {
        int j = nbr[bi * KNN + tid];
        sj[tid] = j;
        const float* vb = vert + (size_t)b * NP * 3;
        float dx = vb[j * 3 + 0] - vb[i * 3 + 0];
        float dy = vb[j * 3 + 1] - vb[i * 3 + 1];
        float dz = vb[j * 3 + 2] - vb[i * 3 + 2];
        float nrm = sqrtf(dx * dx + dy * dy + dz * dz);
        float den = fmaxf(nrm, 1e-12f);
        rf[tid][0] = dx / den; rf[tid][1] = dy / den; rf[tid][2] = dz / den;
    }
    __syncthreads();
    const int oc = tid;
    float accm = 0.0f;
#pragma unroll
    for (int s = 0; s < NSUP; ++s) {
        int m = s * OC + oc;
        float d0 = dirs[m], d1 = dirs[SC + m], d2 = dirs[2 * SC + m];
        float nrm = sqrtf(d0 * d0 + d1 * d1 + d2 * d2);
        float den = fmaxf(nrm, 1e-12f);
        float s0 = d0 / den, s1 = d1 / den, s2 = d2 / den;
        float vm[4] = {-3.0e38f, -3.0e38f, -3.0e38f, -3.0e38f};
#pragma unroll
        for (int kk = 0; kk < KNN; ++kk) {
            float th = fmaxf(rf[kk][0] * s0 + rf[kk][1] * s1 + rf[kk][2] * s2, 0.0f);
            float sup = fm[((size_t)b * NP + sj[kk]) * NC + OC + m];
            vm[kk & 3] = fmaxf(vm[kk & 3], th * sup);
        }
        accm += fmaxf(fmaxf(vm[0], vm[1]), fmaxf(vm[2], vm[3]));
    }
    float v = fm[bi * NC + oc] + accm / 3.0f;
    feature[bi * OC + oc] = v;
    featb[bi * OC + oc] = (short)f2bf(v);
}

// ---------- 6: neighborhood max-pool over vertex-space KNN ----------
__global__ __launch_bounds__(128) void pool_kernel(const float* __restrict__ feature,
                                                   const int* __restrict__ nbr2,
                                                   float* __restrict__ pooled) {
    __shared__ int sj[KNN];
    const int i = blockIdx.x, b = blockIdx.y, tid = threadIdx.x;
    const size_t bi = (size_t)b * NP + i;
    if (tid < KNN) sj[tid] = nbr2[bi * KNN + tid];
    __syncthreads();
    float m0 = -3.0e38f, m1 = -3.0e38f, m2 = -3.0e38f, m3 = -3.0e38f;
#pragma unroll
    for (int kk = 0; kk < KNN; kk += 4) {
        m0 = fmaxf(m0, feature[((size_t)b * NP + sj[kk + 0]) * OC + tid]);
        m1 = fmaxf(m1, feature[((size_t)b * NP + sj[kk + 1]) * OC + tid]);
        m2 = fmaxf(m2, feature[((size_t)b * NP + sj[kk + 2]) * OC + tid]);
        m3 = fmaxf(m3, feature[((size_t)b * NP + sj[kk + 3]) * OC + tid]);
    }
    pooled[bi * OC + tid] = fmaxf(fmaxf(m0, m1), fmaxf(m2, m3));
}

// ---------- 7a: partial sums of pooled over N ----------
__global__ __launch_bounds__(128) void partial_kernel(const float* __restrict__ pooled,
                                                      float* __restrict__ part) {
    const int ch = blockIdx.x, b = blockIdx.y, tid = threadIdx.x;
    float s0 = 0.f, s1 = 0.f, s2 = 0.f, s3 = 0.f;
    const float* base = pooled + ((size_t)b * NP + ch * 128) * OC + tid;
    for (int i = 0; i < 128; i += 4) {
        s0 += base[(size_t)(i + 0) * OC];
        s1 += base[(size_t)(i + 1) * OC];
        s2 += base[(size_t)(i + 2) * OC];
        s3 += base[(size_t)(i + 3) * OC];
    }
    part[((size_t)b * 16 + ch) * OC + tid] = ((s0 + s1) + (s2 + s3));
}
// ---------- 7b: fused fglob + gdot ----------
__global__ __launch_bounds__(128) void fg_gdot_kernel(const float* __restrict__ part,
                                                      const float* __restrict__ conv2,
                                                      float* __restrict__ gd) {
    __shared__ float fgs[OC];
    const int b = blockIdx.x, tid = threadIdx.x;
    float s = 0.f;
#pragma unroll
    for (int c = 0; c < 16; ++c) s += part[((size_t)b * 16 + c) * OC + tid];
    fgs[tid] = s / (float)NP;
    __syncthreads();
    float g = 0.f;
    const float* w = conv2 + (size_t)tid * 2 * OC + OC;
    for (int c = 0; c < OC; ++c) g += fgs[c] * w[c];
    gd[b * OC + tid] = g;
}

// ---------- 8: final — bf16 MFMA conv2(feat) + ste(fmap) + gd + residual ----------
__global__ __launch_bounds__(256) void final_kernel(const short* __restrict__ featb,
                                                    const short* __restrict__ fbb,
                                                    const short* __restrict__ conv2b,
                                                    const short* __restrict__ stewb,
                                                    const float* __restrict__ gd,
                                                    const float* __restrict__ feature,
                                                    float* __restrict__ out) {
    __shared__ alignas(16) short Af[32][128];
    __shared__ alignas(16) short Am[32][128];
    const int m0 = blockIdx.x * 32, tid = threadIdx.x;
    const int lane = tid & 63, wid = tid >> 6, oct = lane >> 4;
    for (int i = 0; i < 2; ++i) {
        int v = i * 256 + tid, row = v >> 4, g = v & 15;
        *(bf16x8*)&Af[row][(g ^ (row & 7)) * 8] =
            *(const bf16x8*)&featb[(size_t)(m0 + row) * OC + g * 8];
        *(bf16x8*)&Am[row][(g ^ (row & 7)) * 8] =
            *(const bf16x8*)&fbb[(size_t)(m0 + row) * CIN + g * 8];
    }
    __syncthreads();
    f32x4 acc[2][2] = {};
#pragma unroll
    for (int kk = 0; kk < 4; ++kk) {
        int g = kk * 4 + oct;
        bf16x8 bC[2], bS[2];
#pragma unroll
        for (int nt = 0; nt < 2; ++nt) {
            int n = (wid * 2 + nt) * 16 + (lane & 15);
            bC[nt] = *(const bf16x8*)&conv2b[(size_t)n * (2 * OC) + g * 8];
            bS[nt] = *(const bf16x8*)&stewb[(size_t)n * CIN + g * 8];
        }
#pragma unroll
        for (int mt = 0; mt < 2; ++mt) {
            int ar = mt * 16 + (lane & 15);
            bf16x8 aF = *(const bf16x8*)&Af[ar][(g ^ (ar & 7)) * 8];
            bf16x8 aM = *(const bf16x8*)&Am[ar][(g ^ (ar & 7)) * 8];
#pragma unroll
            for (int nt = 0; nt < 2; ++nt) {
                acc[mt][nt] = __builtin_amdgcn_mfma_f32_16x16x32_bf16(aF, bC[nt], acc[mt][nt], 0, 0, 0);
                acc[mt][nt] = __builtin_amdgcn_mfma_f32_16x16x32_bf16(aM, bS[nt], acc[mt][nt], 0, 0, 0);
            }
        }
    }
#pragma unroll
    for (int mt = 0; mt < 2; ++mt)
#pragma unroll
        for (int nt = 0; nt < 2; ++nt) {
            int o = (wid * 2 + nt) * 16 + (lane & 15);
            int mbase = m0 + mt * 16 + oct * 4;
#pragma unroll
            for (int r = 0; r < 4; ++r) {
                int m = mbase + r;
                out[(size_t)m * OC + o] = acc[mt][nt][r]
                    + gd[(m >> 11) * OC + o] + feature[(size_t)m * OC + o];
            }
        }
}

extern "C" void kernel_launch(void* const* d_in, const int* in_sizes, int n_in,
                              void* d_out, int out_size, void* d_ws, size_t ws_size,
                              hipStream_t stream) {
    const float* vert  = (const float*)d_in[0];
    const float* fmap  = (const float*)d_in[1];
    const float* W     = (const float*)d_in[2];
    const float* bias  = (const float*)d_in[3];
    const float* dirs  = (const float*)d_in[4];
    const float* stew  = (const float*)d_in[5];
    const float* conv2 = (const float*)d_in[6];
    float* out = (float*)d_out;

    float* ws      = (float*)d_ws;
    float* sqn     = ws;                            // 16384
    short* fbb     = (short*)(sqn + 16384);         // 2M shorts (1M floats)
    float* C1      = sqn + 16384 + 1048576;         // 8.4M
    float* feature = C1 + 8388608;                  // 2M
    short* featb   = (short*)(feature + 2097152);   // 2M shorts (1M floats)
    float* gd      = feature + 2097152 + 1048576;   // 1024
    short* Wt      = (short*)(gd + 1024);           // 65536 shorts
    short* conv2b  = Wt + 65536;                    // 32768 shorts
    short* stewb   = conv2b + 32768;                // 16384 shorts
    int*   nbr1    = (int*)(stewb + 16384);         // 262144
    int*   nbr2    = nbr1 + 262144;                 // 262144
    float* part    = (float*)(nbr2 + 262144);       // 16384
    int*   cand    = (int*)C1;                      // alias: dead before fm_gemm writes C1
    float* pooled  = C1;                            // alias: C1 dead after act

    prep_kernel<<<1472, 256, 0, stream>>>(fmap, sqn, fbb, W, conv2, stew, Wt, conv2b, stewb);
    knn_feat_kernel<<<dim3(64, 8), 256, 0, stream>>>(fbb, sqn, cand);
    knn_refine_kernel<<<4096, 256, 0, stream>>>(fmap, cand, nbr1);
    knn_vert_kernel<<<dim3(64, 8), 256, 0, stream>>>(vert, nbr2);
    fm_gemm_kernel<<<dim3(256, 4), 256, 0, stream>>>(fbb, Wt, bias, C1);
    act_kernel<<<dim3(2048, 8), 128, 0, stream>>>(C1, nbr1, vert, dirs, feature, featb);
    pool_kernel<<<dim3(2048, 8), 128, 0, stream>>>(feature, nbr2, pooled);
    partial_kernel<<<dim3(16, 8), 128, 0, stream>>>(pooled, part);
    fg_gdot_kernel<<<8, 128, 0, stream>>>(part, conv2, gd);
    final_kernel<<<512, 256, 0, stream>>>(featb, fbb, conv2b, stewb, gd, feature, out);
}